// Round 5
// baseline (200.675 us; speedup 1.0000x reference)
//
#include <hip/hip_runtime.h>

#define Bb 4
#define Tt 1024
#define Cc 1024
#define Hh 16
#define BT (Bb*Tt)
#define CHUNK 32
#define NCH (Tt/CHUNK)

typedef unsigned int uint;
typedef unsigned short u16;
typedef __bf16 bf16x8 __attribute__((ext_vector_type(8)));
typedef float f32x4 __attribute__((ext_vector_type(4)));
typedef const __attribute__((address_space(1))) uint GU;
typedef __attribute__((address_space(3))) uint LU;

__device__ __forceinline__ float blo(uint u) { return __uint_as_float(u << 16); }
__device__ __forceinline__ float bhi(uint u) { return __uint_as_float(u & 0xffff0000u); }
__device__ __forceinline__ float b2f(u16 u) { return __uint_as_float(((uint)u) << 16); }
__device__ __forceinline__ u16 f2b(float f) {
  uint u = __float_as_uint(f);
  return (u16)((u + 0x7fffu + ((u >> 16) & 1u)) >> 16);   // RNE
}

// ---------------- prep: xxx = bf16(x + (shift(x)-x)*maa_x) ----------------
__global__ __launch_bounds__(256) void prep_xxx(const float* __restrict__ x,
    const float* __restrict__ maa_x, u16* __restrict__ xxx)
{
  int idx = blockIdx.x*256 + threadIdx.x;
  int c4 = idx & 255;
  int bt = idx >> 8;
  int t = bt & (Tt-1);
  float4 xc = ((const float4*)x)[idx];
  float4 xp = make_float4(0.f,0.f,0.f,0.f);
  if (t > 0) xp = ((const float4*)x)[idx - 256];
  float4 mx = ((const float4*)maa_x)[c4];
  ushort4 o;
  o.x = f2b(fmaf(xp.x - xc.x, mx.x, xc.x));
  o.y = f2b(fmaf(xp.y - xc.y, mx.y, xc.y));
  o.z = f2b(fmaf(xp.z - xc.z, mx.z, xc.z));
  o.w = f2b(fmaf(xp.w - xc.w, mx.w, xc.w));
  ((ushort4*)xxx)[idx] = o;
}

// ---------------- fused mix: MFMA (tanh Σ m1-partials)@w2 + epilogue ----------
__global__ __launch_bounds__(256) void mix_mfma(
    const float* __restrict__ x, const float* __restrict__ m1p,
    const u16* __restrict__ w2T,
    const float* __restrict__ maa_w, const float* __restrict__ maa_k,
    const float* __restrict__ maa_v, const float* __restrict__ maa_r,
    const float* __restrict__ maa_g,
    u16* __restrict__ xw, u16* __restrict__ xk, u16* __restrict__ xv,
    u16* __restrict__ xr, u16* __restrict__ xg)
{
  const int tid = threadIdx.x;
  const int lane = tid & 63;
  const int wv = tid >> 6;
  const int sid = blockIdx.x*4 + wv;        // 4096 strips, row-major
  const int rs = sid >> 4, cs = sid & 15;
  const int r0 = rs*16, c0 = cs*64;
  const int fr = lane & 15, kc = lane >> 4;

  float xc[4][4], xd[4][4];
  #pragma unroll
  for (int n = 0; n < 4; ++n) {
    int col = c0 + n*16 + fr;
    #pragma unroll
    for (int q = 0; q < 4; ++q) {
      int row = r0 + kc*4 + q;
      size_t o = (size_t)row*Cc + col;
      float v = x[o];
      float p = ((row & (Tt-1)) != 0) ? x[o - Cc] : 0.f;
      xc[n][q] = v;
      xd[n][q] = p - v;
    }
  }

  const size_t aBase = (size_t)(r0 + fr)*160 + kc*8;
  u16* const outs[5] = {xw, xk, xv, xr, xg};
  const float* const maas[5] = {maa_w, maa_k, maa_v, maa_r, maa_g};

  #pragma unroll
  for (int f = 0; f < 5; ++f) {
    float s8[8] = {0.f,0.f,0.f,0.f,0.f,0.f,0.f,0.f};
    #pragma unroll
    for (int z = 0; z < 4; ++z) {
      const float4* p = (const float4*)(m1p + (size_t)z*655360 + aBase + f*32);
      float4 a = p[0], b = p[1];
      s8[0]+=a.x; s8[1]+=a.y; s8[2]+=a.z; s8[3]+=a.w;
      s8[4]+=b.x; s8[5]+=b.y; s8[6]+=b.z; s8[7]+=b.w;
    }
    u16 t8[8];
    #pragma unroll
    for (int j = 0; j < 8; ++j) t8[j] = f2b(tanhf(s8[j]));
    bf16x8 af = *(const bf16x8*)t8;
    f32x4 acc[4];
    #pragma unroll
    for (int n = 0; n < 4; ++n) {
      bf16x8 bg = *(const bf16x8*)(w2T + (size_t)(c0 + n*16 + fr)*160 + f*32 + kc*8);
      acc[n] = __builtin_amdgcn_mfma_f32_16x16x32_bf16(af, bg, f32x4{0.f,0.f,0.f,0.f}, 0, 0, 0);
    }
    const float* __restrict__ ma = maas[f];
    u16* __restrict__ op = outs[f];
    #pragma unroll
    for (int n = 0; n < 4; ++n) {
      int col = c0 + n*16 + fr;
      float mv = ma[col];
      #pragma unroll
      for (int q = 0; q < 4; ++q) {
        int row = r0 + kc*4 + q;
        op[(size_t)row*Cc + col] = f2b(fmaf(xd[n][q], mv + acc[n][q], xc[n][q]));
      }
    }
  }
}

// ---------------- weight transpose+convert: dst[n][k] = bf16(src[k][n]) ----------------
struct WPair { const float* s; u16* d; int K; int N; };
struct WPack { WPair p[9]; };

__global__ __launch_bounds__(256) void transW(WPack wp) {
  WPair pr = wp.p[blockIdx.z];
  int c0 = blockIdx.x*32, r0 = blockIdx.y*32;
  if (c0 >= pr.N || r0 >= pr.K) return;
  __shared__ float tile[32][33];
  int tc = threadIdx.x & 31, tr = threadIdx.x >> 5;
  #pragma unroll
  for (int p = 0; p < 4; ++p)
    tile[tr + p*8][tc] = pr.s[(size_t)(r0 + tr + p*8)*pr.N + c0 + tc];
  __syncthreads();
  #pragma unroll
  for (int p = 0; p < 4; ++p) {
    int n = tr + p*8;
    pr.d[(size_t)(c0 + n)*pr.K + r0 + tc] = f2b(tile[tc][n]);
  }
}

// ---------------- bf16 MFMA GEMM core (m97 structure + chunk swizzle) ----------------
// ld: row stride (elems) of A and Bt; kloop: K extent to accumulate (<= ld).
template<bool OUTF32>
__device__ __forceinline__ void mfma_core(
    const u16* __restrict__ A, const u16* __restrict__ Bt,
    void* __restrict__ Cout, const float* __restrict__ bias,
    int ld, int kloop, int N, int act)
{
  __shared__ __align__(16) u16 lds[2][2][128*32];   // 32 KB
  const int tid = threadIdx.x;
  const int lane = tid & 63;
  const int wv = __builtin_amdgcn_readfirstlane(tid >> 6);

  // bijective XCD swizzle (requires gridDim.y % 8 == 0)
  const int nby8 = gridDim.y >> 3;
  const int i_lin = blockIdx.y * gridDim.x + blockIdx.x;
  const int cx = i_lin & 7, rest = i_lin >> 3;
  const int bm = (cx * nby8 + rest % nby8) * 128;
  const int bn = (rest / nby8) * 128;

  const int wm = (wv >> 1) * 64;
  const int wn = (wv & 1) * 64;
  const int kc = lane >> 4;
  const int fr = lane & 15;

  const int srow = wv*16 + (lane >> 2);
  const int ssw  = (srow >> 1) & 3;                 // == s(srow+64)
  const int scol = ((lane & 3) ^ ssw) * 8;
  const size_t aoff = (size_t)(bm + srow) * ld + scol;
  const size_t boff = (size_t)(bn + srow) * ld + scol;

#define STAGE(bufi, kt) do { \
    size_t ko_ = (size_t)(kt) * 32; \
    __builtin_amdgcn_global_load_lds((GU*)(A + aoff + ko_), \
        (LU*)&lds[bufi][0][wv*512], 16, 0, 0); \
    __builtin_amdgcn_global_load_lds((GU*)(A + aoff + (size_t)64*ld + ko_), \
        (LU*)&lds[bufi][0][wv*512 + 64*32], 16, 0, 0); \
    __builtin_amdgcn_global_load_lds((GU*)(Bt + boff + ko_), \
        (LU*)&lds[bufi][1][wv*512], 16, 0, 0); \
    __builtin_amdgcn_global_load_lds((GU*)(Bt + boff + (size_t)64*ld + ko_), \
        (LU*)&lds[bufi][1][wv*512 + 64*32], 16, 0, 0); \
  } while(0)

  int ard[4], brd[4];
  #pragma unroll
  for (int m = 0; m < 4; ++m) {
    int ra = wm + m*16 + fr;
    int rb = wn + m*16 + fr;
    ard[m] = ra*32 + (kc ^ ((ra >> 1) & 3))*8;
    brd[m] = rb*32 + (kc ^ ((rb >> 1) & 3))*8;
  }

  f32x4 acc[4][4];
  #pragma unroll
  for (int m = 0; m < 4; ++m)
    #pragma unroll
    for (int n = 0; n < 4; ++n)
      acc[m][n] = f32x4{0.f, 0.f, 0.f, 0.f};

  const int NK = kloop >> 5;
  STAGE(0, 0);
  __syncthreads();
  int buf = 0;
  for (int kt = 0; kt < NK; ++kt) {
    if (kt + 1 < NK) STAGE(buf^1, kt+1);
    bf16x8 af[4], bg[4];
    #pragma unroll
    for (int m = 0; m < 4; ++m) af[m] = *(const bf16x8*)&lds[buf][0][ard[m]];
    #pragma unroll
    for (int n = 0; n < 4; ++n) bg[n] = *(const bf16x8*)&lds[buf][1][brd[n]];
    #pragma unroll
    for (int m = 0; m < 4; ++m)
      #pragma unroll
      for (int n = 0; n < 4; ++n)
        acc[m][n] = __builtin_amdgcn_mfma_f32_16x16x32_bf16(af[m], bg[n], acc[m][n], 0, 0, 0);
    __syncthreads();
    buf ^= 1;
  }
#undef STAGE

  const int orow = bm + wm + (lane >> 4) * 4;
  const int ocol = bn + wn + fr;
  #pragma unroll
  for (int m = 0; m < 4; ++m) {
    #pragma unroll
    for (int n = 0; n < 4; ++n) {
      int col = ocol + n*16;
      if (col < N) {
        float bs = bias ? bias[col] : 0.f;
        #pragma unroll
        for (int q = 0; q < 4; ++q) {
          float vv = acc[m][n][q] + bs;
          if (act == 1) vv = tanhf(vv);
          else if (act == 2) vv = vv / (1.f + __expf(-vv));
          else if (act == 3) vv = __expf(-__expf(vv));
          else if (act == 4) vv = __expf(vv);
          size_t off = (size_t)(orow + m*16 + q) * N + col;
          if (OUTF32) ((float*)Cout)[off] = vv;
          else ((u16*)Cout)[off] = f2b(vv);
        }
      }
    }
  }
}

template<int ACT, bool OUTF32>
__global__ __launch_bounds__(256) void gemm_mfma(
    const u16* __restrict__ A, const u16* __restrict__ Bt,
    void* __restrict__ Cout, const float* __restrict__ bias, int K, int N)
{
  mfma_core<OUTF32>(A, Bt, Cout, bias, K, K, N, ACT);
}

// K-split GEMM: z-th block-slab accumulates k in [z*ksz, (z+1)*ksz), writes
// raw fp32 partials to Cp + z*4096*N. No activation (applied at consumer).
__global__ __launch_bounds__(256) void gemm_ksplit(
    const u16* __restrict__ A, const u16* __restrict__ Bt,
    float* __restrict__ Cp, int ld, int ksz, int N)
{
  const int z = blockIdx.z;
  mfma_core<true>(A + (size_t)z*ksz, Bt + (size_t)z*ksz,
                  Cp + (size_t)z*4096*N, nullptr, ld, ksz, N, 0);
}

// ---------------- ew = exp(tanh(sum wl1p)@tdw2T^T + tdecay), K=64, no LDS ----
__global__ __launch_bounds__(256) void gemm_ew64(
    const float* __restrict__ wl1p, const u16* __restrict__ Bt,
    const float* __restrict__ tdecay, float* __restrict__ ew)
{
  const int tid = threadIdx.x;
  const int lane = tid & 63;
  const int wv = tid >> 6;
  const int nby8 = gridDim.y >> 3;
  const int i_lin = blockIdx.y * gridDim.x + blockIdx.x;
  const int cx = i_lin & 7, rest = i_lin >> 3;
  const int bm = (cx * nby8 + rest % nby8) * 128;
  const int bn = (rest / nby8) * 128;
  const int wm = (wv >> 1) * 64;
  const int wn = (wv & 1) * 64;
  const int kc = lane >> 4;
  const int fr = lane & 15;

  bf16x8 af[4][2];
  #pragma unroll
  for (int m = 0; m < 4; ++m) {
    int row = bm + wm + m*16 + fr;
    #pragma unroll
    for (int ks = 0; ks < 2; ++ks) {
      size_t base = (size_t)row*64 + ks*32 + kc*8;
      float s8[8] = {0.f,0.f,0.f,0.f,0.f,0.f,0.f,0.f};
      #pragma unroll
      for (int z = 0; z < 4; ++z) {
        const float4* p = (const float4*)(wl1p + (size_t)z*262144 + base);
        float4 a = p[0], b = p[1];
        s8[0]+=a.x; s8[1]+=a.y; s8[2]+=a.z; s8[3]+=a.w;
        s8[4]+=b.x; s8[5]+=b.y; s8[6]+=b.z; s8[7]+=b.w;
      }
      u16 t8[8];
      #pragma unroll
      for (int j = 0; j < 8; ++j) t8[j] = f2b(tanhf(s8[j]));
      af[m][ks] = *(const bf16x8*)t8;
    }
  }

  f32x4 acc[4][4];
  #pragma unroll
  for (int m = 0; m < 4; ++m)
    #pragma unroll
    for (int n = 0; n < 4; ++n)
      acc[m][n] = f32x4{0.f,0.f,0.f,0.f};

  #pragma unroll
  for (int ks = 0; ks < 2; ++ks) {
    bf16x8 bg[4];
    #pragma unroll
    for (int n = 0; n < 4; ++n)
      bg[n] = *(const bf16x8*)(Bt + (size_t)(bn + wn + n*16 + fr)*64 + ks*32 + kc*8);
    #pragma unroll
    for (int m = 0; m < 4; ++m)
      #pragma unroll
      for (int n = 0; n < 4; ++n)
        acc[m][n] = __builtin_amdgcn_mfma_f32_16x16x32_bf16(af[m][ks], bg[n], acc[m][n], 0, 0, 0);
  }

  const int orow = bm + wm + kc*4;
  const int ocol = bn + wn + fr;
  #pragma unroll
  for (int n = 0; n < 4; ++n) {
    int col = ocol + n*16;
    float bs = tdecay[col];
    #pragma unroll
    for (int m = 0; m < 4; ++m)
      #pragma unroll
      for (int q = 0; q < 4; ++q)
        ew[(size_t)(orow + m*16 + q)*Cc + col] = __expf(acc[m][n][q] + bs);
  }
}

// ---------------- 256x256 GEMM for the big batched r/k/v/g GEMMs ----------------
// 2 phases/K-tile (merged from round-2's 4): each phase covers one k-half with
// 12 ds_read_b128 (8 A + 4 B) and 32 MFMA per barrier-pair. Same LDS layout,
// swizzle, and staging as the verified round-2 kernel; only phase grouping and
// vmcnt placement differ. Ledger (4 loads staged/phase, per-wave): steady
// in-flight oscillates 4<->8; VMW(4) at phase end retires the half needed by
// the NEXT phase; every VMW precedes a barrier (cross-wave retirement).
struct GPack { const u16* A[4]; const u16* B[4]; u16* C[4]; };

#define VMW(n) asm volatile("s_waitcnt vmcnt(" #n ")" ::: "memory")
#define LGKM0() asm volatile("s_waitcnt lgkmcnt(0)" ::: "memory")
#define SCHB() __builtin_amdgcn_sched_barrier(0)
#define HBAR() __builtin_amdgcn_s_barrier()

__global__ __launch_bounds__(512) void gemm_rkvg256(GPack gp) {
  __shared__ __align__(16) u16 lds[2][2][2][8192];   // [dbuf][A/B][khalf][256*32] = 128 KB
  const int z = blockIdx.z;
  const u16* __restrict__ Ap  = gp.A[z];
  const u16* __restrict__ Btp = gp.B[z];
  u16* __restrict__ Cp = gp.C[z];
  const int act = (z == 3) ? 2 : 0;

  const int tid = threadIdx.x;
  const int lane = tid & 63;
  const int wv = __builtin_amdgcn_readfirstlane(tid >> 6);

  const int i_lin = blockIdx.y * gridDim.x + blockIdx.x;   // 0..63
  const int tile = (i_lin & 7) * 8 + (i_lin >> 3);
  const int bm = (tile >> 2) * 256;
  const int bn = (tile & 3) * 256;

  const int wm = (wv >> 2) * 128;    // 2 wave-rows of 128
  const int wn = (wv & 3) * 64;      // 4 wave-cols of 64
  const int kc = lane >> 4;
  const int fr = lane & 15;

  const int srow0 = (wv*2 + 0)*16 + (lane >> 2);
  const int srow1 = (wv*2 + 1)*16 + (lane >> 2);
  const int sc0 = ((lane & 3) ^ ((srow0 >> 1) & 3)) * 8;
  const int sc1 = ((lane & 3) ^ ((srow1 >> 1) & 3)) * 8;
  const size_t aoff0 = (size_t)(bm + srow0)*Cc + sc0;
  const size_t aoff1 = (size_t)(bm + srow1)*Cc + sc1;
  const size_t boff0 = (size_t)(bn + srow0)*Cc + sc0;
  const size_t boff1 = (size_t)(bn + srow1)*Cc + sc1;

  int ard[8], brd[4];
  #pragma unroll
  for (int mh = 0; mh < 2; ++mh)
    #pragma unroll
    for (int mf = 0; mf < 4; ++mf) {
      int r = wm + mh*64 + mf*16 + fr;
      ard[mh*4+mf] = r*32 + (kc ^ ((r >> 1) & 3))*8;
    }
  #pragma unroll
  for (int nf = 0; nf < 4; ++nf) {
    int r = wn + nf*16 + fr;
    brd[nf] = r*32 + (kc ^ ((r >> 1) & 3))*8;
  }

  f32x4 acc[8][4];
  #pragma unroll
  for (int m = 0; m < 8; ++m)
    #pragma unroll
    for (int n = 0; n < 4; ++n)
      acc[m][n] = f32x4{0.f, 0.f, 0.f, 0.f};

#define STG256(DB, MAT, KH, kt, off0, off1, src) do { \
    u16* dst_ = &lds[(DB)][(MAT)][(KH)][wv*1024]; \
    __builtin_amdgcn_global_load_lds((GU*)((src) + (off0) + (size_t)(kt)*64 + (KH)*32), \
        (LU*)dst_, 16, 0, 0); \
    __builtin_amdgcn_global_load_lds((GU*)((src) + (off1) + (size_t)(kt)*64 + (KH)*32), \
        (LU*)(dst_ + 512), 16, 0, 0); \
  } while(0)

// One phase = one k-half: 12 ds_reads, optional 4-load stage of tile t+1's
// same k-half, counted vmcnt, barrier, lgkm drain, 32 MFMA, barrier.
#define PH2(cur, KH, DOSTAGE, VMTOK) do { \
    _Pragma("unroll") \
    for (int mf = 0; mf < 8; ++mf) \
      af[mf] = *(const bf16x8*)&lds[(cur)][0][KH][ard[mf]]; \
    _Pragma("unroll") \
    for (int nf = 0; nf < 4; ++nf) \
      bg[nf] = *(const bf16x8*)&lds[(cur)][1][KH][brd[nf]]; \
    if (DOSTAGE) { \
      STG256((cur)^1, 0, KH, t+1, aoff0, aoff1, Ap); \
      STG256((cur)^1, 1, KH, t+1, boff0, boff1, Btp); \
    } \
    VMTOK; \
    SCHB(); \
    HBAR(); \
    LGKM0(); \
    SCHB(); \
    __builtin_amdgcn_s_setprio(1); \
    _Pragma("unroll") \
    for (int mf = 0; mf < 8; ++mf) \
      _Pragma("unroll") \
      for (int nf = 0; nf < 4; ++nf) \
        acc[mf][nf] = __builtin_amdgcn_mfma_f32_16x16x32_bf16(af[mf], bg[nf], acc[mf][nf], 0, 0, 0); \
    __builtin_amdgcn_s_setprio(0); \
    SCHB(); \
    HBAR(); \
  } while(0)

  const int NK = Cc >> 6;   // 16 K-tiles of 64

  // prologue: stage tile 0 (kh0 then kh1); VMW(4) retires kh0
  STG256(0, 0, 0, 0, aoff0, aoff1, Ap);
  STG256(0, 1, 0, 0, boff0, boff1, Btp);
  STG256(0, 0, 1, 0, aoff0, aoff1, Ap);
  STG256(0, 1, 1, 0, boff0, boff1, Btp);
  VMW(4);
  SCHB();
  HBAR();

  bf16x8 af[8], bg[4];
  int t;
  #pragma unroll 2
  for (t = 0; t < NK - 1; ++t) {
    const int cur = t & 1;
    PH2(cur, 0, true, VMW(4));
    PH2(cur, 1, true, VMW(4));
  }
  { // final K-tile: no prefetch; drain kh1 before its phase
    const int cur = t & 1;
    PH2(cur, 0, false, VMW(0));
    PH2(cur, 1, false, (void)0);
  }
#undef PH2
#undef STG256

  const int orow = bm + wm + (lane >> 4) * 4;
  const int ocol = bn + wn + fr;
  #pragma unroll
  for (int m = 0; m < 8; ++m) {
    #pragma unroll
    for (int nf = 0; nf < 4; ++nf) {
      #pragma unroll
      for (int q = 0; q < 4; ++q) {
        float vv = acc[m][nf][q];
        if (act == 2) vv = vv / (1.f + __expf(-vv));
        Cp[(size_t)(orow + (m >> 2)*64 + (m & 3)*16 + q) * Cc + ocol + nf*16] = f2b(vv);
      }
    }
  }
}

// ---------------- WKV6 pass 1: chunked matmul formulation (MFMA) ----------------
__global__ __launch_bounds__(256) void wkv_pass1(u16* __restrict__ r,
    const u16* __restrict__ k, const u16* __restrict__ v,
    const float* __restrict__ ew, const float* __restrict__ u,
    float* __restrict__ y, u16* __restrict__ S, float* __restrict__ D)
{
  __shared__ __align__(16) u16 rS[CHUNK][72];
  __shared__ __align__(16) u16 kS[CHUNK][72];
  __shared__ __align__(16) u16 vS[CHUNK][72];
  __shared__ __align__(16) float bufEW[CHUNK][68];   // ew -> eR (in-place)
  __shared__ __align__(16) float eKnL[CHUNK][68];
  __shared__ __align__(16) u16 Rt[CHUNK][72];
  __shared__ __align__(16) u16 Kt[CHUNK][72];
  __shared__ __align__(16) u16 Ru[CHUNK][72];
  __shared__ __align__(16) u16 KhT[64][40];
  __shared__ __align__(16) u16 VT[64][40];
  __shared__ __align__(16) u16 A_lds[CHUNK][40];
  __shared__ float uL[64];
  __shared__ float Dl[64];

  const int blk = blockIdx.x;
  const int chunk = blk & (NCH-1);
  const int bh = blk >> 5;
  const int h = bh & (Hh-1);
  const int b = bh >> 4;
  const int tid = threadIdx.x;
  const int lane = tid & 63;
  const int wv = tid >> 6;
  const int fr = lane & 15;
  const int kc = lane >> 4;

  const size_t rowbase = ((size_t)(b*Tt + chunk*CHUNK))*Cc + h*64;
  {
    int tt = tid >> 3, c8 = (tid & 7)*8;
    size_t go = rowbase + (size_t)tt*Cc + c8;
    *(uint4*)&rS[tt][c8] = *(const uint4*)(r + go);
    *(uint4*)&kS[tt][c8] = *(const uint4*)(k + go);
    *(uint4*)&vS[tt][c8] = *(const uint4*)(v + go);
    *(float4*)&bufEW[tt][c8]   = *(const float4*)(ew + go);
    *(float4*)&bufEW[tt][c8+4] = *(const float4*)(ew + go + 4);
  }
  if (tid < 64) uL[tid] = u[h*64 + tid];
  __syncthreads();

  if (tid < 64) {
    float lwp = 0.f;
    for (int t = 0; t < CHUNK; ++t) {
      float e = bufEW[t][tid];
      bufEW[t][tid] = __expf(lwp);        // eR[t] = exp(lw[t-1])
      lwp -= e;
      eKnL[t][tid] = __expf(-lwp);        // exp(-lw[t])
    }
    Dl[tid] = __expf(lwp);
    D[(size_t)blk*64 + tid] = Dl[tid];
  }
  __syncthreads();

  {
    int t = tid >> 3, i0 = (tid & 7)*8;
    uint4 rv4 = *(const uint4*)&rS[t][i0];
    uint4 kv4 = *(const uint4*)&kS[t][i0];
    const uint* rw = (const uint*)&rv4;
    const uint* kw = (const uint*)&kv4;
    u16 rt8[8], kt8[8], ru8[8];
    #pragma unroll
    for (int q = 0; q < 8; ++q) {
      int i = i0 + q;
      float rv = (q & 1) ? bhi(rw[q>>1]) : blo(rw[q>>1]);
      float kv = (q & 1) ? bhi(kw[q>>1]) : blo(kw[q>>1]);
      float eR = bufEW[t][i];
      float eKn = eKnL[t][i];
      float ktv = kv * eKn;
      rt8[q] = f2b(rv * eR);
      kt8[q] = f2b(ktv);
      ru8[q] = f2b(rv * uL[i]);
      KhT[i][t] = f2b(ktv * Dl[i]);
      VT[i][t] = vS[t][i];
    }
    *(uint4*)&Rt[t][i0] = *(const uint4*)rt8;
    *(uint4*)&Kt[t][i0] = *(const uint4*)kt8;
    *(uint4*)&Ru[t][i0] = *(const uint4*)ru8;
  }
  __syncthreads();

  {
    const int wr = wv >> 1, wc = wv & 1;
    f32x4 accA = {0.f,0.f,0.f,0.f};
    f32x4 accD = {0.f,0.f,0.f,0.f};
    #pragma unroll
    for (int ks = 0; ks < 2; ++ks) {
      bf16x8 a  = *(const bf16x8*)&Rt[wr*16+fr][kc*8 + ks*32];
      bf16x8 bb = *(const bf16x8*)&Kt[wc*16+fr][kc*8 + ks*32];
      accA = __builtin_amdgcn_mfma_f32_16x16x32_bf16(a, bb, accA, 0, 0, 0);
      bf16x8 a2 = *(const bf16x8*)&Ru[wr*16+fr][kc*8 + ks*32];
      bf16x8 b2 = *(const bf16x8*)&kS[wc*16+fr][kc*8 + ks*32];
      accD = __builtin_amdgcn_mfma_f32_16x16x32_bf16(a2, b2, accD, 0, 0, 0);
    }
    #pragma unroll
    for (int q = 0; q < 4; ++q) {
      int trow = wr*16 + kc*4 + q;
      int scol = wc*16 + fr;
      float val = (scol < trow) ? accA[q] : ((scol == trow) ? accD[q] : 0.f);
      A_lds[trow][scol] = f2b(val);
    }
  }
  __syncthreads();

  #pragma unroll
  for (int tb = 0; tb < 2; ++tb) {
    bf16x8 a  = *(const bf16x8*)&A_lds[tb*16+fr][kc*8];
    bf16x8 bb = *(const bf16x8*)&VT[wv*16+fr][kc*8];
    f32x4 acc = {0.f,0.f,0.f,0.f};
    acc = __builtin_amdgcn_mfma_f32_16x16x32_bf16(a, bb, acc, 0, 0, 0);
    #pragma unroll
    for (int q = 0; q < 4; ++q) {
      int t = tb*16 + kc*4 + q;
      int j = wv*16 + fr;
      y[rowbase + (size_t)t*Cc + j] = acc[q];
    }
  }
  #pragma unroll
  for (int jb = 0; jb < 4; ++jb) {
    bf16x8 a  = *(const bf16x8*)&KhT[wv*16+fr][kc*8];
    bf16x8 bb = *(const bf16x8*)&VT[jb*16+fr][kc*8];
    f32x4 acc = {0.f,0.f,0.f,0.f};
    acc = __builtin_amdgcn_mfma_f32_16x16x32_bf16(a, bb, acc, 0, 0, 0);
    #pragma unroll
    for (int q = 0; q < 4; ++q) {
      int i = wv*16 + kc*4 + q;
      int j = jb*16 + fr;
      S[((size_t)blk*64 + i)*64 + j] = f2b(acc[q]);
    }
  }
  {
    int tt = tid >> 3, c8 = (tid & 7)*8;
    *(uint4*)(r + rowbase + (size_t)tt*Cc + c8) = *(const uint4*)&Rt[tt][c8];
  }
}

// ---------------- WKV6 pass 2: cross-chunk state propagation (in-place) ----------------
__global__ __launch_bounds__(256) void wkv_pass2(u16* __restrict__ S,
    const float* __restrict__ D)
{
  __shared__ float Dl[NCH][64];
  const int bh = blockIdx.x;
  const int tid = threadIdx.x;
  {
    const float4* src = (const float4*)(D + (size_t)bh*NCH*64);
    float4* dst = (float4*)&Dl[0][0];
    dst[tid] = src[tid];
    dst[tid + 256] = src[tid + 256];
  }
  __syncthreads();
  const int j = tid & 63, i0 = (tid >> 6)*16;
  float Sr[16];
  #pragma unroll
  for (int ii = 0; ii < 16; ++ii) Sr[ii] = 0.f;
  for (int c = 0; c < NCH; ++c) {
    size_t base = (((size_t)bh*NCH + c)*64 + i0)*64 + j;
    u16 tmp[16];
    #pragma unroll
    for (int ii = 0; ii < 16; ++ii) tmp[ii] = S[base + ii*64];
    #pragma unroll
    for (int ii = 0; ii < 16; ++ii) S[base + ii*64] = f2b(Sr[ii]);
    #pragma unroll
    for (int ii = 0; ii < 16; ++ii) Sr[ii] = fmaf(Sr[ii], Dl[c][i0+ii], b2f(tmp[ii]));
  }
}

// ---------------- GroupNorm(H) + correction + gate, 8 rows/block ----------------
__global__ __launch_bounds__(256) void gn_gate(const float* __restrict__ y,
   const u16* __restrict__ g, const u16* __restrict__ rc, const u16* __restrict__ S,
   const float* __restrict__ gamma, const float* __restrict__ beta, u16* __restrict__ out)
{
  __shared__ u16 rcl[8][Cc];
  const int bt0 = blockIdx.x * 8;
  const int b = bt0 >> 10;
  const int t0 = bt0 & (Tt-1);
  const int chunk = t0 >> 5;
  const int tid = threadIdx.x;
  #pragma unroll
  for (int rr = 0; rr < 8; ++rr)
    ((ushort4*)rcl[rr])[tid] = ((const ushort4*)(rc + (size_t)(bt0+rr)*Cc))[tid];
  __syncthreads();
  const int c0 = tid*4, h = c0 >> 6, j0 = c0 & 63;
  const u16* Sb = S + (((size_t)(b*Hh + h)*NCH + chunk)*64)*64 + j0;
  float corr[8][4];
  #pragma unroll
  for (int rr = 0; rr < 8; ++rr)
    #pragma unroll
    for (int q = 0; q < 4; ++q) corr[rr][q] = 0.f;
  #pragma unroll 4
  for (int i = 0; i < 64; ++i) {
    ushort4 sv = *(const ushort4*)(Sb + (size_t)i*64);
    float s0 = b2f(sv.x), s1 = b2f(sv.y), s2 = b2f(sv.z), s3 = b2f(sv.w);
    #pragma unroll
    for (int rr = 0; rr < 8; ++rr) {
      float rv = b2f(rcl[rr][h*64 + i]);
      corr[rr][0] = fmaf(rv, s0, corr[rr][0]);
      corr[rr][1] = fmaf(rv, s1, corr[rr][1]);
      corr[rr][2] = fmaf(rv, s2, corr[rr][2]);
      corr[rr][3] = fmaf(rv, s3, corr[rr][3]);
    }
  }
  float4 ga = ((const float4*)gamma)[tid];
  float4 be = ((const float4*)beta)[tid];
  #pragma unroll
  for (int rr = 0; rr < 8; ++rr) {
    size_t o4 = (size_t)(bt0+rr)*(Cc/4) + tid;
    float4 yv = ((const float4*)y)[o4];
    yv.x += corr[rr][0]; yv.y += corr[rr][1]; yv.z += corr[rr][2]; yv.w += corr[rr][3];
    float s  = yv.x + yv.y + yv.z + yv.w;
    float sq = yv.x*yv.x + yv.y*yv.y + yv.z*yv.z + yv.w*yv.w;
    #pragma unroll
    for (int m = 1; m < 16; m <<= 1) {
      s  += __shfl_xor(s, m, 64);
      sq += __shfl_xor(sq, m, 64);
    }
    float mu  = s * (1.f/64.f);
    float var = sq * (1.f/64.f) - mu*mu;
    float rstd = rsqrtf(var + 6.4e-4f);
    ushort4 gu = ((const ushort4*)g)[o4];
    ushort4 ou;
    ou.x = f2b(((yv.x - mu)*rstd*ga.x + be.x) * b2f(gu.x));
    ou.y = f2b(((yv.y - mu)*rstd*ga.y + be.y) * b2f(gu.y));
    ou.z = f2b(((yv.z - mu)*rstd*ga.z + be.z) * b2f(gu.z));
    ou.w = f2b(((yv.w - mu)*rstd*ga.w + be.w) * b2f(gu.w));
    ((ushort4*)out)[o4] = ou;
  }
}

extern "C" void kernel_launch(void* const* d_in, const int* in_sizes, int n_in,
                              void* d_out, int out_size, void* d_ws, size_t ws_size,
                              hipStream_t stream) {
  const float* x      = (const float*)d_in[0];
  const float* maa_x  = (const float*)d_in[1];
  const float* maa_w  = (const float*)d_in[2];
  const float* maa_k  = (const float*)d_in[3];
  const float* maa_v  = (const float*)d_in[4];
  const float* maa_r  = (const float*)d_in[5];
  const float* maa_g  = (const float*)d_in[6];
  const float* w1     = (const float*)d_in[7];
  const float* w2     = (const float*)d_in[8];
  const float* tdecay = (const float*)d_in[9];
  const float* tdw1   = (const float*)d_in[10];
  const float* tdw2   = (const float*)d_in[11];
  const float* faaaa  = (const float*)d_in[12];
  const float* Wr     = (const float*)d_in[13];
  const float* Wk     = (const float*)d_in[14];
  const float* Wv     = (const float*)d_in[15];
  const float* Wg     = (const float*)d_in[16];
  const float* Wo     = (const float*)d_in[17];
  const float* gamma  = (const float*)d_in[18];
  const float* beta   = (const float*)d_in[19];
  float* out = (float*)d_out;

  const size_t MB = 1u << 20;
  char* wsb = (char*)d_ws;
  float* ewb  = (float*)(wsb + 0);            // 16M exp(wval) (step5->7); m1p/w2T overlap, dead by then
  float* m1p  = (float*)(wsb + 0);            // 10.5M fp32 m1 k-partials (step2->3)
  u16*   w2T  = (u16*)(wsb + 12*MB);          // 320K bf16 w2 transposed (step0->3)
  u16*   xk   = (u16*)(wsb + 16*MB);          // 8M
  u16*   xv   = (u16*)(wsb + 24*MB);          // 8M
  u16*   xr   = (u16*)(wsb + 32*MB);          // 8M -> gated
  u16*   xg   = (u16*)(wsb + 40*MB);          // 8M
  u16*   xw   = (u16*)(wsb + 48*MB);          // 8M (dead after wl1)
  u16*   rbuf = (u16*)(wsb + 56*MB);          // 8M (r -> rc in-place)
  float* wl1p = (float*)(wsb + 56*MB);        // 4M fp32 wl1 k-partials (dead before rbuf write)
  u16*   kbuf = (u16*)(wsb + 64*MB);          // 8M
  u16*   vbuf = (u16*)(wsb + 72*MB);          // 8M
  u16*   gbuf = (u16*)(wsb + 80*MB);          // 8M
  float* Dbuf = (float*)(wsb + 88*MB);        // 512K
  u16*   Sbuf = (u16*)(wsb + 16*MB);          // 16M over xk+xv (dead by pass1)
  u16*   BW0  = (u16*)(wsb + 88*MB + 512*1024);
  u16*   BW1  = (u16*)((char*)BW0 + 2*MB);
  u16*   BW2  = (u16*)((char*)BW1 + 2*MB);
  u16*   BW3  = (u16*)((char*)BW2 + 2*MB);
  u16*   BW4  = (u16*)((char*)BW3 + 2*MB);    // ends 98.5M
  u16*   w1T  = (u16*)((char*)BW4 + 2*MB);    // 320K
  u16*   tdw1T = (u16*)(wsb + 99*MB);
  u16*   tdw2T = (u16*)(wsb + 99*MB + 256*1024);
  u16*   gated = xr;
  u16*   xxx16 = (u16*)d_out;
  float* ybuf  = (float*)d_out;

  dim3 blk(256);
  // 0. transpose+convert weights to bf16 [N][K] (incl. w2 -> w2T)
  WPack wp;
  wp.p[0] = {Wr, BW0, Cc, Cc};  wp.p[1] = {Wk, BW1, Cc, Cc};
  wp.p[2] = {Wv, BW2, Cc, Cc};  wp.p[3] = {Wg, BW3, Cc, Cc};
  wp.p[4] = {Wo, BW4, Cc, Cc};  wp.p[5] = {w1, w1T, Cc, 160};
  wp.p[6] = {tdw1, tdw1T, Cc, 64}; wp.p[7] = {tdw2, tdw2T, 64, Cc};
  wp.p[8] = {w2, w2T, 160, Cc};
  transW<<<dim3(32,32,9), blk, 0, stream>>>(wp);
  // 1. xxx (bf16) -> d_out
  prep_xxx<<<BT*Cc/4/256, blk, 0, stream>>>(x, maa_x, xxx16);
  // 2. m1 partials = xxx @ w1 (K-split z=4, fp32; tanh applied in mix_mfma)
  gemm_ksplit<<<dim3(2, 32, 4), blk, 0, stream>>>(xxx16, w1T, m1p, Cc, 256, 160);
  // 3. fused MFMA mix -> xw,xk,xv,xr,xg (all bf16)
  mix_mfma<<<1024, blk, 0, stream>>>(x, m1p, w2T, maa_w, maa_k, maa_v, maa_r, maa_g,
                                     xw, xk, xv, xr, xg);
  // 4. wl1 partials = xw @ tdw1 (K-split z=4, fp32; tanh applied in gemm_ew64)
  gemm_ksplit<<<dim3(1, 32, 4), blk, 0, stream>>>(xw, tdw1T, wl1p, Cc, 256, 64);
  // 5. ew = exp(tanh(sum wl1p) @ tdw2 + tdecay) -> fp32 (no-LDS K=64 GEMM)
  gemm_ew64<<<dim3(8, 32), blk, 0, stream>>>(wl1p, tdw2T, tdecay, ewb);
  // 6. r,k,v,g batched — 256x256 2-phase/K-tile kernel, 256 blocks
  GPack gp;
  gp.A[0] = xr; gp.A[1] = xk; gp.A[2] = xv; gp.A[3] = xg;
  gp.B[0] = BW0; gp.B[1] = BW1; gp.B[2] = BW2; gp.B[3] = BW3;
  gp.C[0] = rbuf; gp.C[1] = kbuf; gp.C[2] = vbuf; gp.C[3] = gbuf;
  gemm_rkvg256<<<dim3(4, 16, 4), dim3(512), 0, stream>>>(gp);
  // 7. wkv chunked scan (MFMA formulation)
  wkv_pass1<<<Bb*Hh*NCH, blk, 0, stream>>>(rbuf, kbuf, vbuf, ewb, faaaa, ybuf, Sbuf, Dbuf);
  wkv_pass2<<<Bb*Hh, blk, 0, stream>>>(Sbuf, Dbuf);
  // 8. groupnorm + correction + gate
  gn_gate<<<BT/8, blk, 0, stream>>>(ybuf, gbuf, rbuf, Sbuf, gamma, beta, gated);
  // 9. out = gated @ Wo (fp32)
  gemm_mfma<0,true><<<dim3(8, 32), blk, 0, stream>>>(gated, BW4, out, nullptr, Cc, Cc);
}

// Round 6
// 200.256 us; speedup vs baseline: 1.0021x; 1.0021x over previous
//
#include <hip/hip_runtime.h>

#define Bb 4
#define Tt 1024
#define Cc 1024
#define Hh 16
#define BT (Bb*Tt)
#define CHUNK 32
#define NCH (Tt/CHUNK)

typedef unsigned int uint;
typedef unsigned short u16;
typedef __bf16 bf16x8 __attribute__((ext_vector_type(8)));
typedef float f32x4 __attribute__((ext_vector_type(4)));
typedef const __attribute__((address_space(1))) uint GU;
typedef __attribute__((address_space(3))) uint LU;

__device__ __forceinline__ float blo(uint u) { return __uint_as_float(u << 16); }
__device__ __forceinline__ float bhi(uint u) { return __uint_as_float(u & 0xffff0000u); }
__device__ __forceinline__ float b2f(u16 u) { return __uint_as_float(((uint)u) << 16); }
__device__ __forceinline__ u16 f2b(float f) {
  uint u = __float_as_uint(f);
  return (u16)((u + 0x7fffu + ((u >> 16) & 1u)) >> 16);   // RNE
}
// fast tanh: 1 - 2/(e^{2x}+1); exact limits at +-inf, rel err ~2^-21
__device__ __forceinline__ float fast_tanh(float x) {
  float e = __expf(2.f * x);
  return 1.f - 2.f / (e + 1.f);
}

// ---------------- prep: xxx = bf16(x + (shift(x)-x)*maa_x) ----------------
__global__ __launch_bounds__(256) void prep_xxx(const float* __restrict__ x,
    const float* __restrict__ maa_x, u16* __restrict__ xxx)
{
  int idx = blockIdx.x*256 + threadIdx.x;
  int c4 = idx & 255;
  int bt = idx >> 8;
  int t = bt & (Tt-1);
  float4 xc = ((const float4*)x)[idx];
  float4 xp = make_float4(0.f,0.f,0.f,0.f);
  if (t > 0) xp = ((const float4*)x)[idx - 256];
  float4 mx = ((const float4*)maa_x)[c4];
  ushort4 o;
  o.x = f2b(fmaf(xp.x - xc.x, mx.x, xc.x));
  o.y = f2b(fmaf(xp.y - xc.y, mx.y, xc.y));
  o.z = f2b(fmaf(xp.z - xc.z, mx.z, xc.z));
  o.w = f2b(fmaf(xp.w - xc.w, mx.w, xc.w));
  ((ushort4*)xxx)[idx] = o;
}

// ---------------- fused mix: MFMA (tanh Σ m1-partials)@w2 + epilogue ----------
// Epilogue coalesced via per-wave LDS strip [16][72] (16B-aligned rows, wave-
// private so no barriers): scatter o16 by fragment layout, then 2x 1KB
// dwordx4 store rounds per field. Replaces 16 scattered u16 stores/field.
__global__ __launch_bounds__(256) void mix_mfma(
    const float* __restrict__ x, const float* __restrict__ m1p,
    const u16* __restrict__ w2T,
    const float* __restrict__ maa_w, const float* __restrict__ maa_k,
    const float* __restrict__ maa_v, const float* __restrict__ maa_r,
    const float* __restrict__ maa_g,
    u16* __restrict__ xw, u16* __restrict__ xk, u16* __restrict__ xv,
    u16* __restrict__ xr, u16* __restrict__ xg)
{
  __shared__ __align__(16) u16 strip[4][16][72];
  const int tid = threadIdx.x;
  const int lane = tid & 63;
  const int wv = tid >> 6;
  const int sid = blockIdx.x*4 + wv;        // 4096 strips, row-major
  const int rs = sid >> 4, cs = sid & 15;
  const int r0 = rs*16, c0 = cs*64;
  const int fr = lane & 15, kc = lane >> 4;

  float xc[4][4], xd[4][4];
  #pragma unroll
  for (int n = 0; n < 4; ++n) {
    int col = c0 + n*16 + fr;
    #pragma unroll
    for (int q = 0; q < 4; ++q) {
      int row = r0 + kc*4 + q;
      size_t o = (size_t)row*Cc + col;
      float v = x[o];
      float p = ((row & (Tt-1)) != 0) ? x[o - Cc] : 0.f;
      xc[n][q] = v;
      xd[n][q] = p - v;
    }
  }

  const size_t aBase = (size_t)(r0 + fr)*160 + kc*8;
  u16* const outs[5] = {xw, xk, xv, xr, xg};
  const float* const maas[5] = {maa_w, maa_k, maa_v, maa_r, maa_g};

  #pragma unroll
  for (int f = 0; f < 5; ++f) {
    float s8[8] = {0.f,0.f,0.f,0.f,0.f,0.f,0.f,0.f};
    #pragma unroll
    for (int z = 0; z < 4; ++z) {
      const float4* p = (const float4*)(m1p + (size_t)z*655360 + aBase + f*32);
      float4 a = p[0], b = p[1];
      s8[0]+=a.x; s8[1]+=a.y; s8[2]+=a.z; s8[3]+=a.w;
      s8[4]+=b.x; s8[5]+=b.y; s8[6]+=b.z; s8[7]+=b.w;
    }
    u16 t8[8];
    #pragma unroll
    for (int j = 0; j < 8; ++j) t8[j] = f2b(fast_tanh(s8[j]));
    bf16x8 af = *(const bf16x8*)t8;
    f32x4 acc[4];
    #pragma unroll
    for (int n = 0; n < 4; ++n) {
      bf16x8 bg = *(const bf16x8*)(w2T + (size_t)(c0 + n*16 + fr)*160 + f*32 + kc*8);
      acc[n] = __builtin_amdgcn_mfma_f32_16x16x32_bf16(af, bg, f32x4{0.f,0.f,0.f,0.f}, 0, 0, 0);
    }
    const float* __restrict__ ma = maas[f];
    u16* __restrict__ op = outs[f];
    // scatter into wave-private strip (fragment layout)
    #pragma unroll
    for (int n = 0; n < 4; ++n) {
      int colL = n*16 + fr;
      float mv = ma[c0 + colL];
      #pragma unroll
      for (int q = 0; q < 4; ++q)
        strip[wv][kc*4 + q][colL] = f2b(fmaf(xd[n][q], mv + acc[n][q], xc[n][q]));
    }
    // coalesced flush: 2 rounds x (8 rows x 128B) = 1KB dwordx4 per round
    #pragma unroll
    for (int rd = 0; rd < 2; ++rd) {
      int r8 = (lane >> 3) + rd*8;
      uint4 v = *(const uint4*)&strip[wv][r8][(lane & 7)*8];
      *(uint4*)(op + (size_t)(r0 + r8)*Cc + c0 + (lane & 7)*8) = v;
    }
  }
}

// ---------------- weight transpose+convert: dst[n][k] = bf16(src[k][n]) ----------------
struct WPair { const float* s; u16* d; int K; int N; };
struct WPack { WPair p[9]; };

__global__ __launch_bounds__(256) void transW(WPack wp) {
  WPair pr = wp.p[blockIdx.z];
  int c0 = blockIdx.x*32, r0 = blockIdx.y*32;
  if (c0 >= pr.N || r0 >= pr.K) return;
  __shared__ float tile[32][33];
  int tc = threadIdx.x & 31, tr = threadIdx.x >> 5;
  #pragma unroll
  for (int p = 0; p < 4; ++p)
    tile[tr + p*8][tc] = pr.s[(size_t)(r0 + tr + p*8)*pr.N + c0 + tc];
  __syncthreads();
  #pragma unroll
  for (int p = 0; p < 4; ++p) {
    int n = tr + p*8;
    pr.d[(size_t)(c0 + n)*pr.K + r0 + tc] = f2b(tile[tc][n]);
  }
}

// ---------------- bf16 MFMA GEMM core (m97 structure + chunk swizzle) ----------------
// ld: row stride (elems) of A and Bt; kloop: K extent to accumulate (<= ld).
template<bool OUTF32>
__device__ __forceinline__ void mfma_core(
    const u16* __restrict__ A, const u16* __restrict__ Bt,
    void* __restrict__ Cout, const float* __restrict__ bias,
    int ld, int kloop, int N, int act)
{
  __shared__ __align__(16) u16 lds[2][2][128*32];   // 32 KB
  const int tid = threadIdx.x;
  const int lane = tid & 63;
  const int wv = __builtin_amdgcn_readfirstlane(tid >> 6);

  // bijective XCD swizzle (requires gridDim.y % 8 == 0)
  const int nby8 = gridDim.y >> 3;
  const int i_lin = blockIdx.y * gridDim.x + blockIdx.x;
  const int cx = i_lin & 7, rest = i_lin >> 3;
  const int bm = (cx * nby8 + rest % nby8) * 128;
  const int bn = (rest / nby8) * 128;

  const int wm = (wv >> 1) * 64;
  const int wn = (wv & 1) * 64;
  const int kc = lane >> 4;
  const int fr = lane & 15;

  const int srow = wv*16 + (lane >> 2);
  const int ssw  = (srow >> 1) & 3;                 // == s(srow+64)
  const int scol = ((lane & 3) ^ ssw) * 8;
  const size_t aoff = (size_t)(bm + srow) * ld + scol;
  const size_t boff = (size_t)(bn + srow) * ld + scol;

#define STAGE(bufi, kt) do { \
    size_t ko_ = (size_t)(kt) * 32; \
    __builtin_amdgcn_global_load_lds((GU*)(A + aoff + ko_), \
        (LU*)&lds[bufi][0][wv*512], 16, 0, 0); \
    __builtin_amdgcn_global_load_lds((GU*)(A + aoff + (size_t)64*ld + ko_), \
        (LU*)&lds[bufi][0][wv*512 + 64*32], 16, 0, 0); \
    __builtin_amdgcn_global_load_lds((GU*)(Bt + boff + ko_), \
        (LU*)&lds[bufi][1][wv*512], 16, 0, 0); \
    __builtin_amdgcn_global_load_lds((GU*)(Bt + boff + (size_t)64*ld + ko_), \
        (LU*)&lds[bufi][1][wv*512 + 64*32], 16, 0, 0); \
  } while(0)

  int ard[4], brd[4];
  #pragma unroll
  for (int m = 0; m < 4; ++m) {
    int ra = wm + m*16 + fr;
    int rb = wn + m*16 + fr;
    ard[m] = ra*32 + (kc ^ ((ra >> 1) & 3))*8;
    brd[m] = rb*32 + (kc ^ ((rb >> 1) & 3))*8;
  }

  f32x4 acc[4][4];
  #pragma unroll
  for (int m = 0; m < 4; ++m)
    #pragma unroll
    for (int n = 0; n < 4; ++n)
      acc[m][n] = f32x4{0.f, 0.f, 0.f, 0.f};

  const int NK = kloop >> 5;
  STAGE(0, 0);
  __syncthreads();
  int buf = 0;
  for (int kt = 0; kt < NK; ++kt) {
    if (kt + 1 < NK) STAGE(buf^1, kt+1);
    bf16x8 af[4], bg[4];
    #pragma unroll
    for (int m = 0; m < 4; ++m) af[m] = *(const bf16x8*)&lds[buf][0][ard[m]];
    #pragma unroll
    for (int n = 0; n < 4; ++n) bg[n] = *(const bf16x8*)&lds[buf][1][brd[n]];
    #pragma unroll
    for (int m = 0; m < 4; ++m)
      #pragma unroll
      for (int n = 0; n < 4; ++n)
        acc[m][n] = __builtin_amdgcn_mfma_f32_16x16x32_bf16(af[m], bg[n], acc[m][n], 0, 0, 0);
    __syncthreads();
    buf ^= 1;
  }
#undef STAGE

  const int orow = bm + wm + (lane >> 4) * 4;
  const int ocol = bn + wn + fr;
  #pragma unroll
  for (int m = 0; m < 4; ++m) {
    #pragma unroll
    for (int n = 0; n < 4; ++n) {
      int col = ocol + n*16;
      if (col < N) {
        float bs = bias ? bias[col] : 0.f;
        #pragma unroll
        for (int q = 0; q < 4; ++q) {
          float vv = acc[m][n][q] + bs;
          if (act == 1) vv = tanhf(vv);
          else if (act == 2) vv = vv / (1.f + __expf(-vv));
          else if (act == 3) vv = __expf(-__expf(vv));
          else if (act == 4) vv = __expf(vv);
          size_t off = (size_t)(orow + m*16 + q) * N + col;
          if (OUTF32) ((float*)Cout)[off] = vv;
          else ((u16*)Cout)[off] = f2b(vv);
        }
      }
    }
  }
}

template<int ACT, bool OUTF32>
__global__ __launch_bounds__(256) void gemm_mfma(
    const u16* __restrict__ A, const u16* __restrict__ Bt,
    void* __restrict__ Cout, const float* __restrict__ bias, int K, int N)
{
  mfma_core<OUTF32>(A, Bt, Cout, bias, K, K, N, ACT);
}

// K-split GEMM: z-th block-slab accumulates k in [z*ksz, (z+1)*ksz), writes
// raw fp32 partials to Cp + z*4096*N. No activation (applied at consumer).
__global__ __launch_bounds__(256) void gemm_ksplit(
    const u16* __restrict__ A, const u16* __restrict__ Bt,
    float* __restrict__ Cp, int ld, int ksz, int N)
{
  const int z = blockIdx.z;
  mfma_core<true>(A + (size_t)z*ksz, Bt + (size_t)z*ksz,
                  Cp + (size_t)z*4096*N, nullptr, ld, ksz, N, 0);
}

// ---------------- ew = exp(tanh(sum wl1p)@tdw2T^T + tdecay), K=64, no LDS ----
__global__ __launch_bounds__(256) void gemm_ew64(
    const float* __restrict__ wl1p, const u16* __restrict__ Bt,
    const float* __restrict__ tdecay, float* __restrict__ ew)
{
  const int tid = threadIdx.x;
  const int lane = tid & 63;
  const int wv = tid >> 6;
  const int nby8 = gridDim.y >> 3;
  const int i_lin = blockIdx.y * gridDim.x + blockIdx.x;
  const int cx = i_lin & 7, rest = i_lin >> 3;
  const int bm = (cx * nby8 + rest % nby8) * 128;
  const int bn = (rest / nby8) * 128;
  const int wm = (wv >> 1) * 64;
  const int wn = (wv & 1) * 64;
  const int kc = lane >> 4;
  const int fr = lane & 15;

  bf16x8 af[4][2];
  #pragma unroll
  for (int m = 0; m < 4; ++m) {
    int row = bm + wm + m*16 + fr;
    #pragma unroll
    for (int ks = 0; ks < 2; ++ks) {
      size_t base = (size_t)row*64 + ks*32 + kc*8;
      float s8[8] = {0.f,0.f,0.f,0.f,0.f,0.f,0.f,0.f};
      #pragma unroll
      for (int z = 0; z < 4; ++z) {
        const float4* p = (const float4*)(wl1p + (size_t)z*262144 + base);
        float4 a = p[0], b = p[1];
        s8[0]+=a.x; s8[1]+=a.y; s8[2]+=a.z; s8[3]+=a.w;
        s8[4]+=b.x; s8[5]+=b.y; s8[6]+=b.z; s8[7]+=b.w;
      }
      u16 t8[8];
      #pragma unroll
      for (int j = 0; j < 8; ++j) t8[j] = f2b(fast_tanh(s8[j]));
      af[m][ks] = *(const bf16x8*)t8;
    }
  }

  f32x4 acc[4][4];
  #pragma unroll
  for (int m = 0; m < 4; ++m)
    #pragma unroll
    for (int n = 0; n < 4; ++n)
      acc[m][n] = f32x4{0.f,0.f,0.f,0.f};

  #pragma unroll
  for (int ks = 0; ks < 2; ++ks) {
    bf16x8 bg[4];
    #pragma unroll
    for (int n = 0; n < 4; ++n)
      bg[n] = *(const bf16x8*)(Bt + (size_t)(bn + wn + n*16 + fr)*64 + ks*32 + kc*8);
    #pragma unroll
    for (int m = 0; m < 4; ++m)
      #pragma unroll
      for (int n = 0; n < 4; ++n)
        acc[m][n] = __builtin_amdgcn_mfma_f32_16x16x32_bf16(af[m][ks], bg[n], acc[m][n], 0, 0, 0);
  }

  const int orow = bm + wm + kc*4;
  const int ocol = bn + wn + fr;
  #pragma unroll
  for (int n = 0; n < 4; ++n) {
    int col = ocol + n*16;
    float bs = tdecay[col];
    #pragma unroll
    for (int m = 0; m < 4; ++m)
      #pragma unroll
      for (int q = 0; q < 4; ++q)
        ew[(size_t)(orow + m*16 + q)*Cc + col] = __expf(acc[m][n][q] + bs);
  }
}

// ---------------- 256x256 8-phase GEMM for the big batched r/k/v/g GEMMs ----------------
// (round-2/3 verified 4-phase version: best-measured config, 41.5 us, 0 conflicts)
struct GPack { const u16* A[4]; const u16* B[4]; u16* C[4]; };

#define VMW(n) asm volatile("s_waitcnt vmcnt(" #n ")" ::: "memory")
#define LGKM0() asm volatile("s_waitcnt lgkmcnt(0)" ::: "memory")
#define SCHB() __builtin_amdgcn_sched_barrier(0)
#define HBAR() __builtin_amdgcn_s_barrier()

__global__ __launch_bounds__(512) void gemm_rkvg256(GPack gp) {
  __shared__ __align__(16) u16 lds[2][2][2][8192];   // [dbuf][A/B][khalf][256*32] = 128 KB
  const int z = blockIdx.z;
  const u16* __restrict__ Ap  = gp.A[z];
  const u16* __restrict__ Btp = gp.B[z];
  u16* __restrict__ Cp = gp.C[z];
  const int act = (z == 3) ? 2 : 0;

  const int tid = threadIdx.x;
  const int lane = tid & 63;
  const int wv = __builtin_amdgcn_readfirstlane(tid >> 6);

  const int i_lin = blockIdx.y * gridDim.x + blockIdx.x;   // 0..63
  const int tile = (i_lin & 7) * 8 + (i_lin >> 3);
  const int bm = (tile >> 2) * 256;
  const int bn = (tile & 3) * 256;

  const int wm = (wv >> 2) * 128;    // 2 wave-rows of 128
  const int wn = (wv & 3) * 64;      // 4 wave-cols of 64
  const int kc = lane >> 4;
  const int fr = lane & 15;

  const int srow0 = (wv*2 + 0)*16 + (lane >> 2);
  const int srow1 = (wv*2 + 1)*16 + (lane >> 2);
  const int sc0 = ((lane & 3) ^ ((srow0 >> 1) & 3)) * 8;
  const int sc1 = ((lane & 3) ^ ((srow1 >> 1) & 3)) * 8;
  const size_t aoff0 = (size_t)(bm + srow0)*Cc + sc0;
  const size_t aoff1 = (size_t)(bm + srow1)*Cc + sc1;
  const size_t boff0 = (size_t)(bn + srow0)*Cc + sc0;
  const size_t boff1 = (size_t)(bn + srow1)*Cc + sc1;

  int ard[8], brd[4];
  #pragma unroll
  for (int mh = 0; mh < 2; ++mh)
    #pragma unroll
    for (int mf = 0; mf < 4; ++mf) {
      int r = wm + mh*64 + mf*16 + fr;
      ard[mh*4+mf] = r*32 + (kc ^ ((r >> 1) & 3))*8;
    }
  #pragma unroll
  for (int nf = 0; nf < 4; ++nf) {
    int r = wn + nf*16 + fr;
    brd[nf] = r*32 + (kc ^ ((r >> 1) & 3))*8;
  }

  f32x4 acc[8][4];
  #pragma unroll
  for (int m = 0; m < 8; ++m)
    #pragma unroll
    for (int n = 0; n < 4; ++n)
      acc[m][n] = f32x4{0.f, 0.f, 0.f, 0.f};

#define STG256(DB, MAT, KH, kt, off0, off1, src) do { \
    u16* dst_ = &lds[(DB)][(MAT)][(KH)][wv*1024]; \
    __builtin_amdgcn_global_load_lds((GU*)((src) + (off0) + (size_t)(kt)*64 + (KH)*32), \
        (LU*)dst_, 16, 0, 0); \
    __builtin_amdgcn_global_load_lds((GU*)((src) + (off1) + (size_t)(kt)*64 + (KH)*32), \
        (LU*)(dst_ + 512), 16, 0, 0); \
  } while(0)

#define PH256(cur, KH, MH, LOADB, STMAT, STKH, DOSTAGE, VMTOK) do { \
    _Pragma("unroll") \
    for (int mf = 0; mf < 4; ++mf) \
      af[mf] = *(const bf16x8*)&lds[(cur)][0][KH][ard[(MH)*4+mf]]; \
    if (LOADB) { \
      _Pragma("unroll") \
      for (int nf = 0; nf < 4; ++nf) \
        bg[nf] = *(const bf16x8*)&lds[(cur)][1][KH][brd[nf]]; \
    } \
    if (DOSTAGE) { \
      if ((STMAT) == 0) STG256((cur)^1, 0, STKH, t+1, aoff0, aoff1, Ap); \
      else              STG256((cur)^1, 1, STKH, t+1, boff0, boff1, Btp); \
    } \
    VMTOK; \
    SCHB(); \
    HBAR(); \
    LGKM0(); \
    SCHB(); \
    __builtin_amdgcn_s_setprio(1); \
    _Pragma("unroll") \
    for (int mf = 0; mf < 4; ++mf) \
      _Pragma("unroll") \
      for (int nf = 0; nf < 4; ++nf) \
        acc[(MH)*4+mf][nf] = __builtin_amdgcn_mfma_f32_16x16x32_bf16(af[mf], bg[nf], acc[(MH)*4+mf][nf], 0, 0, 0); \
    __builtin_amdgcn_s_setprio(0); \
    SCHB(); \
    HBAR(); \
  } while(0)

  const int NK = Cc >> 6;   // 16 K-tiles of 64

  STG256(0, 0, 0, 0, aoff0, aoff1, Ap);
  STG256(0, 1, 0, 0, boff0, boff1, Btp);
  STG256(0, 0, 1, 0, aoff0, aoff1, Ap);
  STG256(0, 1, 1, 0, boff0, boff1, Btp);
  VMW(4);
  SCHB();
  HBAR();

  bf16x8 af[4], bg[4];
  int t;
  #pragma unroll 2
  for (t = 0; t < NK - 1; ++t) {
    const int cur = t & 1;
    PH256(cur, 0, 0, true,  0, 0, true,  (void)0);
    PH256(cur, 0, 1, false, 1, 0, true,  VMW(4));
    PH256(cur, 1, 0, true,  0, 1, true,  (void)0);
    PH256(cur, 1, 1, false, 1, 1, true,  VMW(4));
  }
  { // final K-tile: no prefetch; full drain before its second k-half
    const int cur = t & 1;
    PH256(cur, 0, 0, true,  0, 0, false, (void)0);
    PH256(cur, 0, 1, false, 0, 0, false, VMW(0));
    PH256(cur, 1, 0, true,  0, 0, false, (void)0);
    PH256(cur, 1, 1, false, 0, 0, false, (void)0);
  }
#undef PH256
#undef STG256

  const int orow = bm + wm + (lane >> 4) * 4;
  const int ocol = bn + wn + fr;
  #pragma unroll
  for (int m = 0; m < 8; ++m) {
    #pragma unroll
    for (int nf = 0; nf < 4; ++nf) {
      #pragma unroll
      for (int q = 0; q < 4; ++q) {
        float vv = acc[m][nf][q];
        if (act == 2) vv = vv / (1.f + __expf(-vv));
        Cp[(size_t)(orow + (m >> 2)*64 + (m & 3)*16 + q) * Cc + ocol + nf*16] = f2b(vv);
      }
    }
  }
}

// ---------------- WKV6 pass 1: chunked matmul formulation (MFMA) ----------------
// y output now bf16 (consumed by gn_gate); cumsum uses 1 exp + rcp per step.
__global__ __launch_bounds__(256) void wkv_pass1(u16* __restrict__ r,
    const u16* __restrict__ k, const u16* __restrict__ v,
    const float* __restrict__ ew, const float* __restrict__ u,
    u16* __restrict__ y, u16* __restrict__ S, float* __restrict__ D)
{
  __shared__ __align__(16) u16 rS[CHUNK][72];
  __shared__ __align__(16) u16 kS[CHUNK][72];
  __shared__ __align__(16) u16 vS[CHUNK][72];
  __shared__ __align__(16) float bufEW[CHUNK][68];   // ew -> eR (in-place)
  __shared__ __align__(16) float eKnL[CHUNK][68];
  __shared__ __align__(16) u16 Rt[CHUNK][72];
  __shared__ __align__(16) u16 Kt[CHUNK][72];
  __shared__ __align__(16) u16 Ru[CHUNK][72];
  __shared__ __align__(16) u16 KhT[64][40];
  __shared__ __align__(16) u16 VT[64][40];
  __shared__ __align__(16) u16 A_lds[CHUNK][40];
  __shared__ float uL[64];
  __shared__ float Dl[64];

  const int blk = blockIdx.x;
  const int chunk = blk & (NCH-1);
  const int bh = blk >> 5;
  const int h = bh & (Hh-1);
  const int b = bh >> 4;
  const int tid = threadIdx.x;
  const int lane = tid & 63;
  const int wv = tid >> 6;
  const int fr = lane & 15;
  const int kc = lane >> 4;

  const size_t rowbase = ((size_t)(b*Tt + chunk*CHUNK))*Cc + h*64;
  {
    int tt = tid >> 3, c8 = (tid & 7)*8;
    size_t go = rowbase + (size_t)tt*Cc + c8;
    *(uint4*)&rS[tt][c8] = *(const uint4*)(r + go);
    *(uint4*)&kS[tt][c8] = *(const uint4*)(k + go);
    *(uint4*)&vS[tt][c8] = *(const uint4*)(v + go);
    *(float4*)&bufEW[tt][c8]   = *(const float4*)(ew + go);
    *(float4*)&bufEW[tt][c8+4] = *(const float4*)(ew + go + 4);
  }
  if (tid < 64) uL[tid] = u[h*64 + tid];
  __syncthreads();

  if (tid < 64) {
    float eR = 1.f;
    for (int t = 0; t < CHUNK; ++t) {
      float e = bufEW[t][tid];
      bufEW[t][tid] = eR;                         // exp(lw[t-1])
      eR *= __expf(-e);                           // exp(lw[t])
      eKnL[t][tid] = __builtin_amdgcn_rcpf(eR);   // exp(-lw[t])
    }
    Dl[tid] = eR;
    D[(size_t)blk*64 + tid] = eR;
  }
  __syncthreads();

  {
    int t = tid >> 3, i0 = (tid & 7)*8;
    uint4 rv4 = *(const uint4*)&rS[t][i0];
    uint4 kv4 = *(const uint4*)&kS[t][i0];
    const uint* rw = (const uint*)&rv4;
    const uint* kw = (const uint*)&kv4;
    u16 rt8[8], kt8[8], ru8[8];
    #pragma unroll
    for (int q = 0; q < 8; ++q) {
      int i = i0 + q;
      float rv = (q & 1) ? bhi(rw[q>>1]) : blo(rw[q>>1]);
      float kv = (q & 1) ? bhi(kw[q>>1]) : blo(kw[q>>1]);
      float eR = bufEW[t][i];
      float eKn = eKnL[t][i];
      float ktv = kv * eKn;
      rt8[q] = f2b(rv * eR);
      kt8[q] = f2b(ktv);
      ru8[q] = f2b(rv * uL[i]);
      KhT[i][t] = f2b(ktv * Dl[i]);
      VT[i][t] = vS[t][i];
    }
    *(uint4*)&Rt[t][i0] = *(const uint4*)rt8;
    *(uint4*)&Kt[t][i0] = *(const uint4*)kt8;
    *(uint4*)&Ru[t][i0] = *(const uint4*)ru8;
  }
  __syncthreads();

  {
    const int wr = wv >> 1, wc = wv & 1;
    f32x4 accA = {0.f,0.f,0.f,0.f};
    f32x4 accD = {0.f,0.f,0.f,0.f};
    #pragma unroll
    for (int ks = 0; ks < 2; ++ks) {
      bf16x8 a  = *(const bf16x8*)&Rt[wr*16+fr][kc*8 + ks*32];
      bf16x8 bb = *(const bf16x8*)&Kt[wc*16+fr][kc*8 + ks*32];
      accA = __builtin_amdgcn_mfma_f32_16x16x32_bf16(a, bb, accA, 0, 0, 0);
      bf16x8 a2 = *(const bf16x8*)&Ru[wr*16+fr][kc*8 + ks*32];
      bf16x8 b2 = *(const bf16x8*)&kS[wc*16+fr][kc*8 + ks*32];
      accD = __builtin_amdgcn_mfma_f32_16x16x32_bf16(a2, b2, accD, 0, 0, 0);
    }
    #pragma unroll
    for (int q = 0; q < 4; ++q) {
      int trow = wr*16 + kc*4 + q;
      int scol = wc*16 + fr;
      float val = (scol < trow) ? accA[q] : ((scol == trow) ? accD[q] : 0.f);
      A_lds[trow][scol] = f2b(val);
    }
  }
  __syncthreads();

  #pragma unroll
  for (int tb = 0; tb < 2; ++tb) {
    bf16x8 a  = *(const bf16x8*)&A_lds[tb*16+fr][kc*8];
    bf16x8 bb = *(const bf16x8*)&VT[wv*16+fr][kc*8];
    f32x4 acc = {0.f,0.f,0.f,0.f};
    acc = __builtin_amdgcn_mfma_f32_16x16x32_bf16(a, bb, acc, 0, 0, 0);
    #pragma unroll
    for (int q = 0; q < 4; ++q) {
      int t = tb*16 + kc*4 + q;
      int j = wv*16 + fr;
      y[rowbase + (size_t)t*Cc + j] = f2b(acc[q]);
    }
  }
  #pragma unroll
  for (int jb = 0; jb < 4; ++jb) {
    bf16x8 a  = *(const bf16x8*)&KhT[wv*16+fr][kc*8];
    bf16x8 bb = *(const bf16x8*)&VT[jb*16+fr][kc*8];
    f32x4 acc = {0.f,0.f,0.f,0.f};
    acc = __builtin_amdgcn_mfma_f32_16x16x32_bf16(a, bb, acc, 0, 0, 0);
    #pragma unroll
    for (int q = 0; q < 4; ++q) {
      int i = wv*16 + kc*4 + q;
      int j = jb*16 + fr;
      S[((size_t)blk*64 + i)*64 + j] = f2b(acc[q]);
    }
  }
  {
    int tt = tid >> 3, c8 = (tid & 7)*8;
    *(uint4*)(r + rowbase + (size_t)tt*Cc + c8) = *(const uint4*)&Rt[tt][c8];
  }
}

// ---------------- WKV6 pass 2: cross-chunk state propagation (in-place) ----------------
__global__ __launch_bounds__(256) void wkv_pass2(u16* __restrict__ S,
    const float* __restrict__ D)
{
  __shared__ float Dl[NCH][64];
  const int bh = blockIdx.x;
  const int tid = threadIdx.x;
  {
    const float4* src = (const float4*)(D + (size_t)bh*NCH*64);
    float4* dst = (float4*)&Dl[0][0];
    dst[tid] = src[tid];
    dst[tid + 256] = src[tid + 256];
  }
  __syncthreads();
  const int j = tid & 63, i0 = (tid >> 6)*16;
  float Sr[16];
  #pragma unroll
  for (int ii = 0; ii < 16; ++ii) Sr[ii] = 0.f;
  for (int c = 0; c < NCH; ++c) {
    size_t base = (((size_t)bh*NCH + c)*64 + i0)*64 + j;
    u16 tmp[16];
    #pragma unroll
    for (int ii = 0; ii < 16; ++ii) tmp[ii] = S[base + ii*64];
    #pragma unroll
    for (int ii = 0; ii < 16; ++ii) S[base + ii*64] = f2b(Sr[ii]);
    #pragma unroll
    for (int ii = 0; ii < 16; ++ii) Sr[ii] = fmaf(Sr[ii], Dl[c][i0+ii], b2f(tmp[ii]));
  }
}

// ---------------- GroupNorm(H) + correction + gate, 8 rows/block ----------------
__global__ __launch_bounds__(256) void gn_gate(const u16* __restrict__ y,
   const u16* __restrict__ g, const u16* __restrict__ rc, const u16* __restrict__ S,
   const float* __restrict__ gamma, const float* __restrict__ beta, u16* __restrict__ out)
{
  __shared__ u16 rcl[8][Cc];
  const int bt0 = blockIdx.x * 8;
  const int b = bt0 >> 10;
  const int t0 = bt0 & (Tt-1);
  const int chunk = t0 >> 5;
  const int tid = threadIdx.x;
  #pragma unroll
  for (int rr = 0; rr < 8; ++rr)
    ((ushort4*)rcl[rr])[tid] = ((const ushort4*)(rc + (size_t)(bt0+rr)*Cc))[tid];
  __syncthreads();
  const int c0 = tid*4, h = c0 >> 6, j0 = c0 & 63;
  const u16* Sb = S + (((size_t)(b*Hh + h)*NCH + chunk)*64)*64 + j0;
  float corr[8][4];
  #pragma unroll
  for (int rr = 0; rr < 8; ++rr)
    #pragma unroll
    for (int q = 0; q < 4; ++q) corr[rr][q] = 0.f;
  #pragma unroll 4
  for (int i = 0; i < 64; ++i) {
    ushort4 sv = *(const ushort4*)(Sb + (size_t)i*64);
    float s0 = b2f(sv.x), s1 = b2f(sv.y), s2 = b2f(sv.z), s3 = b2f(sv.w);
    #pragma unroll
    for (int rr = 0; rr < 8; ++rr) {
      float rv = b2f(rcl[rr][h*64 + i]);
      corr[rr][0] = fmaf(rv, s0, corr[rr][0]);
      corr[rr][1] = fmaf(rv, s1, corr[rr][1]);
      corr[rr][2] = fmaf(rv, s2, corr[rr][2]);
      corr[rr][3] = fmaf(rv, s3, corr[rr][3]);
    }
  }
  float4 ga = ((const float4*)gamma)[tid];
  float4 be = ((const float4*)beta)[tid];
  #pragma unroll
  for (int rr = 0; rr < 8; ++rr) {
    size_t o4 = (size_t)(bt0+rr)*(Cc/4) + tid;
    ushort4 yv4 = ((const ushort4*)y)[o4];
    float y0 = b2f(yv4.x) + corr[rr][0];
    float y1 = b2f(yv4.y) + corr[rr][1];
    float y2 = b2f(yv4.z) + corr[rr][2];
    float y3 = b2f(yv4.w) + corr[rr][3];
    float s  = y0 + y1 + y2 + y3;
    float sq = y0*y0 + y1*y1 + y2*y2 + y3*y3;
    #pragma unroll
    for (int m = 1; m < 16; m <<= 1) {
      s  += __shfl_xor(s, m, 64);
      sq += __shfl_xor(sq, m, 64);
    }
    float mu  = s * (1.f/64.f);
    float var = sq * (1.f/64.f) - mu*mu;
    float rstd = rsqrtf(var + 6.4e-4f);
    ushort4 gu = ((const ushort4*)g)[o4];
    ushort4 ou;
    ou.x = f2b(((y0 - mu)*rstd*ga.x + be.x) * b2f(gu.x));
    ou.y = f2b(((y1 - mu)*rstd*ga.y + be.y) * b2f(gu.y));
    ou.z = f2b(((y2 - mu)*rstd*ga.z + be.z) * b2f(gu.z));
    ou.w = f2b(((y3 - mu)*rstd*ga.w + be.w) * b2f(gu.w));
    ((ushort4*)out)[o4] = ou;
  }
}

extern "C" void kernel_launch(void* const* d_in, const int* in_sizes, int n_in,
                              void* d_out, int out_size, void* d_ws, size_t ws_size,
                              hipStream_t stream) {
  const float* x      = (const float*)d_in[0];
  const float* maa_x  = (const float*)d_in[1];
  const float* maa_w  = (const float*)d_in[2];
  const float* maa_k  = (const float*)d_in[3];
  const float* maa_v  = (const float*)d_in[4];
  const float* maa_r  = (const float*)d_in[5];
  const float* maa_g  = (const float*)d_in[6];
  const float* w1     = (const float*)d_in[7];
  const float* w2     = (const float*)d_in[8];
  const float* tdecay = (const float*)d_in[9];
  const float* tdw1   = (const float*)d_in[10];
  const float* tdw2   = (const float*)d_in[11];
  const float* faaaa  = (const float*)d_in[12];
  const float* Wr     = (const float*)d_in[13];
  const float* Wk     = (const float*)d_in[14];
  const float* Wv     = (const float*)d_in[15];
  const float* Wg     = (const float*)d_in[16];
  const float* Wo     = (const float*)d_in[17];
  const float* gamma  = (const float*)d_in[18];
  const float* beta   = (const float*)d_in[19];
  float* out = (float*)d_out;

  const size_t MB = 1u << 20;
  char* wsb = (char*)d_ws;
  float* ewb  = (float*)(wsb + 0);            // 16M exp(wval) (step5->7); m1p/w2T overlap, dead by then
  float* m1p  = (float*)(wsb + 0);            // 10.5M fp32 m1 k-partials (step2->3)
  u16*   w2T  = (u16*)(wsb + 12*MB);          // 320K bf16 w2 transposed (step0->3)
  u16*   xk   = (u16*)(wsb + 16*MB);          // 8M
  u16*   xv   = (u16*)(wsb + 24*MB);          // 8M
  u16*   xr   = (u16*)(wsb + 32*MB);          // 8M -> gated
  u16*   xg   = (u16*)(wsb + 40*MB);          // 8M
  u16*   xw   = (u16*)(wsb + 48*MB);          // 8M (dead after wl1)
  u16*   rbuf = (u16*)(wsb + 56*MB);          // 8M (r -> rc in-place)
  float* wl1p = (float*)(wsb + 56*MB);        // 4M fp32 wl1 k-partials (dead before rbuf write)
  u16*   kbuf = (u16*)(wsb + 64*MB);          // 8M
  u16*   vbuf = (u16*)(wsb + 72*MB);          // 8M
  u16*   gbuf = (u16*)(wsb + 80*MB);          // 8M
  float* Dbuf = (float*)(wsb + 88*MB);        // 512K
  u16*   Sbuf = (u16*)(wsb + 16*MB);          // 16M over xk+xv (dead by pass1)
  u16*   BW0  = (u16*)(wsb + 88*MB + 512*1024);
  u16*   BW1  = (u16*)((char*)BW0 + 2*MB);
  u16*   BW2  = (u16*)((char*)BW1 + 2*MB);
  u16*   BW3  = (u16*)((char*)BW2 + 2*MB);
  u16*   BW4  = (u16*)((char*)BW3 + 2*MB);    // ends 98.5M
  u16*   w1T  = (u16*)((char*)BW4 + 2*MB);    // 320K
  u16*   tdw1T = (u16*)(wsb + 99*MB);
  u16*   tdw2T = (u16*)(wsb + 99*MB + 256*1024);
  u16*   gated = xr;
  u16*   xxx16 = (u16*)d_out;
  u16*   yb16  = (u16*)d_out;                 // 8M bf16 y (step7->8)

  dim3 blk(256);
  // 0. transpose+convert weights to bf16 [N][K] (incl. w2 -> w2T)
  WPack wp;
  wp.p[0] = {Wr, BW0, Cc, Cc};  wp.p[1] = {Wk, BW1, Cc, Cc};
  wp.p[2] = {Wv, BW2, Cc, Cc};  wp.p[3] = {Wg, BW3, Cc, Cc};
  wp.p[4] = {Wo, BW4, Cc, Cc};  wp.p[5] = {w1, w1T, Cc, 160};
  wp.p[6] = {tdw1, tdw1T, Cc, 64}; wp.p[7] = {tdw2, tdw2T, 64, Cc};
  wp.p[8] = {w2, w2T, 160, Cc};
  transW<<<dim3(32,32,9), blk, 0, stream>>>(wp);
  // 1. xxx (bf16) -> d_out
  prep_xxx<<<BT*Cc/4/256, blk, 0, stream>>>(x, maa_x, xxx16);
  // 2. m1 partials = xxx @ w1 (K-split z=4, fp32; tanh applied in mix_mfma)
  gemm_ksplit<<<dim3(2, 32, 4), blk, 0, stream>>>(xxx16, w1T, m1p, Cc, 256, 160);
  // 3. fused MFMA mix -> xw,xk,xv,xr,xg (all bf16; coalesced LDS epilogue)
  mix_mfma<<<1024, blk, 0, stream>>>(x, m1p, w2T, maa_w, maa_k, maa_v, maa_r, maa_g,
                                     xw, xk, xv, xr, xg);
  // 4. wl1 partials = xw @ tdw1 (K-split z=4, fp32; tanh applied in gemm_ew64)
  gemm_ksplit<<<dim3(1, 32, 4), blk, 0, stream>>>(xw, tdw1T, wl1p, Cc, 256, 64);
  // 5. ew = exp(tanh(sum wl1p) @ tdw2 + tdecay) -> fp32 (no-LDS K=64 GEMM)
  gemm_ew64<<<dim3(8, 32), blk, 0, stream>>>(wl1p, tdw2T, tdecay, ewb);
  // 6. r,k,v,g batched — 256x256 4-phase kernel (best-measured), 256 blocks
  GPack gp;
  gp.A[0] = xr; gp.A[1] = xk; gp.A[2] = xv; gp.A[3] = xg;
  gp.B[0] = BW0; gp.B[1] = BW1; gp.B[2] = BW2; gp.B[3] = BW3;
  gp.C[0] = rbuf; gp.C[1] = kbuf; gp.C[2] = vbuf; gp.C[3] = gbuf;
  gemm_rkvg256<<<dim3(4, 16, 4), dim3(512), 0, stream>>>(gp);
  // 7. wkv chunked scan (MFMA formulation; y bf16)
  wkv_pass1<<<Bb*Hh*NCH, blk, 0, stream>>>(rbuf, kbuf, vbuf, ewb, faaaa, yb16, Sbuf, Dbuf);
  wkv_pass2<<<Bb*Hh, blk, 0, stream>>>(Sbuf, Dbuf);
  // 8. groupnorm + correction + gate (y bf16 in)
  gn_gate<<<BT/8, blk, 0, stream>>>(yb16, gbuf, rbuf, Sbuf, gamma, beta, gated);
  // 9. out = gated @ Wo (fp32)
  gemm_mfma<0,true><<<dim3(8, 32), blk, 0, stream>>>(gated, BW4, out, nullptr, Cc, Cc);
}

// Round 7
// 188.948 us; speedup vs baseline: 1.0621x; 1.0598x over previous
//
#include <hip/hip_runtime.h>

#define Bb 4
#define Tt 1024
#define Cc 1024
#define Hh 16
#define BT (Bb*Tt)
#define CHUNK 32
#define NCH (Tt/CHUNK)

typedef unsigned int uint;
typedef unsigned short u16;
typedef __bf16 bf16x8 __attribute__((ext_vector_type(8)));
typedef float f32x4 __attribute__((ext_vector_type(4)));
typedef const __attribute__((address_space(1))) uint GU;
typedef __attribute__((address_space(3))) uint LU;

__device__ __forceinline__ float blo(uint u) { return __uint_as_float(u << 16); }
__device__ __forceinline__ float bhi(uint u) { return __uint_as_float(u & 0xffff0000u); }
__device__ __forceinline__ float b2f(u16 u) { return __uint_as_float(((uint)u) << 16); }
__device__ __forceinline__ u16 f2b(float f) {
  uint u = __float_as_uint(f);
  return (u16)((u + 0x7fffu + ((u >> 16) & 1u)) >> 16);   // RNE
}
// fast tanh: 1 - 2/(e^{2x}+1); exact limits at +-inf, rel err ~2^-21
__device__ __forceinline__ float fast_tanh(float x) {
  float e = __expf(2.f * x);
  return 1.f - 2.f / (e + 1.f);
}

// ---------------- merged: weight transpose (z<9) + prep_xxx (z>=9) ----------
// transW and prep are independent producers; one launch lets them co-run.
struct WPair { const float* s; u16* d; int K; int N; };
struct WPack { WPair p[9]; };

__global__ __launch_bounds__(256) void prep_transW(WPack wp,
    const float* __restrict__ x, const float* __restrict__ maa_x,
    u16* __restrict__ xxx)
{
  __shared__ float tile[32][33];
  if (blockIdx.z < 9) {
    WPair pr = wp.p[blockIdx.z];
    int c0 = blockIdx.x*32, r0 = blockIdx.y*32;
    if (c0 >= pr.N || r0 >= pr.K) return;
    int tc = threadIdx.x & 31, tr = threadIdx.x >> 5;
    #pragma unroll
    for (int p = 0; p < 4; ++p)
      tile[tr + p*8][tc] = pr.s[(size_t)(r0 + tr + p*8)*pr.N + c0 + tc];
    __syncthreads();
    #pragma unroll
    for (int p = 0; p < 4; ++p) {
      int n = tr + p*8;
      pr.d[(size_t)(c0 + n)*pr.K + r0 + tc] = f2b(tile[tc][n]);
    }
  } else {
    int vb = (blockIdx.z - 9)*1024 + blockIdx.y*32 + blockIdx.x;  // 0..4095
    int idx = vb*256 + threadIdx.x;
    int c4 = idx & 255;
    int bt = idx >> 8;
    int t = bt & (Tt-1);
    float4 xc = ((const float4*)x)[idx];
    float4 xp = make_float4(0.f,0.f,0.f,0.f);
    if (t > 0) xp = ((const float4*)x)[idx - 256];
    float4 mx = ((const float4*)maa_x)[c4];
    ushort4 o;
    o.x = f2b(fmaf(xp.x - xc.x, mx.x, xc.x));
    o.y = f2b(fmaf(xp.y - xc.y, mx.y, xc.y));
    o.z = f2b(fmaf(xp.z - xc.z, mx.z, xc.z));
    o.w = f2b(fmaf(xp.w - xc.w, mx.w, xc.w));
    ((ushort4*)xxx)[idx] = o;
  }
}

// ---------------- fused mix: MFMA (tanh Σ m1-partials)@w2 + epilogue ----------
__global__ __launch_bounds__(256) void mix_mfma(
    const float* __restrict__ x, const float* __restrict__ m1p,
    const u16* __restrict__ w2T,
    const float* __restrict__ maa_w, const float* __restrict__ maa_k,
    const float* __restrict__ maa_v, const float* __restrict__ maa_r,
    const float* __restrict__ maa_g,
    u16* __restrict__ xw, u16* __restrict__ xk, u16* __restrict__ xv,
    u16* __restrict__ xr, u16* __restrict__ xg)
{
  __shared__ __align__(16) u16 strip[4][16][72];
  const int tid = threadIdx.x;
  const int lane = tid & 63;
  const int wv = tid >> 6;
  const int sid = blockIdx.x*4 + wv;        // 4096 strips, row-major
  const int rs = sid >> 4, cs = sid & 15;
  const int r0 = rs*16, c0 = cs*64;
  const int fr = lane & 15, kc = lane >> 4;

  float xc[4][4], xd[4][4];
  #pragma unroll
  for (int n = 0; n < 4; ++n) {
    int col = c0 + n*16 + fr;
    #pragma unroll
    for (int q = 0; q < 4; ++q) {
      int row = r0 + kc*4 + q;
      size_t o = (size_t)row*Cc + col;
      float v = x[o];
      float p = ((row & (Tt-1)) != 0) ? x[o - Cc] : 0.f;
      xc[n][q] = v;
      xd[n][q] = p - v;
    }
  }

  const size_t aBase = (size_t)(r0 + fr)*160 + kc*8;
  u16* const outs[5] = {xw, xk, xv, xr, xg};
  const float* const maas[5] = {maa_w, maa_k, maa_v, maa_r, maa_g};

  #pragma unroll
  for (int f = 0; f < 5; ++f) {
    float s8[8] = {0.f,0.f,0.f,0.f,0.f,0.f,0.f,0.f};
    #pragma unroll
    for (int z = 0; z < 4; ++z) {
      const float4* p = (const float4*)(m1p + (size_t)z*655360 + aBase + f*32);
      float4 a = p[0], b = p[1];
      s8[0]+=a.x; s8[1]+=a.y; s8[2]+=a.z; s8[3]+=a.w;
      s8[4]+=b.x; s8[5]+=b.y; s8[6]+=b.z; s8[7]+=b.w;
    }
    u16 t8[8];
    #pragma unroll
    for (int j = 0; j < 8; ++j) t8[j] = f2b(fast_tanh(s8[j]));
    bf16x8 af = *(const bf16x8*)t8;
    f32x4 acc[4];
    #pragma unroll
    for (int n = 0; n < 4; ++n) {
      bf16x8 bg = *(const bf16x8*)(w2T + (size_t)(c0 + n*16 + fr)*160 + f*32 + kc*8);
      acc[n] = __builtin_amdgcn_mfma_f32_16x16x32_bf16(af, bg, f32x4{0.f,0.f,0.f,0.f}, 0, 0, 0);
    }
    const float* __restrict__ ma = maas[f];
    u16* __restrict__ op = outs[f];
    #pragma unroll
    for (int n = 0; n < 4; ++n) {
      int colL = n*16 + fr;
      float mv = ma[c0 + colL];
      #pragma unroll
      for (int q = 0; q < 4; ++q)
        strip[wv][kc*4 + q][colL] = f2b(fmaf(xd[n][q], mv + acc[n][q], xc[n][q]));
    }
    #pragma unroll
    for (int rd = 0; rd < 2; ++rd) {
      int r8 = (lane >> 3) + rd*8;
      uint4 v = *(const uint4*)&strip[wv][r8][(lane & 7)*8];
      *(uint4*)(op + (size_t)(r0 + r8)*Cc + c0 + (lane & 7)*8) = v;
    }
  }
}

// ---------------- bf16 MFMA GEMM core (m97 structure + chunk swizzle) ----------------
// ld: row stride (elems) of A and Bt; kloop: K extent to accumulate (<= ld).
template<bool OUTF32>
__device__ __forceinline__ void mfma_core(
    const u16* __restrict__ A, const u16* __restrict__ Bt,
    void* __restrict__ Cout, const float* __restrict__ bias,
    int ld, int kloop, int N, int act)
{
  __shared__ __align__(16) u16 lds[2][2][128*32];   // 32 KB
  const int tid = threadIdx.x;
  const int lane = tid & 63;
  const int wv = __builtin_amdgcn_readfirstlane(tid >> 6);

  // bijective XCD swizzle (requires gridDim.y % 8 == 0)
  const int nby8 = gridDim.y >> 3;
  const int i_lin = blockIdx.y * gridDim.x + blockIdx.x;
  const int cx = i_lin & 7, rest = i_lin >> 3;
  const int bm = (cx * nby8 + rest % nby8) * 128;
  const int bn = (rest / nby8) * 128;

  const int wm = (wv >> 1) * 64;
  const int wn = (wv & 1) * 64;
  const int kc = lane >> 4;
  const int fr = lane & 15;

  const int srow = wv*16 + (lane >> 2);
  const int ssw  = (srow >> 1) & 3;                 // == s(srow+64)
  const int scol = ((lane & 3) ^ ssw) * 8;
  const size_t aoff = (size_t)(bm + srow) * ld + scol;
  const size_t boff = (size_t)(bn + srow) * ld + scol;

#define STAGE(bufi, kt) do { \
    size_t ko_ = (size_t)(kt) * 32; \
    __builtin_amdgcn_global_load_lds((GU*)(A + aoff + ko_), \
        (LU*)&lds[bufi][0][wv*512], 16, 0, 0); \
    __builtin_amdgcn_global_load_lds((GU*)(A + aoff + (size_t)64*ld + ko_), \
        (LU*)&lds[bufi][0][wv*512 + 64*32], 16, 0, 0); \
    __builtin_amdgcn_global_load_lds((GU*)(Bt + boff + ko_), \
        (LU*)&lds[bufi][1][wv*512], 16, 0, 0); \
    __builtin_amdgcn_global_load_lds((GU*)(Bt + boff + (size_t)64*ld + ko_), \
        (LU*)&lds[bufi][1][wv*512 + 64*32], 16, 0, 0); \
  } while(0)

  int ard[4], brd[4];
  #pragma unroll
  for (int m = 0; m < 4; ++m) {
    int ra = wm + m*16 + fr;
    int rb = wn + m*16 + fr;
    ard[m] = ra*32 + (kc ^ ((ra >> 1) & 3))*8;
    brd[m] = rb*32 + (kc ^ ((rb >> 1) & 3))*8;
  }

  f32x4 acc[4][4];
  #pragma unroll
  for (int m = 0; m < 4; ++m)
    #pragma unroll
    for (int n = 0; n < 4; ++n)
      acc[m][n] = f32x4{0.f, 0.f, 0.f, 0.f};

  const int NK = kloop >> 5;
  STAGE(0, 0);
  __syncthreads();
  int buf = 0;
  for (int kt = 0; kt < NK; ++kt) {
    if (kt + 1 < NK) STAGE(buf^1, kt+1);
    bf16x8 af[4], bg[4];
    #pragma unroll
    for (int m = 0; m < 4; ++m) af[m] = *(const bf16x8*)&lds[buf][0][ard[m]];
    #pragma unroll
    for (int n = 0; n < 4; ++n) bg[n] = *(const bf16x8*)&lds[buf][1][brd[n]];
    #pragma unroll
    for (int m = 0; m < 4; ++m)
      #pragma unroll
      for (int n = 0; n < 4; ++n)
        acc[m][n] = __builtin_amdgcn_mfma_f32_16x16x32_bf16(af[m], bg[n], acc[m][n], 0, 0, 0);
    __syncthreads();
    buf ^= 1;
  }
#undef STAGE

  const int orow = bm + wm + (lane >> 4) * 4;
  const int ocol = bn + wn + fr;
  #pragma unroll
  for (int m = 0; m < 4; ++m) {
    #pragma unroll
    for (int n = 0; n < 4; ++n) {
      int col = ocol + n*16;
      if (col < N) {
        float bs = bias ? bias[col] : 0.f;
        #pragma unroll
        for (int q = 0; q < 4; ++q) {
          float vv = acc[m][n][q] + bs;
          if (act == 1) vv = tanhf(vv);
          else if (act == 2) vv = vv / (1.f + __expf(-vv));
          size_t off = (size_t)(orow + m*16 + q) * N + col;
          if (OUTF32) ((float*)Cout)[off] = vv;
          else ((u16*)Cout)[off] = f2b(vv);
        }
      }
    }
  }
}

template<int ACT, bool OUTF32>
__global__ __launch_bounds__(256) void gemm_mfma(
    const u16* __restrict__ A, const u16* __restrict__ Bt,
    void* __restrict__ Cout, const float* __restrict__ bias, int K, int N)
{
  mfma_core<OUTF32>(A, Bt, Cout, bias, K, K, N, ACT);
}

// K-split GEMM: z-th block-slab accumulates k in [z*ksz, (z+1)*ksz), writes
// raw fp32 partials to Cp + z*4096*N. No activation (applied at consumer).
__global__ __launch_bounds__(256) void gemm_ksplit(
    const u16* __restrict__ A, const u16* __restrict__ Bt,
    float* __restrict__ Cp, int ld, int ksz, int N)
{
  const int z = blockIdx.z;
  mfma_core<true>(A + (size_t)z*ksz, Bt + (size_t)z*ksz,
                  Cp + (size_t)z*4096*N, nullptr, ld, ksz, N, 0);
}

// ---------------- 256x256 4-phase GEMM for the big batched r/k/v/g GEMMs ----------------
struct GPack { const u16* A[4]; const u16* B[4]; u16* C[4]; };

#define VMW(n) asm volatile("s_waitcnt vmcnt(" #n ")" ::: "memory")
#define LGKM0() asm volatile("s_waitcnt lgkmcnt(0)" ::: "memory")
#define SCHB() __builtin_amdgcn_sched_barrier(0)
#define HBAR() __builtin_amdgcn_s_barrier()

__global__ __launch_bounds__(512) void gemm_rkvg256(GPack gp) {
  __shared__ __align__(16) u16 lds[2][2][2][8192];   // [dbuf][A/B][khalf][256*32] = 128 KB
  const int z = blockIdx.z;
  const u16* __restrict__ Ap  = gp.A[z];
  const u16* __restrict__ Btp = gp.B[z];
  u16* __restrict__ Cp = gp.C[z];
  const int act = (z == 3) ? 2 : 0;

  const int tid = threadIdx.x;
  const int lane = tid & 63;
  const int wv = __builtin_amdgcn_readfirstlane(tid >> 6);

  const int i_lin = blockIdx.y * gridDim.x + blockIdx.x;   // 0..63
  const int tile = (i_lin & 7) * 8 + (i_lin >> 3);
  const int bm = (tile >> 2) * 256;
  const int bn = (tile & 3) * 256;

  const int wm = (wv >> 2) * 128;    // 2 wave-rows of 128
  const int wn = (wv & 3) * 64;      // 4 wave-cols of 64
  const int kc = lane >> 4;
  const int fr = lane & 15;

  const int srow0 = (wv*2 + 0)*16 + (lane >> 2);
  const int srow1 = (wv*2 + 1)*16 + (lane >> 2);
  const int sc0 = ((lane & 3) ^ ((srow0 >> 1) & 3)) * 8;
  const int sc1 = ((lane & 3) ^ ((srow1 >> 1) & 3)) * 8;
  const size_t aoff0 = (size_t)(bm + srow0)*Cc + sc0;
  const size_t aoff1 = (size_t)(bm + srow1)*Cc + sc1;
  const size_t boff0 = (size_t)(bn + srow0)*Cc + sc0;
  const size_t boff1 = (size_t)(bn + srow1)*Cc + sc1;

  int ard[8], brd[4];
  #pragma unroll
  for (int mh = 0; mh < 2; ++mh)
    #pragma unroll
    for (int mf = 0; mf < 4; ++mf) {
      int r = wm + mh*64 + mf*16 + fr;
      ard[mh*4+mf] = r*32 + (kc ^ ((r >> 1) & 3))*8;
    }
  #pragma unroll
  for (int nf = 0; nf < 4; ++nf) {
    int r = wn + nf*16 + fr;
    brd[nf] = r*32 + (kc ^ ((r >> 1) & 3))*8;
  }

  f32x4 acc[8][4];
  #pragma unroll
  for (int m = 0; m < 8; ++m)
    #pragma unroll
    for (int n = 0; n < 4; ++n)
      acc[m][n] = f32x4{0.f, 0.f, 0.f, 0.f};

#define STG256(DB, MAT, KH, kt, off0, off1, src) do { \
    u16* dst_ = &lds[(DB)][(MAT)][(KH)][wv*1024]; \
    __builtin_amdgcn_global_load_lds((GU*)((src) + (off0) + (size_t)(kt)*64 + (KH)*32), \
        (LU*)dst_, 16, 0, 0); \
    __builtin_amdgcn_global_load_lds((GU*)((src) + (off1) + (size_t)(kt)*64 + (KH)*32), \
        (LU*)(dst_ + 512), 16, 0, 0); \
  } while(0)

#define PH256(cur, KH, MH, LOADB, STMAT, STKH, DOSTAGE, VMTOK) do { \
    _Pragma("unroll") \
    for (int mf = 0; mf < 4; ++mf) \
      af[mf] = *(const bf16x8*)&lds[(cur)][0][KH][ard[(MH)*4+mf]]; \
    if (LOADB) { \
      _Pragma("unroll") \
      for (int nf = 0; nf < 4; ++nf) \
        bg[nf] = *(const bf16x8*)&lds[(cur)][1][KH][brd[nf]]; \
    } \
    if (DOSTAGE) { \
      if ((STMAT) == 0) STG256((cur)^1, 0, STKH, t+1, aoff0, aoff1, Ap); \
      else              STG256((cur)^1, 1, STKH, t+1, boff0, boff1, Btp); \
    } \
    VMTOK; \
    SCHB(); \
    HBAR(); \
    LGKM0(); \
    SCHB(); \
    __builtin_amdgcn_s_setprio(1); \
    _Pragma("unroll") \
    for (int mf = 0; mf < 4; ++mf) \
      _Pragma("unroll") \
      for (int nf = 0; nf < 4; ++nf) \
        acc[(MH)*4+mf][nf] = __builtin_amdgcn_mfma_f32_16x16x32_bf16(af[mf], bg[nf], acc[(MH)*4+mf][nf], 0, 0, 0); \
    __builtin_amdgcn_s_setprio(0); \
    SCHB(); \
    HBAR(); \
  } while(0)

  const int NK = Cc >> 6;   // 16 K-tiles of 64

  STG256(0, 0, 0, 0, aoff0, aoff1, Ap);
  STG256(0, 1, 0, 0, boff0, boff1, Btp);
  STG256(0, 0, 1, 0, aoff0, aoff1, Ap);
  STG256(0, 1, 1, 0, boff0, boff1, Btp);
  VMW(4);
  SCHB();
  HBAR();

  bf16x8 af[4], bg[4];
  int t;
  #pragma unroll 2
  for (t = 0; t < NK - 1; ++t) {
    const int cur = t & 1;
    PH256(cur, 0, 0, true,  0, 0, true,  (void)0);
    PH256(cur, 0, 1, false, 1, 0, true,  VMW(4));
    PH256(cur, 1, 0, true,  0, 1, true,  (void)0);
    PH256(cur, 1, 1, false, 1, 1, true,  VMW(4));
  }
  { // final K-tile: no prefetch; full drain before its second k-half
    const int cur = t & 1;
    PH256(cur, 0, 0, true,  0, 0, false, (void)0);
    PH256(cur, 0, 1, false, 0, 0, false, VMW(0));
    PH256(cur, 1, 0, true,  0, 0, false, (void)0);
    PH256(cur, 1, 1, false, 0, 0, false, (void)0);
  }
#undef PH256
#undef STG256

  const int orow = bm + wm + (lane >> 4) * 4;
  const int ocol = bn + wn + fr;
  #pragma unroll
  for (int m = 0; m < 8; ++m) {
    #pragma unroll
    for (int nf = 0; nf < 4; ++nf) {
      #pragma unroll
      for (int q = 0; q < 4; ++q) {
        float vv = acc[m][nf][q];
        if (act == 2) vv = vv / (1.f + __expf(-vv));
        Cp[(size_t)(orow + (m >> 2)*64 + (m & 3)*16 + q) * Cc + ocol + nf*16] = f2b(vv);
      }
    }
  }
}

// ---------------- WKV6 pass 1: chunked matmul formulation (MFMA) ----------------
// Fused ew: per-block 32x64 ew tile computed in-kernel via K=64 MFMA from
// wl1p partials (L2-resident 4MB) + tdw2T + tdecay -> bufEW. Eliminates the
// gemm_ew64 launch and the 16MB ewb HBM round-trip; identical math.
__global__ __launch_bounds__(256) void wkv_pass1(u16* __restrict__ r,
    const u16* __restrict__ k, const u16* __restrict__ v,
    const float* __restrict__ wl1p, const u16* __restrict__ tdw2T,
    const float* __restrict__ tdecay, const float* __restrict__ u,
    u16* __restrict__ y, u16* __restrict__ S, float* __restrict__ D)
{
  __shared__ __align__(16) u16 rS[CHUNK][72];
  __shared__ __align__(16) u16 kS[CHUNK][72];
  __shared__ __align__(16) u16 vS[CHUNK][72];
  __shared__ __align__(16) u16 aW[CHUNK][72];        // tanh(sum wl1p) bf16
  __shared__ __align__(16) float bufEW[CHUNK][68];   // ew -> eR (in-place)
  __shared__ __align__(16) float eKnL[CHUNK][68];
  __shared__ __align__(16) u16 Rt[CHUNK][72];
  __shared__ __align__(16) u16 Kt[CHUNK][72];
  __shared__ __align__(16) u16 Ru[CHUNK][72];
  __shared__ __align__(16) u16 KhT[64][40];
  __shared__ __align__(16) u16 VT[64][40];
  __shared__ __align__(16) u16 A_lds[CHUNK][40];
  __shared__ float uL[64];
  __shared__ float Dl[64];

  const int blk = blockIdx.x;
  const int chunk = blk & (NCH-1);
  const int bh = blk >> 5;
  const int h = bh & (Hh-1);
  const int b = bh >> 4;
  const int tid = threadIdx.x;
  const int lane = tid & 63;
  const int wv = tid >> 6;
  const int fr = lane & 15;
  const int kc = lane >> 4;

  const int trow0 = b*Tt + chunk*CHUNK;
  const size_t rowbase = (size_t)trow0*Cc + h*64;
  {
    int tt = tid >> 3, c8 = (tid & 7)*8;
    size_t go = rowbase + (size_t)tt*Cc + c8;
    *(uint4*)&rS[tt][c8] = *(const uint4*)(r + go);
    *(uint4*)&kS[tt][c8] = *(const uint4*)(k + go);
    *(uint4*)&vS[tt][c8] = *(const uint4*)(v + go);
    // wl1 partial sum + tanh -> aW (bf16), K=64 row for this t
    size_t wrow = (size_t)(trow0 + tt)*64 + c8;
    float s8[8] = {0.f,0.f,0.f,0.f,0.f,0.f,0.f,0.f};
    #pragma unroll
    for (int z = 0; z < 4; ++z) {
      const float4* p = (const float4*)(wl1p + (size_t)z*262144 + wrow);
      float4 a = p[0], b2 = p[1];
      s8[0]+=a.x; s8[1]+=a.y; s8[2]+=a.z; s8[3]+=a.w;
      s8[4]+=b2.x; s8[5]+=b2.y; s8[6]+=b2.z; s8[7]+=b2.w;
    }
    u16 t8[8];
    #pragma unroll
    for (int j = 0; j < 8; ++j) t8[j] = f2b(fast_tanh(s8[j]));
    *(uint4*)&aW[tt][c8] = *(const uint4*)t8;
  }
  if (tid < 64) uL[tid] = u[h*64 + tid];
  __syncthreads();

  // ew MFMA: bufEW[t][i] = exp( (aW @ tdw2T^T)[t][i] + tdecay[h*64+i] )
  {
    const int icol = wv*16 + fr;
    const float bs = tdecay[h*64 + icol];
    #pragma unroll
    for (int tb = 0; tb < 2; ++tb) {
      f32x4 acc = {0.f,0.f,0.f,0.f};
      #pragma unroll
      for (int ks = 0; ks < 2; ++ks) {
        bf16x8 a  = *(const bf16x8*)&aW[tb*16+fr][kc*8 + ks*32];
        bf16x8 bb = *(const bf16x8*)(tdw2T + (size_t)(h*64 + icol)*64 + ks*32 + kc*8);
        acc = __builtin_amdgcn_mfma_f32_16x16x32_bf16(a, bb, acc, 0, 0, 0);
      }
      #pragma unroll
      for (int q = 0; q < 4; ++q)
        bufEW[tb*16 + kc*4 + q][icol] = __expf(acc[q] + bs);
    }
  }
  __syncthreads();

  if (tid < 64) {
    float eR = 1.f;
    for (int t = 0; t < CHUNK; ++t) {
      float e = bufEW[t][tid];
      bufEW[t][tid] = eR;                         // exp(lw[t-1])
      eR *= __expf(-e);                           // exp(lw[t])
      eKnL[t][tid] = __builtin_amdgcn_rcpf(eR);   // exp(-lw[t])
    }
    Dl[tid] = eR;
    D[(size_t)blk*64 + tid] = eR;
  }
  __syncthreads();

  {
    int t = tid >> 3, i0 = (tid & 7)*8;
    uint4 rv4 = *(const uint4*)&rS[t][i0];
    uint4 kv4 = *(const uint4*)&kS[t][i0];
    const uint* rw = (const uint*)&rv4;
    const uint* kw = (const uint*)&kv4;
    u16 rt8[8], kt8[8], ru8[8];
    #pragma unroll
    for (int q = 0; q < 8; ++q) {
      int i = i0 + q;
      float rv = (q & 1) ? bhi(rw[q>>1]) : blo(rw[q>>1]);
      float kv = (q & 1) ? bhi(kw[q>>1]) : blo(kw[q>>1]);
      float eR = bufEW[t][i];
      float eKn = eKnL[t][i];
      float ktv = kv * eKn;
      rt8[q] = f2b(rv * eR);
      kt8[q] = f2b(ktv);
      ru8[q] = f2b(rv * uL[i]);
      KhT[i][t] = f2b(ktv * Dl[i]);
      VT[i][t] = vS[t][i];
    }
    *(uint4*)&Rt[t][i0] = *(const uint4*)rt8;
    *(uint4*)&Kt[t][i0] = *(const uint4*)kt8;
    *(uint4*)&Ru[t][i0] = *(const uint4*)ru8;
  }
  __syncthreads();

  {
    const int wr = wv >> 1, wc = wv & 1;
    f32x4 accA = {0.f,0.f,0.f,0.f};
    f32x4 accD = {0.f,0.f,0.f,0.f};
    #pragma unroll
    for (int ks = 0; ks < 2; ++ks) {
      bf16x8 a  = *(const bf16x8*)&Rt[wr*16+fr][kc*8 + ks*32];
      bf16x8 bb = *(const bf16x8*)&Kt[wc*16+fr][kc*8 + ks*32];
      accA = __builtin_amdgcn_mfma_f32_16x16x32_bf16(a, bb, accA, 0, 0, 0);
      bf16x8 a2 = *(const bf16x8*)&Ru[wr*16+fr][kc*8 + ks*32];
      bf16x8 b2 = *(const bf16x8*)&kS[wc*16+fr][kc*8 + ks*32];
      accD = __builtin_amdgcn_mfma_f32_16x16x32_bf16(a2, b2, accD, 0, 0, 0);
    }
    #pragma unroll
    for (int q = 0; q < 4; ++q) {
      int trow = wr*16 + kc*4 + q;
      int scol = wc*16 + fr;
      float val = (scol < trow) ? accA[q] : ((scol == trow) ? accD[q] : 0.f);
      A_lds[trow][scol] = f2b(val);
    }
  }
  __syncthreads();

  #pragma unroll
  for (int tb = 0; tb < 2; ++tb) {
    bf16x8 a  = *(const bf16x8*)&A_lds[tb*16+fr][kc*8];
    bf16x8 bb = *(const bf16x8*)&VT[wv*16+fr][kc*8];
    f32x4 acc = {0.f,0.f,0.f,0.f};
    acc = __builtin_amdgcn_mfma_f32_16x16x32_bf16(a, bb, acc, 0, 0, 0);
    #pragma unroll
    for (int q = 0; q < 4; ++q) {
      int t = tb*16 + kc*4 + q;
      int j = wv*16 + fr;
      y[rowbase + (size_t)t*Cc + j] = f2b(acc[q]);
    }
  }
  #pragma unroll
  for (int jb = 0; jb < 4; ++jb) {
    bf16x8 a  = *(const bf16x8*)&KhT[wv*16+fr][kc*8];
    bf16x8 bb = *(const bf16x8*)&VT[jb*16+fr][kc*8];
    f32x4 acc = {0.f,0.f,0.f,0.f};
    acc = __builtin_amdgcn_mfma_f32_16x16x32_bf16(a, bb, acc, 0, 0, 0);
    #pragma unroll
    for (int q = 0; q < 4; ++q) {
      int i = wv*16 + kc*4 + q;
      int j = jb*16 + fr;
      S[((size_t)blk*64 + i)*64 + j] = f2b(acc[q]);
    }
  }
  {
    int tt = tid >> 3, c8 = (tid & 7)*8;
    *(uint4*)(r + rowbase + (size_t)tt*Cc + c8) = *(const uint4*)&Rt[tt][c8];
  }
}

// ---------------- WKV6 pass 2: cross-chunk state propagation (in-place) ----------------
// Latency-killer rewrite: 256 blocks (bh x 4 j-quarters), 4 regs/thread,
// ALL 32 chunks' tmp preloaded up front (128 independent loads -> single
// latency exposure), then a register-only scan with interleaved stores.
__global__ __launch_bounds__(256) void wkv_pass2(u16* __restrict__ S,
    const float* __restrict__ D)
{
  __shared__ float Dl[NCH][64];
  const int bh = blockIdx.x >> 2;
  const int jq = blockIdx.x & 3;
  const int tid = threadIdx.x;
  {
    const float4* src = (const float4*)(D + (size_t)bh*NCH*64);
    float4* dst = (float4*)&Dl[0][0];
    dst[tid] = src[tid];
    dst[tid + 256] = src[tid + 256];
  }
  __syncthreads();
  const int j = jq*16 + (tid & 15);
  const int i0 = (tid >> 4) * 4;
  const size_t base0 = (((size_t)bh*NCH)*64 + i0)*64 + j;
  u16 tmp[NCH][4];
  #pragma unroll
  for (int c = 0; c < NCH; ++c) {
    size_t base = base0 + (size_t)c*4096;
    #pragma unroll
    for (int ii = 0; ii < 4; ++ii) tmp[c][ii] = S[base + ii*64];
  }
  float Sr[4] = {0.f, 0.f, 0.f, 0.f};
  #pragma unroll
  for (int c = 0; c < NCH; ++c) {
    size_t base = base0 + (size_t)c*4096;
    #pragma unroll
    for (int ii = 0; ii < 4; ++ii) {
      S[base + ii*64] = f2b(Sr[ii]);
      Sr[ii] = fmaf(Sr[ii], Dl[c][i0+ii], b2f(tmp[c][ii]));
    }
  }
}

// ---------------- GroupNorm(H) + correction + gate, 8 rows/block ----------------
__global__ __launch_bounds__(256) void gn_gate(const u16* __restrict__ y,
   const u16* __restrict__ g, const u16* __restrict__ rc, const u16* __restrict__ S,
   const float* __restrict__ gamma, const float* __restrict__ beta, u16* __restrict__ out)
{
  __shared__ u16 rcl[8][Cc];
  const int bt0 = blockIdx.x * 8;
  const int b = bt0 >> 10;
  const int t0 = bt0 & (Tt-1);
  const int chunk = t0 >> 5;
  const int tid = threadIdx.x;
  #pragma unroll
  for (int rr = 0; rr < 8; ++rr)
    ((ushort4*)rcl[rr])[tid] = ((const ushort4*)(rc + (size_t)(bt0+rr)*Cc))[tid];
  __syncthreads();
  const int c0 = tid*4, h = c0 >> 6, j0 = c0 & 63;
  const u16* Sb = S + (((size_t)(b*Hh + h)*NCH + chunk)*64)*64 + j0;
  float corr[8][4];
  #pragma unroll
  for (int rr = 0; rr < 8; ++rr)
    #pragma unroll
    for (int q = 0; q < 4; ++q) corr[rr][q] = 0.f;
  #pragma unroll 4
  for (int i = 0; i < 64; ++i) {
    ushort4 sv = *(const ushort4*)(Sb + (size_t)i*64);
    float s0 = b2f(sv.x), s1 = b2f(sv.y), s2 = b2f(sv.z), s3 = b2f(sv.w);
    #pragma unroll
    for (int rr = 0; rr < 8; ++rr) {
      float rv = b2f(rcl[rr][h*64 + i]);
      corr[rr][0] = fmaf(rv, s0, corr[rr][0]);
      corr[rr][1] = fmaf(rv, s1, corr[rr][1]);
      corr[rr][2] = fmaf(rv, s2, corr[rr][2]);
      corr[rr][3] = fmaf(rv, s3, corr[rr][3]);
    }
  }
  float4 ga = ((const float4*)gamma)[tid];
  float4 be = ((const float4*)beta)[tid];
  #pragma unroll
  for (int rr = 0; rr < 8; ++rr) {
    size_t o4 = (size_t)(bt0+rr)*(Cc/4) + tid;
    ushort4 yv4 = ((const ushort4*)y)[o4];
    float y0 = b2f(yv4.x) + corr[rr][0];
    float y1 = b2f(yv4.y) + corr[rr][1];
    float y2 = b2f(yv4.z) + corr[rr][2];
    float y3 = b2f(yv4.w) + corr[rr][3];
    float s  = y0 + y1 + y2 + y3;
    float sq = y0*y0 + y1*y1 + y2*y2 + y3*y3;
    #pragma unroll
    for (int m = 1; m < 16; m <<= 1) {
      s  += __shfl_xor(s, m, 64);
      sq += __shfl_xor(sq, m, 64);
    }
    float mu  = s * (1.f/64.f);
    float var = sq * (1.f/64.f) - mu*mu;
    float rstd = rsqrtf(var + 6.4e-4f);
    ushort4 gu = ((const ushort4*)g)[o4];
    ushort4 ou;
    ou.x = f2b(((y0 - mu)*rstd*ga.x + be.x) * b2f(gu.x));
    ou.y = f2b(((y1 - mu)*rstd*ga.y + be.y) * b2f(gu.y));
    ou.z = f2b(((y2 - mu)*rstd*ga.z + be.z) * b2f(gu.z));
    ou.w = f2b(((y3 - mu)*rstd*ga.w + be.w) * b2f(gu.w));
    ((ushort4*)out)[o4] = ou;
  }
}

extern "C" void kernel_launch(void* const* d_in, const int* in_sizes, int n_in,
                              void* d_out, int out_size, void* d_ws, size_t ws_size,
                              hipStream_t stream) {
  const float* x      = (const float*)d_in[0];
  const float* maa_x  = (const float*)d_in[1];
  const float* maa_w  = (const float*)d_in[2];
  const float* maa_k  = (const float*)d_in[3];
  const float* maa_v  = (const float*)d_in[4];
  const float* maa_r  = (const float*)d_in[5];
  const float* maa_g  = (const float*)d_in[6];
  const float* w1     = (const float*)d_in[7];
  const float* w2     = (const float*)d_in[8];
  const float* tdecay = (const float*)d_in[9];
  const float* tdw1   = (const float*)d_in[10];
  const float* tdw2   = (const float*)d_in[11];
  const float* faaaa  = (const float*)d_in[12];
  const float* Wr     = (const float*)d_in[13];
  const float* Wk     = (const float*)d_in[14];
  const float* Wv     = (const float*)d_in[15];
  const float* Wg     = (const float*)d_in[16];
  const float* Wo     = (const float*)d_in[17];
  const float* gamma  = (const float*)d_in[18];
  const float* beta   = (const float*)d_in[19];
  float* out = (float*)d_out;

  const size_t MB = 1u << 20;
  char* wsb = (char*)d_ws;
  float* m1p  = (float*)(wsb + 0);            // 10.5M fp32 m1 k-partials (step2->3)
  float* wl1p = (float*)(wsb + 0);            // 4M fp32 wl1 k-partials (step4->6; over dead m1p)
  u16*   w2T  = (u16*)(wsb + 12*MB);          // 320K bf16 w2 transposed (step0->3)
  u16*   xk   = (u16*)(wsb + 16*MB);          // 8M
  u16*   xv   = (u16*)(wsb + 24*MB);          // 8M
  u16*   xr   = (u16*)(wsb + 32*MB);          // 8M -> gated
  u16*   xg   = (u16*)(wsb + 40*MB);          // 8M
  u16*   xw   = (u16*)(wsb + 48*MB);          // 8M (dead after wl1)
  u16*   rbuf = (u16*)(wsb + 56*MB);          // 8M (r -> rc in-place)
  u16*   kbuf = (u16*)(wsb + 64*MB);          // 8M
  u16*   vbuf = (u16*)(wsb + 72*MB);          // 8M
  u16*   gbuf = (u16*)(wsb + 80*MB);          // 8M
  float* Dbuf = (float*)(wsb + 88*MB);        // 512K
  u16*   Sbuf = (u16*)(wsb + 16*MB);          // 16M over xk+xv (dead by pass1)
  u16*   BW0  = (u16*)(wsb + 88*MB + 512*1024);
  u16*   BW1  = (u16*)((char*)BW0 + 2*MB);
  u16*   BW2  = (u16*)((char*)BW1 + 2*MB);
  u16*   BW3  = (u16*)((char*)BW2 + 2*MB);
  u16*   BW4  = (u16*)((char*)BW3 + 2*MB);    // ends 98.5M
  u16*   w1T  = (u16*)((char*)BW4 + 2*MB);    // 320K
  u16*   tdw1T = (u16*)(wsb + 99*MB);
  u16*   tdw2T = (u16*)(wsb + 99*MB + 256*1024);
  u16*   gated = xr;
  u16*   xxx16 = (u16*)d_out;
  u16*   yb16  = (u16*)d_out;                 // 8M bf16 y (step6->7)

  dim3 blk(256);
  // 0+1. merged: weight transpose (z<9) + prep xxx (z>=9)
  WPack wp;
  wp.p[0] = {Wr, BW0, Cc, Cc};  wp.p[1] = {Wk, BW1, Cc, Cc};
  wp.p[2] = {Wv, BW2, Cc, Cc};  wp.p[3] = {Wg, BW3, Cc, Cc};
  wp.p[4] = {Wo, BW4, Cc, Cc};  wp.p[5] = {w1, w1T, Cc, 160};
  wp.p[6] = {tdw1, tdw1T, Cc, 64}; wp.p[7] = {tdw2, tdw2T, 64, Cc};
  wp.p[8] = {w2, w2T, 160, Cc};
  prep_transW<<<dim3(32,32,13), blk, 0, stream>>>(wp, x, maa_x, xxx16);
  // 2. m1 partials = xxx @ w1 (K-split z=4, fp32; tanh applied in mix_mfma)
  gemm_ksplit<<<dim3(2, 32, 4), blk, 0, stream>>>(xxx16, w1T, m1p, Cc, 256, 160);
  // 3. fused MFMA mix -> xw,xk,xv,xr,xg (all bf16)
  mix_mfma<<<1024, blk, 0, stream>>>(x, m1p, w2T, maa_w, maa_k, maa_v, maa_r, maa_g,
                                     xw, xk, xv, xr, xg);
  // 4. wl1 partials = xw @ tdw1 (K-split z=4, fp32; consumed inside wkv_pass1)
  gemm_ksplit<<<dim3(1, 32, 4), blk, 0, stream>>>(xw, tdw1T, wl1p, Cc, 256, 64);
  // 5. r,k,v,g batched — 256x256 4-phase kernel, 256 blocks
  GPack gp;
  gp.A[0] = xr; gp.A[1] = xk; gp.A[2] = xv; gp.A[3] = xg;
  gp.B[0] = BW0; gp.B[1] = BW1; gp.B[2] = BW2; gp.B[3] = BW3;
  gp.C[0] = rbuf; gp.C[1] = kbuf; gp.C[2] = vbuf; gp.C[3] = gbuf;
  gemm_rkvg256<<<dim3(4, 16, 4), dim3(512), 0, stream>>>(gp);
  // 6. wkv chunked scan (fused ew-GEMM; y bf16)
  wkv_pass1<<<Bb*Hh*NCH, blk, 0, stream>>>(rbuf, kbuf, vbuf, wl1p, tdw2T, tdecay,
                                           faaaa, yb16, Sbuf, Dbuf);
  wkv_pass2<<<Bb*Hh*4, blk, 0, stream>>>(Sbuf, Dbuf);
  // 7. groupnorm + correction + gate
  gn_gate<<<BT/8, blk, 0, stream>>>(yb16, gbuf, rbuf, Sbuf, gamma, beta, gated);
  // 8. out = gated @ Wo (fp32)
  gemm_mfma<0,true><<<dim3(8, 32), blk, 0, stream>>>(gated, BW4, out, nullptr, Cc, Cc);
}

// Round 8
// 180.164 us; speedup vs baseline: 1.1138x; 1.0488x over previous
//
#include <hip/hip_runtime.h>

#define Bb 4
#define Tt 1024
#define Cc 1024
#define Hh 16
#define BT (Bb*Tt)
#define CHUNK 32
#define NCH (Tt/CHUNK)

typedef unsigned int uint;
typedef unsigned short u16;
typedef __bf16 bf16x8 __attribute__((ext_vector_type(8)));
typedef float f32x4 __attribute__((ext_vector_type(4)));
typedef const __attribute__((address_space(1))) uint GU;
typedef __attribute__((address_space(3))) uint LU;

__device__ __forceinline__ float blo(uint u) { return __uint_as_float(u << 16); }
__device__ __forceinline__ float bhi(uint u) { return __uint_as_float(u & 0xffff0000u); }
__device__ __forceinline__ float b2f(u16 u) { return __uint_as_float(((uint)u) << 16); }
__device__ __forceinline__ u16 f2b(float f) {
  uint u = __float_as_uint(f);
  return (u16)((u + 0x7fffu + ((u >> 16) & 1u)) >> 16);   // RNE
}
// fast tanh: 1 - 2/(e^{2x}+1); exact limits at +-inf, rel err ~2^-21
__device__ __forceinline__ float fast_tanh(float x) {
  float e = __expf(2.f * x);
  return 1.f - 2.f / (e + 1.f);
}

// ---------------- merged: weight transpose (z<9) + prep_xxx (z>=9) ----------
struct WPair { const float* s; u16* d; int K; int N; };
struct WPack { WPair p[9]; };

__global__ __launch_bounds__(256) void prep_transW(WPack wp,
    const float* __restrict__ x, const float* __restrict__ maa_x,
    u16* __restrict__ xxx)
{
  __shared__ float tile[32][33];
  if (blockIdx.z < 9) {
    WPair pr = wp.p[blockIdx.z];
    int c0 = blockIdx.x*32, r0 = blockIdx.y*32;
    if (c0 >= pr.N || r0 >= pr.K) return;
    int tc = threadIdx.x & 31, tr = threadIdx.x >> 5;
    #pragma unroll
    for (int p = 0; p < 4; ++p)
      tile[tr + p*8][tc] = pr.s[(size_t)(r0 + tr + p*8)*pr.N + c0 + tc];
    __syncthreads();
    #pragma unroll
    for (int p = 0; p < 4; ++p) {
      int n = tr + p*8;
      pr.d[(size_t)(c0 + n)*pr.K + r0 + tc] = f2b(tile[tc][n]);
    }
  } else {
    int vb = (blockIdx.z - 9)*1024 + blockIdx.y*32 + blockIdx.x;  // 0..4095
    int idx = vb*256 + threadIdx.x;
    int c4 = idx & 255;
    int bt = idx >> 8;
    int t = bt & (Tt-1);
    float4 xc = ((const float4*)x)[idx];
    float4 xp = make_float4(0.f,0.f,0.f,0.f);
    if (t > 0) xp = ((const float4*)x)[idx - 256];
    float4 mx = ((const float4*)maa_x)[c4];
    ushort4 o;
    o.x = f2b(fmaf(xp.x - xc.x, mx.x, xc.x));
    o.y = f2b(fmaf(xp.y - xc.y, mx.y, xc.y));
    o.z = f2b(fmaf(xp.z - xc.z, mx.z, xc.z));
    o.w = f2b(fmaf(xp.w - xc.w, mx.w, xc.w));
    ((ushort4*)xxx)[idx] = o;
  }
}

// ---------------- fused mix: MFMA (tanh Σ m1-partials)@w2 + epilogue ----------
// Block = 16 rows x 256 cols (4 waves each own a 64-col strip of the SAME rows).
// Stage 1 (cooperative, coalesced): aW[16][160] = bf16(tanh(sum_z m1p)) once
// per block (was recomputed per wave = 4x exp + scattered 16B reads), and
// xS[17 rows][256 cols] fp32 (x + shifted row) via float4 loads (was 32
// scalar dword loads/thread). Stage 2: per-wave MFMA + epilogue via the
// wave-private strip bounce (coalesced uint4 stores).
__global__ __launch_bounds__(256) void mix_mfma(
    const float* __restrict__ x, const float* __restrict__ m1p,
    const u16* __restrict__ w2T,
    const float* __restrict__ maa_w, const float* __restrict__ maa_k,
    const float* __restrict__ maa_v, const float* __restrict__ maa_r,
    const float* __restrict__ maa_g,
    u16* __restrict__ xw, u16* __restrict__ xk, u16* __restrict__ xv,
    u16* __restrict__ xr, u16* __restrict__ xg)
{
  __shared__ __align__(16) u16 aW[16][168];
  __shared__ __align__(16) float xS[17][260];
  __shared__ __align__(16) u16 strip[4][16][72];
  const int tid = threadIdx.x;
  const int lane = tid & 63;
  const int wv = tid >> 6;
  const int rs = blockIdx.x >> 2;          // 0..255
  const int cb = blockIdx.x & 3;           // 0..3
  const int r0 = rs*16;
  const int c0b = cb*256;
  const int fr = lane & 15, kc = lane >> 4;
  const bool firstrow = (r0 & (Tt-1)) == 0;

  // stage aW (640 float4-tasks: 5 f x 16 rows x 8 col4)
  for (int task = tid; task < 640; task += 256) {
    int f  = task >> 7;
    int r  = (task >> 3) & 15;
    int c4 = task & 7;
    size_t off = (size_t)(r0 + r)*160 + f*32 + c4*4;
    float4 s = *(const float4*)(m1p + off);
    #pragma unroll
    for (int z = 1; z < 4; ++z) {
      float4 p = *(const float4*)(m1p + (size_t)z*655360 + off);
      s.x += p.x; s.y += p.y; s.z += p.z; s.w += p.w;
    }
    ushort4 t4;
    t4.x = f2b(fast_tanh(s.x)); t4.y = f2b(fast_tanh(s.y));
    t4.z = f2b(fast_tanh(s.z)); t4.w = f2b(fast_tanh(s.w));
    *(ushort4*)&aW[r][f*32 + c4*4] = t4;
  }
  // stage x rows r0-1..r0+15, cols c0b..c0b+255 (1088 float4-tasks)
  for (int i = tid; i < 1088; i += 256) {
    int r17 = i >> 6;            // 0..16
    int c4  = i & 63;
    float4 v = make_float4(0.f,0.f,0.f,0.f);
    if (!(r17 == 0 && firstrow))
      v = *(const float4*)(x + (size_t)(r0 - 1 + r17)*Cc + c0b + c4*4);
    *(float4*)&xS[r17][c4*4] = v;
  }
  __syncthreads();

  const int c0 = c0b + wv*64;
  float xc[4][4], xd[4][4];
  #pragma unroll
  for (int n = 0; n < 4; ++n) {
    int cl = wv*64 + n*16 + fr;
    #pragma unroll
    for (int q = 0; q < 4; ++q) {
      int rl = kc*4 + q;
      float v = xS[rl + 1][cl];
      float p = xS[rl][cl];
      xc[n][q] = v;
      xd[n][q] = p - v;
    }
  }

  u16* const outs[5] = {xw, xk, xv, xr, xg};
  const float* const maas[5] = {maa_w, maa_k, maa_v, maa_r, maa_g};

  #pragma unroll
  for (int f = 0; f < 5; ++f) {
    bf16x8 af = *(const bf16x8*)&aW[fr][f*32 + kc*8];
    f32x4 acc[4];
    #pragma unroll
    for (int n = 0; n < 4; ++n) {
      bf16x8 bg = *(const bf16x8*)(w2T + (size_t)(c0 + n*16 + fr)*160 + f*32 + kc*8);
      acc[n] = __builtin_amdgcn_mfma_f32_16x16x32_bf16(af, bg, f32x4{0.f,0.f,0.f,0.f}, 0, 0, 0);
    }
    const float* __restrict__ ma = maas[f];
    u16* __restrict__ op = outs[f];
    #pragma unroll
    for (int n = 0; n < 4; ++n) {
      int colL = n*16 + fr;
      float mv = ma[c0 + colL];
      #pragma unroll
      for (int q = 0; q < 4; ++q)
        strip[wv][kc*4 + q][colL] = f2b(fmaf(xd[n][q], mv + acc[n][q], xc[n][q]));
    }
    #pragma unroll
    for (int rd = 0; rd < 2; ++rd) {
      int r8 = (lane >> 3) + rd*8;
      uint4 v = *(const uint4*)&strip[wv][r8][(lane & 7)*8];
      *(uint4*)(op + (size_t)(r0 + r8)*Cc + c0 + (lane & 7)*8) = v;
    }
  }
}

// ---------------- bf16 MFMA GEMM core (m97 structure + chunk swizzle) ----------------
// ld: row stride (elems) of A and Bt; kloop: K extent to accumulate (<= ld).
template<bool OUTF32>
__device__ __forceinline__ void mfma_core(
    const u16* __restrict__ A, const u16* __restrict__ Bt,
    void* __restrict__ Cout, const float* __restrict__ bias,
    int ld, int kloop, int N, int act)
{
  __shared__ __align__(16) u16 lds[2][2][128*32];   // 32 KB
  const int tid = threadIdx.x;
  const int lane = tid & 63;
  const int wv = __builtin_amdgcn_readfirstlane(tid >> 6);

  // bijective XCD swizzle (requires gridDim.y % 8 == 0)
  const int nby8 = gridDim.y >> 3;
  const int i_lin = blockIdx.y * gridDim.x + blockIdx.x;
  const int cx = i_lin & 7, rest = i_lin >> 3;
  const int bm = (cx * nby8 + rest % nby8) * 128;
  const int bn = (rest / nby8) * 128;

  const int wm = (wv >> 1) * 64;
  const int wn = (wv & 1) * 64;
  const int kc = lane >> 4;
  const int fr = lane & 15;

  const int srow = wv*16 + (lane >> 2);
  const int ssw  = (srow >> 1) & 3;                 // == s(srow+64)
  const int scol = ((lane & 3) ^ ssw) * 8;
  const size_t aoff = (size_t)(bm + srow) * ld + scol;
  const size_t boff = (size_t)(bn + srow) * ld + scol;

#define STAGE(bufi, kt) do { \
    size_t ko_ = (size_t)(kt) * 32; \
    __builtin_amdgcn_global_load_lds((GU*)(A + aoff + ko_), \
        (LU*)&lds[bufi][0][wv*512], 16, 0, 0); \
    __builtin_amdgcn_global_load_lds((GU*)(A + aoff + (size_t)64*ld + ko_), \
        (LU*)&lds[bufi][0][wv*512 + 64*32], 16, 0, 0); \
    __builtin_amdgcn_global_load_lds((GU*)(Bt + boff + ko_), \
        (LU*)&lds[bufi][1][wv*512], 16, 0, 0); \
    __builtin_amdgcn_global_load_lds((GU*)(Bt + boff + (size_t)64*ld + ko_), \
        (LU*)&lds[bufi][1][wv*512 + 64*32], 16, 0, 0); \
  } while(0)

  int ard[4], brd[4];
  #pragma unroll
  for (int m = 0; m < 4; ++m) {
    int ra = wm + m*16 + fr;
    int rb = wn + m*16 + fr;
    ard[m] = ra*32 + (kc ^ ((ra >> 1) & 3))*8;
    brd[m] = rb*32 + (kc ^ ((rb >> 1) & 3))*8;
  }

  f32x4 acc[4][4];
  #pragma unroll
  for (int m = 0; m < 4; ++m)
    #pragma unroll
    for (int n = 0; n < 4; ++n)
      acc[m][n] = f32x4{0.f, 0.f, 0.f, 0.f};

  const int NK = kloop >> 5;
  STAGE(0, 0);
  __syncthreads();
  int buf = 0;
  for (int kt = 0; kt < NK; ++kt) {
    if (kt + 1 < NK) STAGE(buf^1, kt+1);
    bf16x8 af[4], bg[4];
    #pragma unroll
    for (int m = 0; m < 4; ++m) af[m] = *(const bf16x8*)&lds[buf][0][ard[m]];
    #pragma unroll
    for (int n = 0; n < 4; ++n) bg[n] = *(const bf16x8*)&lds[buf][1][brd[n]];
    #pragma unroll
    for (int m = 0; m < 4; ++m)
      #pragma unroll
      for (int n = 0; n < 4; ++n)
        acc[m][n] = __builtin_amdgcn_mfma_f32_16x16x32_bf16(af[m], bg[n], acc[m][n], 0, 0, 0);
    __syncthreads();
    buf ^= 1;
  }
#undef STAGE

  const int orow = bm + wm + (lane >> 4) * 4;
  const int ocol = bn + wn + fr;
  #pragma unroll
  for (int m = 0; m < 4; ++m) {
    #pragma unroll
    for (int n = 0; n < 4; ++n) {
      int col = ocol + n*16;
      if (col < N) {
        float bs = bias ? bias[col] : 0.f;
        #pragma unroll
        for (int q = 0; q < 4; ++q) {
          float vv = acc[m][n][q] + bs;
          if (act == 1) vv = tanhf(vv);
          else if (act == 2) vv = vv / (1.f + __expf(-vv));
          size_t off = (size_t)(orow + m*16 + q) * N + col;
          if (OUTF32) ((float*)Cout)[off] = vv;
          else ((u16*)Cout)[off] = f2b(vv);
        }
      }
    }
  }
}

template<int ACT, bool OUTF32>
__global__ __launch_bounds__(256) void gemm_mfma(
    const u16* __restrict__ A, const u16* __restrict__ Bt,
    void* __restrict__ Cout, const float* __restrict__ bias, int K, int N)
{
  mfma_core<OUTF32>(A, Bt, Cout, bias, K, K, N, ACT);
}

// K-split GEMM: z-th block-slab accumulates k in [z*ksz, (z+1)*ksz), writes
// raw fp32 partials to Cp + z*4096*N. No activation (applied at consumer).
__global__ __launch_bounds__(256) void gemm_ksplit(
    const u16* __restrict__ A, const u16* __restrict__ Bt,
    float* __restrict__ Cp, int ld, int ksz, int N)
{
  const int z = blockIdx.z;
  mfma_core<true>(A + (size_t)z*ksz, Bt + (size_t)z*ksz,
                  Cp + (size_t)z*4096*N, nullptr, ld, ksz, N, 0);
}

// ---------------- 256x256 4-phase GEMM for the big batched r/k/v/g GEMMs ----------------
struct GPack { const u16* A[4]; const u16* B[4]; u16* C[4]; };

#define VMW(n) asm volatile("s_waitcnt vmcnt(" #n ")" ::: "memory")
#define LGKM0() asm volatile("s_waitcnt lgkmcnt(0)" ::: "memory")
#define SCHB() __builtin_amdgcn_sched_barrier(0)
#define HBAR() __builtin_amdgcn_s_barrier()

__global__ __launch_bounds__(512) void gemm_rkvg256(GPack gp) {
  __shared__ __align__(16) u16 lds[2][2][2][8192];   // [dbuf][A/B][khalf][256*32] = 128 KB
  const int z = blockIdx.z;
  const u16* __restrict__ Ap  = gp.A[z];
  const u16* __restrict__ Btp = gp.B[z];
  u16* __restrict__ Cp = gp.C[z];
  const int act = (z == 3) ? 2 : 0;

  const int tid = threadIdx.x;
  const int lane = tid & 63;
  const int wv = __builtin_amdgcn_readfirstlane(tid >> 6);

  const int i_lin = blockIdx.y * gridDim.x + blockIdx.x;   // 0..63
  const int tile = (i_lin & 7) * 8 + (i_lin >> 3);
  const int bm = (tile >> 2) * 256;
  const int bn = (tile & 3) * 256;

  const int wm = (wv >> 2) * 128;    // 2 wave-rows of 128
  const int wn = (wv & 3) * 64;      // 4 wave-cols of 64
  const int kc = lane >> 4;
  const int fr = lane & 15;

  const int srow0 = (wv*2 + 0)*16 + (lane >> 2);
  const int srow1 = (wv*2 + 1)*16 + (lane >> 2);
  const int sc0 = ((lane & 3) ^ ((srow0 >> 1) & 3)) * 8;
  const int sc1 = ((lane & 3) ^ ((srow1 >> 1) & 3)) * 8;
  const size_t aoff0 = (size_t)(bm + srow0)*Cc + sc0;
  const size_t aoff1 = (size_t)(bm + srow1)*Cc + sc1;
  const size_t boff0 = (size_t)(bn + srow0)*Cc + sc0;
  const size_t boff1 = (size_t)(bn + srow1)*Cc + sc1;

  int ard[8], brd[4];
  #pragma unroll
  for (int mh = 0; mh < 2; ++mh)
    #pragma unroll
    for (int mf = 0; mf < 4; ++mf) {
      int r = wm + mh*64 + mf*16 + fr;
      ard[mh*4+mf] = r*32 + (kc ^ ((r >> 1) & 3))*8;
    }
  #pragma unroll
  for (int nf = 0; nf < 4; ++nf) {
    int r = wn + nf*16 + fr;
    brd[nf] = r*32 + (kc ^ ((r >> 1) & 3))*8;
  }

  f32x4 acc[8][4];
  #pragma unroll
  for (int m = 0; m < 8; ++m)
    #pragma unroll
    for (int n = 0; n < 4; ++n)
      acc[m][n] = f32x4{0.f, 0.f, 0.f, 0.f};

#define STG256(DB, MAT, KH, kt, off0, off1, src) do { \
    u16* dst_ = &lds[(DB)][(MAT)][(KH)][wv*1024]; \
    __builtin_amdgcn_global_load_lds((GU*)((src) + (off0) + (size_t)(kt)*64 + (KH)*32), \
        (LU*)dst_, 16, 0, 0); \
    __builtin_amdgcn_global_load_lds((GU*)((src) + (off1) + (size_t)(kt)*64 + (KH)*32), \
        (LU*)(dst_ + 512), 16, 0, 0); \
  } while(0)

#define PH256(cur, KH, MH, LOADB, STMAT, STKH, DOSTAGE, VMTOK) do { \
    _Pragma("unroll") \
    for (int mf = 0; mf < 4; ++mf) \
      af[mf] = *(const bf16x8*)&lds[(cur)][0][KH][ard[(MH)*4+mf]]; \
    if (LOADB) { \
      _Pragma("unroll") \
      for (int nf = 0; nf < 4; ++nf) \
        bg[nf] = *(const bf16x8*)&lds[(cur)][1][KH][brd[nf]]; \
    } \
    if (DOSTAGE) { \
      if ((STMAT) == 0) STG256((cur)^1, 0, STKH, t+1, aoff0, aoff1, Ap); \
      else              STG256((cur)^1, 1, STKH, t+1, boff0, boff1, Btp); \
    } \
    VMTOK; \
    SCHB(); \
    HBAR(); \
    LGKM0(); \
    SCHB(); \
    __builtin_amdgcn_s_setprio(1); \
    _Pragma("unroll") \
    for (int mf = 0; mf < 4; ++mf) \
      _Pragma("unroll") \
      for (int nf = 0; nf < 4; ++nf) \
        acc[(MH)*4+mf][nf] = __builtin_amdgcn_mfma_f32_16x16x32_bf16(af[mf], bg[nf], acc[(MH)*4+mf][nf], 0, 0, 0); \
    __builtin_amdgcn_s_setprio(0); \
    SCHB(); \
    HBAR(); \
  } while(0)

  const int NK = Cc >> 6;   // 16 K-tiles of 64

  STG256(0, 0, 0, 0, aoff0, aoff1, Ap);
  STG256(0, 1, 0, 0, boff0, boff1, Btp);
  STG256(0, 0, 1, 0, aoff0, aoff1, Ap);
  STG256(0, 1, 1, 0, boff0, boff1, Btp);
  VMW(4);
  SCHB();
  HBAR();

  bf16x8 af[4], bg[4];
  int t;
  #pragma unroll 2
  for (t = 0; t < NK - 1; ++t) {
    const int cur = t & 1;
    PH256(cur, 0, 0, true,  0, 0, true,  (void)0);
    PH256(cur, 0, 1, false, 1, 0, true,  VMW(4));
    PH256(cur, 1, 0, true,  0, 1, true,  (void)0);
    PH256(cur, 1, 1, false, 1, 1, true,  VMW(4));
  }
  { // final K-tile: no prefetch; full drain before its second k-half
    const int cur = t & 1;
    PH256(cur, 0, 0, true,  0, 0, false, (void)0);
    PH256(cur, 0, 1, false, 0, 0, false, VMW(0));
    PH256(cur, 1, 0, true,  0, 0, false, (void)0);
    PH256(cur, 1, 1, false, 0, 0, false, (void)0);
  }
#undef PH256
#undef STG256

  const int orow = bm + wm + (lane >> 4) * 4;
  const int ocol = bn + wn + fr;
  #pragma unroll
  for (int m = 0; m < 8; ++m) {
    #pragma unroll
    for (int nf = 0; nf < 4; ++nf) {
      #pragma unroll
      for (int q = 0; q < 4; ++q) {
        float vv = acc[m][nf][q];
        if (act == 2) vv = vv / (1.f + __expf(-vv));
        Cp[(size_t)(orow + (m >> 2)*64 + (m & 3)*16 + q) * Cc + ocol + nf*16] = f2b(vv);
      }
    }
  }
}

// ---------------- WKV6 pass 1: chunked matmul formulation (MFMA) ----------------
// Fused ew-GEMM (round 7). New: y and S outputs bounce through dead LDS
// buffers (kS for y; rS/vS for S) and flush with coalesced uint4 stores —
// replaces 24 scattered u16 stores per thread-group with 3 vector stores.
// Safety: kS last read in the A-matrix phase (before the A_lds barrier);
// rS/vS last read in the build phase (two barriers earlier).
__global__ __launch_bounds__(256) void wkv_pass1(u16* __restrict__ r,
    const u16* __restrict__ k, const u16* __restrict__ v,
    const float* __restrict__ wl1p, const u16* __restrict__ tdw2T,
    const float* __restrict__ tdecay, const float* __restrict__ u,
    u16* __restrict__ y, u16* __restrict__ S, float* __restrict__ D)
{
  __shared__ __align__(16) u16 rS[CHUNK][72];
  __shared__ __align__(16) u16 kS[CHUNK][72];
  __shared__ __align__(16) u16 vS[CHUNK][72];
  __shared__ __align__(16) u16 aW[CHUNK][72];        // tanh(sum wl1p) bf16
  __shared__ __align__(16) float bufEW[CHUNK][68];   // ew -> eR (in-place)
  __shared__ __align__(16) float eKnL[CHUNK][68];
  __shared__ __align__(16) u16 Rt[CHUNK][72];
  __shared__ __align__(16) u16 Kt[CHUNK][72];
  __shared__ __align__(16) u16 Ru[CHUNK][72];
  __shared__ __align__(16) u16 KhT[64][40];
  __shared__ __align__(16) u16 VT[64][40];
  __shared__ __align__(16) u16 A_lds[CHUNK][40];
  __shared__ float uL[64];
  __shared__ float Dl[64];

  const int blk = blockIdx.x;
  const int chunk = blk & (NCH-1);
  const int bh = blk >> 5;
  const int h = bh & (Hh-1);
  const int b = bh >> 4;
  const int tid = threadIdx.x;
  const int lane = tid & 63;
  const int wv = tid >> 6;
  const int fr = lane & 15;
  const int kc = lane >> 4;

  const int trow0 = b*Tt + chunk*CHUNK;
  const size_t rowbase = (size_t)trow0*Cc + h*64;
  {
    int tt = tid >> 3, c8 = (tid & 7)*8;
    size_t go = rowbase + (size_t)tt*Cc + c8;
    *(uint4*)&rS[tt][c8] = *(const uint4*)(r + go);
    *(uint4*)&kS[tt][c8] = *(const uint4*)(k + go);
    *(uint4*)&vS[tt][c8] = *(const uint4*)(v + go);
    // wl1 partial sum + tanh -> aW (bf16), K=64 row for this t
    size_t wrow = (size_t)(trow0 + tt)*64 + c8;
    float s8[8] = {0.f,0.f,0.f,0.f,0.f,0.f,0.f,0.f};
    #pragma unroll
    for (int z = 0; z < 4; ++z) {
      const float4* p = (const float4*)(wl1p + (size_t)z*262144 + wrow);
      float4 a = p[0], b2 = p[1];
      s8[0]+=a.x; s8[1]+=a.y; s8[2]+=a.z; s8[3]+=a.w;
      s8[4]+=b2.x; s8[5]+=b2.y; s8[6]+=b2.z; s8[7]+=b2.w;
    }
    u16 t8[8];
    #pragma unroll
    for (int j = 0; j < 8; ++j) t8[j] = f2b(fast_tanh(s8[j]));
    *(uint4*)&aW[tt][c8] = *(const uint4*)t8;
  }
  if (tid < 64) uL[tid] = u[h*64 + tid];
  __syncthreads();

  // ew MFMA: bufEW[t][i] = exp( (aW @ tdw2T^T)[t][i] + tdecay[h*64+i] )
  {
    const int icol = wv*16 + fr;
    const float bs = tdecay[h*64 + icol];
    #pragma unroll
    for (int tb = 0; tb < 2; ++tb) {
      f32x4 acc = {0.f,0.f,0.f,0.f};
      #pragma unroll
      for (int ks = 0; ks < 2; ++ks) {
        bf16x8 a  = *(const bf16x8*)&aW[tb*16+fr][kc*8 + ks*32];
        bf16x8 bb = *(const bf16x8*)(tdw2T + (size_t)(h*64 + icol)*64 + ks*32 + kc*8);
        acc = __builtin_amdgcn_mfma_f32_16x16x32_bf16(a, bb, acc, 0, 0, 0);
      }
      #pragma unroll
      for (int q = 0; q < 4; ++q)
        bufEW[tb*16 + kc*4 + q][icol] = __expf(acc[q] + bs);
    }
  }
  __syncthreads();

  if (tid < 64) {
    float eR = 1.f;
    for (int t = 0; t < CHUNK; ++t) {
      float e = bufEW[t][tid];
      bufEW[t][tid] = eR;                         // exp(lw[t-1])
      eR *= __expf(-e);                           // exp(lw[t])
      eKnL[t][tid] = __builtin_amdgcn_rcpf(eR);   // exp(-lw[t])
    }
    Dl[tid] = eR;
    D[(size_t)blk*64 + tid] = eR;
  }
  __syncthreads();

  {
    int t = tid >> 3, i0 = (tid & 7)*8;
    uint4 rv4 = *(const uint4*)&rS[t][i0];
    uint4 kv4 = *(const uint4*)&kS[t][i0];
    const uint* rw = (const uint*)&rv4;
    const uint* kw = (const uint*)&kv4;
    u16 rt8[8], kt8[8], ru8[8];
    #pragma unroll
    for (int q = 0; q < 8; ++q) {
      int i = i0 + q;
      float rv = (q & 1) ? bhi(rw[q>>1]) : blo(rw[q>>1]);
      float kv = (q & 1) ? bhi(kw[q>>1]) : blo(kw[q>>1]);
      float eR = bufEW[t][i];
      float eKn = eKnL[t][i];
      float ktv = kv * eKn;
      rt8[q] = f2b(rv * eR);
      kt8[q] = f2b(ktv);
      ru8[q] = f2b(rv * uL[i]);
      KhT[i][t] = f2b(ktv * Dl[i]);
      VT[i][t] = vS[t][i];
    }
    *(uint4*)&Rt[t][i0] = *(const uint4*)rt8;
    *(uint4*)&Kt[t][i0] = *(const uint4*)kt8;
    *(uint4*)&Ru[t][i0] = *(const uint4*)ru8;
  }
  __syncthreads();

  {
    const int wr = wv >> 1, wc = wv & 1;
    f32x4 accA = {0.f,0.f,0.f,0.f};
    f32x4 accD = {0.f,0.f,0.f,0.f};
    #pragma unroll
    for (int ks = 0; ks < 2; ++ks) {
      bf16x8 a  = *(const bf16x8*)&Rt[wr*16+fr][kc*8 + ks*32];
      bf16x8 bb = *(const bf16x8*)&Kt[wc*16+fr][kc*8 + ks*32];
      accA = __builtin_amdgcn_mfma_f32_16x16x32_bf16(a, bb, accA, 0, 0, 0);
      bf16x8 a2 = *(const bf16x8*)&Ru[wr*16+fr][kc*8 + ks*32];
      bf16x8 b2 = *(const bf16x8*)&kS[wc*16+fr][kc*8 + ks*32];
      accD = __builtin_amdgcn_mfma_f32_16x16x32_bf16(a2, b2, accD, 0, 0, 0);
    }
    #pragma unroll
    for (int q = 0; q < 4; ++q) {
      int trow = wr*16 + kc*4 + q;
      int scol = wc*16 + fr;
      float val = (scol < trow) ? accA[q] : ((scol == trow) ? accD[q] : 0.f);
      A_lds[trow][scol] = f2b(val);
    }
  }
  __syncthreads();
  // kS/rS/vS are dead from here (last reads above) -> reuse as store bounce.

  #pragma unroll
  for (int tb = 0; tb < 2; ++tb) {
    bf16x8 a  = *(const bf16x8*)&A_lds[tb*16+fr][kc*8];
    bf16x8 bb = *(const bf16x8*)&VT[wv*16+fr][kc*8];
    f32x4 acc = {0.f,0.f,0.f,0.f};
    acc = __builtin_amdgcn_mfma_f32_16x16x32_bf16(a, bb, acc, 0, 0, 0);
    #pragma unroll
    for (int q = 0; q < 4; ++q)
      kS[tb*16 + kc*4 + q][wv*16 + fr] = f2b(acc[q]);
  }
  #pragma unroll
  for (int jb = 0; jb < 4; ++jb) {
    bf16x8 a  = *(const bf16x8*)&KhT[wv*16+fr][kc*8];
    bf16x8 bb = *(const bf16x8*)&VT[jb*16+fr][kc*8];
    f32x4 acc = {0.f,0.f,0.f,0.f};
    acc = __builtin_amdgcn_mfma_f32_16x16x32_bf16(a, bb, acc, 0, 0, 0);
    #pragma unroll
    for (int q = 0; q < 4; ++q) {
      int i = kc*4 + q;     // row within the wave's 16-row band
      int j = jb*16 + fr;
      if (wv < 2) rS[wv*16 + i][j] = f2b(acc[q]);
      else        vS[(wv-2)*16 + i][j] = f2b(acc[q]);
    }
  }
  __syncthreads();
  { // coalesced y flush: 32 rows x 128B
    int row = tid >> 3, seg = tid & 7;
    *(uint4*)(y + rowbase + (size_t)row*Cc + seg*8) = *(const uint4*)&kS[row][seg*8];
  }
  #pragma unroll
  for (int rd = 0; rd < 2; ++rd) { // coalesced S flush: 64 rows x 128B
    int row = tid >> 2, s8 = (tid & 3) + rd*4;
    const u16* src = (row < 32) ? &rS[row][s8*8] : &vS[row-32][s8*8];
    *(uint4*)(S + ((size_t)blk*64 + row)*64 + s8*8) = *(const uint4*)src;
  }
  { // rc = R~ (in-place over r)
    int tt = tid >> 3, c8 = (tid & 7)*8;
    *(uint4*)(r + rowbase + (size_t)tt*Cc + c8) = *(const uint4*)&Rt[tt][c8];
  }
}

// ---------------- WKV6 pass 2: cross-chunk state propagation (in-place) ----------------
__global__ __launch_bounds__(256) void wkv_pass2(u16* __restrict__ S,
    const float* __restrict__ D)
{
  __shared__ float Dl[NCH][64];
  const int bh = blockIdx.x >> 2;
  const int jq = blockIdx.x & 3;
  const int tid = threadIdx.x;
  {
    const float4* src = (const float4*)(D + (size_t)bh*NCH*64);
    float4* dst = (float4*)&Dl[0][0];
    dst[tid] = src[tid];
    dst[tid + 256] = src[tid + 256];
  }
  __syncthreads();
  const int j = jq*16 + (tid & 15);
  const int i0 = (tid >> 4) * 4;
  const size_t base0 = (((size_t)bh*NCH)*64 + i0)*64 + j;
  u16 tmp[NCH][4];
  #pragma unroll
  for (int c = 0; c < NCH; ++c) {
    size_t base = base0 + (size_t)c*4096;
    #pragma unroll
    for (int ii = 0; ii < 4; ++ii) tmp[c][ii] = S[base + ii*64];
  }
  float Sr[4] = {0.f, 0.f, 0.f, 0.f};
  #pragma unroll
  for (int c = 0; c < NCH; ++c) {
    size_t base = base0 + (size_t)c*4096;
    #pragma unroll
    for (int ii = 0; ii < 4; ++ii) {
      S[base + ii*64] = f2b(Sr[ii]);
      Sr[ii] = fmaf(Sr[ii], Dl[c][i0+ii], b2f(tmp[c][ii]));
    }
  }
}

// ---------------- GroupNorm(H) + correction + gate, 8 rows/block ----------------
__global__ __launch_bounds__(256) void gn_gate(const u16* __restrict__ y,
   const u16* __restrict__ g, const u16* __restrict__ rc, const u16* __restrict__ S,
   const float* __restrict__ gamma, const float* __restrict__ beta, u16* __restrict__ out)
{
  __shared__ u16 rcl[8][Cc];
  const int bt0 = blockIdx.x * 8;
  const int b = bt0 >> 10;
  const int t0 = bt0 & (Tt-1);
  const int chunk = t0 >> 5;
  const int tid = threadIdx.x;
  #pragma unroll
  for (int rr = 0; rr < 8; ++rr)
    ((ushort4*)rcl[rr])[tid] = ((const ushort4*)(rc + (size_t)(bt0+rr)*Cc))[tid];
  __syncthreads();
  const int c0 = tid*4, h = c0 >> 6, j0 = c0 & 63;
  const u16* Sb = S + (((size_t)(b*Hh + h)*NCH + chunk)*64)*64 + j0;
  float corr[8][4];
  #pragma unroll
  for (int rr = 0; rr < 8; ++rr)
    #pragma unroll
    for (int q = 0; q < 4; ++q) corr[rr][q] = 0.f;
  #pragma unroll 4
  for (int i = 0; i < 64; ++i) {
    ushort4 sv = *(const ushort4*)(Sb + (size_t)i*64);
    float s0 = b2f(sv.x), s1 = b2f(sv.y), s2 = b2f(sv.z), s3 = b2f(sv.w);
    #pragma unroll
    for (int rr = 0; rr < 8; ++rr) {
      float rv = b2f(rcl[rr][h*64 + i]);
      corr[rr][0] = fmaf(rv, s0, corr[rr][0]);
      corr[rr][1] = fmaf(rv, s1, corr[rr][1]);
      corr[rr][2] = fmaf(rv, s2, corr[rr][2]);
      corr[rr][3] = fmaf(rv, s3, corr[rr][3]);
    }
  }
  float4 ga = ((const float4*)gamma)[tid];
  float4 be = ((const float4*)beta)[tid];
  #pragma unroll
  for (int rr = 0; rr < 8; ++rr) {
    size_t o4 = (size_t)(bt0+rr)*(Cc/4) + tid;
    ushort4 yv4 = ((const ushort4*)y)[o4];
    float y0 = b2f(yv4.x) + corr[rr][0];
    float y1 = b2f(yv4.y) + corr[rr][1];
    float y2 = b2f(yv4.z) + corr[rr][2];
    float y3 = b2f(yv4.w) + corr[rr][3];
    float s  = y0 + y1 + y2 + y3;
    float sq = y0*y0 + y1*y1 + y2*y2 + y3*y3;
    #pragma unroll
    for (int m = 1; m < 16; m <<= 1) {
      s  += __shfl_xor(s, m, 64);
      sq += __shfl_xor(sq, m, 64);
    }
    float mu  = s * (1.f/64.f);
    float var = sq * (1.f/64.f) - mu*mu;
    float rstd = rsqrtf(var + 6.4e-4f);
    ushort4 gu = ((const ushort4*)g)[o4];
    ushort4 ou;
    ou.x = f2b(((y0 - mu)*rstd*ga.x + be.x) * b2f(gu.x));
    ou.y = f2b(((y1 - mu)*rstd*ga.y + be.y) * b2f(gu.y));
    ou.z = f2b(((y2 - mu)*rstd*ga.z + be.z) * b2f(gu.z));
    ou.w = f2b(((y3 - mu)*rstd*ga.w + be.w) * b2f(gu.w));
    ((ushort4*)out)[o4] = ou;
  }
}

extern "C" void kernel_launch(void* const* d_in, const int* in_sizes, int n_in,
                              void* d_out, int out_size, void* d_ws, size_t ws_size,
                              hipStream_t stream) {
  const float* x      = (const float*)d_in[0];
  const float* maa_x  = (const float*)d_in[1];
  const float* maa_w  = (const float*)d_in[2];
  const float* maa_k  = (const float*)d_in[3];
  const float* maa_v  = (const float*)d_in[4];
  const float* maa_r  = (const float*)d_in[5];
  const float* maa_g  = (const float*)d_in[6];
  const float* w1     = (const float*)d_in[7];
  const float* w2     = (const float*)d_in[8];
  const float* tdecay = (const float*)d_in[9];
  const float* tdw1   = (const float*)d_in[10];
  const float* tdw2   = (const float*)d_in[11];
  const float* faaaa  = (const float*)d_in[12];
  const float* Wr     = (const float*)d_in[13];
  const float* Wk     = (const float*)d_in[14];
  const float* Wv     = (const float*)d_in[15];
  const float* Wg     = (const float*)d_in[16];
  const float* Wo     = (const float*)d_in[17];
  const float* gamma  = (const float*)d_in[18];
  const float* beta   = (const float*)d_in[19];
  float* out = (float*)d_out;

  const size_t MB = 1u << 20;
  char* wsb = (char*)d_ws;
  float* m1p  = (float*)(wsb + 0);            // 10.5M fp32 m1 k-partials (step2->3)
  float* wl1p = (float*)(wsb + 0);            // 4M fp32 wl1 k-partials (step4->6; over dead m1p)
  u16*   w2T  = (u16*)(wsb + 12*MB);          // 320K bf16 w2 transposed (step0->3)
  u16*   xk   = (u16*)(wsb + 16*MB);          // 8M
  u16*   xv   = (u16*)(wsb + 24*MB);          // 8M
  u16*   xr   = (u16*)(wsb + 32*MB);          // 8M -> gated
  u16*   xg   = (u16*)(wsb + 40*MB);          // 8M
  u16*   xw   = (u16*)(wsb + 48*MB);          // 8M (dead after wl1)
  u16*   rbuf = (u16*)(wsb + 56*MB);          // 8M (r -> rc in-place)
  u16*   kbuf = (u16*)(wsb + 64*MB);          // 8M
  u16*   vbuf = (u16*)(wsb + 72*MB);          // 8M
  u16*   gbuf = (u16*)(wsb + 80*MB);          // 8M
  float* Dbuf = (float*)(wsb + 88*MB);        // 512K
  u16*   Sbuf = (u16*)(wsb + 16*MB);          // 16M over xk+xv (dead by pass1)
  u16*   BW0  = (u16*)(wsb + 88*MB + 512*1024);
  u16*   BW1  = (u16*)((char*)BW0 + 2*MB);
  u16*   BW2  = (u16*)((char*)BW1 + 2*MB);
  u16*   BW3  = (u16*)((char*)BW2 + 2*MB);
  u16*   BW4  = (u16*)((char*)BW3 + 2*MB);    // ends 98.5M
  u16*   w1T  = (u16*)((char*)BW4 + 2*MB);    // 320K
  u16*   tdw1T = (u16*)(wsb + 99*MB);
  u16*   tdw2T = (u16*)(wsb + 99*MB + 256*1024);
  u16*   gated = xr;
  u16*   xxx16 = (u16*)d_out;
  u16*   yb16  = (u16*)d_out;                 // 8M bf16 y (step6->7)

  dim3 blk(256);
  // 0+1. merged: weight transpose (z<9) + prep xxx (z>=9)
  WPack wp;
  wp.p[0] = {Wr, BW0, Cc, Cc};  wp.p[1] = {Wk, BW1, Cc, Cc};
  wp.p[2] = {Wv, BW2, Cc, Cc};  wp.p[3] = {Wg, BW3, Cc, Cc};
  wp.p[4] = {Wo, BW4, Cc, Cc};  wp.p[5] = {w1, w1T, Cc, 160};
  wp.p[6] = {tdw1, tdw1T, Cc, 64}; wp.p[7] = {tdw2, tdw2T, 64, Cc};
  wp.p[8] = {w2, w2T, 160, Cc};
  prep_transW<<<dim3(32,32,13), blk, 0, stream>>>(wp, x, maa_x, xxx16);
  // 2. m1 partials = xxx @ w1 (K-split z=4, fp32; tanh applied in mix_mfma)
  gemm_ksplit<<<dim3(2, 32, 4), blk, 0, stream>>>(xxx16, w1T, m1p, Cc, 256, 160);
  // 3. fused MFMA mix -> xw,xk,xv,xr,xg (all bf16; block-staged aW + xS)
  mix_mfma<<<1024, blk, 0, stream>>>(x, m1p, w2T, maa_w, maa_k, maa_v, maa_r, maa_g,
                                     xw, xk, xv, xr, xg);
  // 4. wl1 partials = xw @ tdw1 (K-split z=4, fp32; consumed inside wkv_pass1)
  gemm_ksplit<<<dim3(1, 32, 4), blk, 0, stream>>>(xw, tdw1T, wl1p, Cc, 256, 64);
  // 5. r,k,v,g batched — 256x256 4-phase kernel, 256 blocks
  GPack gp;
  gp.A[0] = xr; gp.A[1] = xk; gp.A[2] = xv; gp.A[3] = xg;
  gp.B[0] = BW0; gp.B[1] = BW1; gp.B[2] = BW2; gp.B[3] = BW3;
  gp.C[0] = rbuf; gp.C[1] = kbuf; gp.C[2] = vbuf; gp.C[3] = gbuf;
  gemm_rkvg256<<<dim3(4, 16, 4), dim3(512), 0, stream>>>(gp);
  // 6. wkv chunked scan (fused ew-GEMM; coalesced y/S flush)
  wkv_pass1<<<Bb*Hh*NCH, blk, 0, stream>>>(rbuf, kbuf, vbuf, wl1p, tdw2T, tdecay,
                                           faaaa, yb16, Sbuf, Dbuf);
  wkv_pass2<<<Bb*Hh*4, blk, 0, stream>>>(Sbuf, Dbuf);
  // 7. groupnorm + correction + gate
  gn_gate<<<BT/8, blk, 0, stream>>>(yb16, gbuf, rbuf, Sbuf, gamma, beta, gated);
  // 8. out = gated @ Wo (fp32)
  gemm_mfma<0,true><<<dim3(8, 32), blk, 0, stream>>>(gated, BW4, out, nullptr, Cc, Cc);
}

// Round 9
// 174.179 us; speedup vs baseline: 1.1521x; 1.0344x over previous
//
#include <hip/hip_runtime.h>

#define Bb 4
#define Tt 1024
#define Cc 1024
#define Hh 16
#define BT (Bb*Tt)
#define CHUNK 32
#define NCH (Tt/CHUNK)

typedef unsigned int uint;
typedef unsigned short u16;
typedef __bf16 bf16x8 __attribute__((ext_vector_type(8)));
typedef float f32x4 __attribute__((ext_vector_type(4)));
typedef const __attribute__((address_space(1))) uint GU;
typedef __attribute__((address_space(3))) uint LU;

__device__ __forceinline__ float blo(uint u) { return __uint_as_float(u << 16); }
__device__ __forceinline__ float bhi(uint u) { return __uint_as_float(u & 0xffff0000u); }
__device__ __forceinline__ float b2f(u16 u) { return __uint_as_float(((uint)u) << 16); }
__device__ __forceinline__ u16 f2b(float f) {
  uint u = __float_as_uint(f);
  return (u16)((u + 0x7fffu + ((u >> 16) & 1u)) >> 16);   // RNE
}
// fast tanh: 1 - 2/(e^{2x}+1); exact limits at +-inf, rel err ~2^-21
__device__ __forceinline__ float fast_tanh(float x) {
  float e = __expf(2.f * x);
  return 1.f - 2.f / (e + 1.f);
}

// ---------------- merged: weight transpose (z<9) + prep_xxx (z>=9) ----------
struct WPair { const float* s; u16* d; int K; int N; };
struct WPack { WPair p[9]; };

__global__ __launch_bounds__(256) void prep_transW(WPack wp,
    const float* __restrict__ x, const float* __restrict__ maa_x,
    u16* __restrict__ xxx)
{
  __shared__ float tile[32][33];
  if (blockIdx.z < 9) {
    WPair pr = wp.p[blockIdx.z];
    int c0 = blockIdx.x*32, r0 = blockIdx.y*32;
    if (c0 >= pr.N || r0 >= pr.K) return;
    int tc = threadIdx.x & 31, tr = threadIdx.x >> 5;
    #pragma unroll
    for (int p = 0; p < 4; ++p)
      tile[tr + p*8][tc] = pr.s[(size_t)(r0 + tr + p*8)*pr.N + c0 + tc];
    __syncthreads();
    #pragma unroll
    for (int p = 0; p < 4; ++p) {
      int n = tr + p*8;
      pr.d[(size_t)(c0 + n)*pr.K + r0 + tc] = f2b(tile[tc][n]);
    }
  } else {
    int vb = (blockIdx.z - 9)*1024 + blockIdx.y*32 + blockIdx.x;  // 0..4095
    int idx = vb*256 + threadIdx.x;
    int c4 = idx & 255;
    int bt = idx >> 8;
    int t = bt & (Tt-1);
    float4 xc = ((const float4*)x)[idx];
    float4 xp = make_float4(0.f,0.f,0.f,0.f);
    if (t > 0) xp = ((const float4*)x)[idx - 256];
    float4 mx = ((const float4*)maa_x)[c4];
    ushort4 o;
    o.x = f2b(fmaf(xp.x - xc.x, mx.x, xc.x));
    o.y = f2b(fmaf(xp.y - xc.y, mx.y, xc.y));
    o.z = f2b(fmaf(xp.z - xc.z, mx.z, xc.z));
    o.w = f2b(fmaf(xp.w - xc.w, mx.w, xc.w));
    ((ushort4*)xxx)[idx] = o;
  }
}

// ---------------- fused mix: MFMA (tanh Σ m1-partials)@w2 + epilogue ----------
// Block = 16 rows x 256 cols. Stage aW + xS cooperatively (round 8). NEW in
// round 9: the wl1 K-split partial GEMM is fused here — at f=0 the block's
// strip LDS holds the exact 16x256 bf16 xw tile that IS the z=cb K-slab of
// wl1p, so each wave computes its K=64 partial (8 MFMAs, tdw1T L2-hot), and
// the 4 wave-partials reduce through the dead xS buffer into wl1p[cb].
// xw is never materialized to HBM; the wl1 ksplit launch is gone.
__global__ __launch_bounds__(256) void mix_mfma(
    const float* __restrict__ x, const float* __restrict__ m1p,
    const u16* __restrict__ w2T, const u16* __restrict__ tdw1T,
    const float* __restrict__ maa_w, const float* __restrict__ maa_k,
    const float* __restrict__ maa_v, const float* __restrict__ maa_r,
    const float* __restrict__ maa_g,
    float* __restrict__ wl1p,
    u16* __restrict__ xk, u16* __restrict__ xv,
    u16* __restrict__ xr, u16* __restrict__ xg)
{
  __shared__ __align__(16) u16 aW[16][168];
  __shared__ __align__(16) float xS[17][260];     // reused as wl1 reduction buf
  __shared__ __align__(16) u16 strip[4][16][72];
  const int tid = threadIdx.x;
  const int lane = tid & 63;
  const int wv = tid >> 6;
  const int rs = blockIdx.x >> 2;          // 0..255
  const int cb = blockIdx.x & 3;           // 0..3
  const int r0 = rs*16;
  const int c0b = cb*256;
  const int fr = lane & 15, kc = lane >> 4;
  const bool firstrow = (r0 & (Tt-1)) == 0;

  // stage aW (640 float4-tasks: 5 f x 16 rows x 8 col4)
  for (int task = tid; task < 640; task += 256) {
    int f  = task >> 7;
    int r  = (task >> 3) & 15;
    int c4 = task & 7;
    size_t off = (size_t)(r0 + r)*160 + f*32 + c4*4;
    float4 s = *(const float4*)(m1p + off);
    #pragma unroll
    for (int z = 1; z < 4; ++z) {
      float4 p = *(const float4*)(m1p + (size_t)z*655360 + off);
      s.x += p.x; s.y += p.y; s.z += p.z; s.w += p.w;
    }
    ushort4 t4;
    t4.x = f2b(fast_tanh(s.x)); t4.y = f2b(fast_tanh(s.y));
    t4.z = f2b(fast_tanh(s.z)); t4.w = f2b(fast_tanh(s.w));
    *(ushort4*)&aW[r][f*32 + c4*4] = t4;
  }
  // stage x rows r0-1..r0+15, cols c0b..c0b+255 (1088 float4-tasks)
  for (int i = tid; i < 1088; i += 256) {
    int r17 = i >> 6;            // 0..16
    int c4  = i & 63;
    float4 v = make_float4(0.f,0.f,0.f,0.f);
    if (!(r17 == 0 && firstrow))
      v = *(const float4*)(x + (size_t)(r0 - 1 + r17)*Cc + c0b + c4*4);
    *(float4*)&xS[r17][c4*4] = v;
  }
  __syncthreads();

  const int c0 = c0b + wv*64;
  float xc[4][4], xd[4][4];
  #pragma unroll
  for (int n = 0; n < 4; ++n) {
    int cl = wv*64 + n*16 + fr;
    #pragma unroll
    for (int q = 0; q < 4; ++q) {
      int rl = kc*4 + q;
      float v = xS[rl + 1][cl];
      float p = xS[rl][cl];
      xc[n][q] = v;
      xd[n][q] = p - v;
    }
  }

  u16* const outs[5] = {nullptr, xk, xv, xr, xg};
  const float* const maas[5] = {maa_w, maa_k, maa_v, maa_r, maa_g};
  f32x4 wacc[4];
  #pragma unroll
  for (int n = 0; n < 4; ++n) wacc[n] = f32x4{0.f,0.f,0.f,0.f};

  #pragma unroll
  for (int f = 0; f < 5; ++f) {
    bf16x8 af = *(const bf16x8*)&aW[fr][f*32 + kc*8];
    f32x4 acc[4];
    #pragma unroll
    for (int n = 0; n < 4; ++n) {
      bf16x8 bg = *(const bf16x8*)(w2T + (size_t)(c0 + n*16 + fr)*160 + f*32 + kc*8);
      acc[n] = __builtin_amdgcn_mfma_f32_16x16x32_bf16(af, bg, f32x4{0.f,0.f,0.f,0.f}, 0, 0, 0);
    }
    const float* __restrict__ ma = maas[f];
    #pragma unroll
    for (int n = 0; n < 4; ++n) {
      int colL = n*16 + fr;
      float mv = ma[c0 + colL];
      #pragma unroll
      for (int q = 0; q < 4; ++q)
        strip[wv][kc*4 + q][colL] = f2b(fmaf(xd[n][q], mv + acc[n][q], xc[n][q]));
    }
    if (f == 0) {
      // wl1 partial: (xw strip 16x64K) @ tdw1T -> wacc (K=64 per wave)
      #pragma unroll
      for (int ks = 0; ks < 2; ++ks) {
        bf16x8 a = *(const bf16x8*)&strip[wv][fr][ks*32 + kc*8];
        #pragma unroll
        for (int n2 = 0; n2 < 4; ++n2) {
          bf16x8 bg2 = *(const bf16x8*)(tdw1T + (size_t)(n2*16 + fr)*Cc + c0 + ks*32 + kc*8);
          wacc[n2] = __builtin_amdgcn_mfma_f32_16x16x32_bf16(a, bg2, wacc[n2], 0, 0, 0);
        }
      }
    } else {
      u16* __restrict__ op = outs[f];
      #pragma unroll
      for (int rd = 0; rd < 2; ++rd) {
        int r8 = (lane >> 3) + rd*8;
        uint4 v = *(const uint4*)&strip[wv][r8][(lane & 7)*8];
        *(uint4*)(op + (size_t)(r0 + r8)*Cc + c0 + (lane & 7)*8) = v;
      }
    }
  }

  // cross-wave wl1 reduction through dead xS (all xS reads happened pre-loop)
  __syncthreads();
  float* red = (float*)&xS[0][0];           // [4][16][68]
  #pragma unroll
  for (int n2 = 0; n2 < 4; ++n2)
    #pragma unroll
    for (int q = 0; q < 4; ++q)
      red[wv*1088 + (kc*4 + q)*68 + n2*16 + fr] = wacc[n2][q];
  __syncthreads();
  {
    int row = tid >> 4, c4 = (tid & 15) * 4;
    float4 s = make_float4(0.f,0.f,0.f,0.f);
    #pragma unroll
    for (int w2i = 0; w2i < 4; ++w2i) {
      float4 p = *(const float4*)&red[w2i*1088 + row*68 + c4];
      s.x += p.x; s.y += p.y; s.z += p.z; s.w += p.w;
    }
    *(float4*)(wl1p + (size_t)cb*262144 + (size_t)(r0 + row)*64 + c4) = s;
  }
}

// ---------------- bf16 MFMA GEMM core (m97 structure + chunk swizzle) ----------------
// ld: row stride (elems) of A and Bt; kloop: K extent to accumulate (<= ld).
template<bool OUTF32>
__device__ __forceinline__ void mfma_core(
    const u16* __restrict__ A, const u16* __restrict__ Bt,
    void* __restrict__ Cout, const float* __restrict__ bias,
    int ld, int kloop, int N, int act)
{
  __shared__ __align__(16) u16 lds[2][2][128*32];   // 32 KB
  const int tid = threadIdx.x;
  const int lane = tid & 63;
  const int wv = __builtin_amdgcn_readfirstlane(tid >> 6);

  // bijective XCD swizzle (requires gridDim.y % 8 == 0)
  const int nby8 = gridDim.y >> 3;
  const int i_lin = blockIdx.y * gridDim.x + blockIdx.x;
  const int cx = i_lin & 7, rest = i_lin >> 3;
  const int bm = (cx * nby8 + rest % nby8) * 128;
  const int bn = (rest / nby8) * 128;

  const int wm = (wv >> 1) * 64;
  const int wn = (wv & 1) * 64;
  const int kc = lane >> 4;
  const int fr = lane & 15;

  const int srow = wv*16 + (lane >> 2);
  const int ssw  = (srow >> 1) & 3;                 // == s(srow+64)
  const int scol = ((lane & 3) ^ ssw) * 8;
  const size_t aoff = (size_t)(bm + srow) * ld + scol;
  const size_t boff = (size_t)(bn + srow) * ld + scol;

#define STAGE(bufi, kt) do { \
    size_t ko_ = (size_t)(kt) * 32; \
    __builtin_amdgcn_global_load_lds((GU*)(A + aoff + ko_), \
        (LU*)&lds[bufi][0][wv*512], 16, 0, 0); \
    __builtin_amdgcn_global_load_lds((GU*)(A + aoff + (size_t)64*ld + ko_), \
        (LU*)&lds[bufi][0][wv*512 + 64*32], 16, 0, 0); \
    __builtin_amdgcn_global_load_lds((GU*)(Bt + boff + ko_), \
        (LU*)&lds[bufi][1][wv*512], 16, 0, 0); \
    __builtin_amdgcn_global_load_lds((GU*)(Bt + boff + (size_t)64*ld + ko_), \
        (LU*)&lds[bufi][1][wv*512 + 64*32], 16, 0, 0); \
  } while(0)

  int ard[4], brd[4];
  #pragma unroll
  for (int m = 0; m < 4; ++m) {
    int ra = wm + m*16 + fr;
    int rb = wn + m*16 + fr;
    ard[m] = ra*32 + (kc ^ ((ra >> 1) & 3))*8;
    brd[m] = rb*32 + (kc ^ ((rb >> 1) & 3))*8;
  }

  f32x4 acc[4][4];
  #pragma unroll
  for (int m = 0; m < 4; ++m)
    #pragma unroll
    for (int n = 0; n < 4; ++n)
      acc[m][n] = f32x4{0.f, 0.f, 0.f, 0.f};

  const int NK = kloop >> 5;
  STAGE(0, 0);
  __syncthreads();
  int buf = 0;
  for (int kt = 0; kt < NK; ++kt) {
    if (kt + 1 < NK) STAGE(buf^1, kt+1);
    bf16x8 af[4], bg[4];
    #pragma unroll
    for (int m = 0; m < 4; ++m) af[m] = *(const bf16x8*)&lds[buf][0][ard[m]];
    #pragma unroll
    for (int n = 0; n < 4; ++n) bg[n] = *(const bf16x8*)&lds[buf][1][brd[n]];
    #pragma unroll
    for (int m = 0; m < 4; ++m)
      #pragma unroll
      for (int n = 0; n < 4; ++n)
        acc[m][n] = __builtin_amdgcn_mfma_f32_16x16x32_bf16(af[m], bg[n], acc[m][n], 0, 0, 0);
    __syncthreads();
    buf ^= 1;
  }
#undef STAGE

  const int orow = bm + wm + (lane >> 4) * 4;
  const int ocol = bn + wn + fr;
  #pragma unroll
  for (int m = 0; m < 4; ++m) {
    #pragma unroll
    for (int n = 0; n < 4; ++n) {
      int col = ocol + n*16;
      if (col < N) {
        float bs = bias ? bias[col] : 0.f;
        #pragma unroll
        for (int q = 0; q < 4; ++q) {
          float vv = acc[m][n][q] + bs;
          if (act == 1) vv = tanhf(vv);
          else if (act == 2) vv = vv / (1.f + __expf(-vv));
          size_t off = (size_t)(orow + m*16 + q) * N + col;
          if (OUTF32) ((float*)Cout)[off] = vv;
          else ((u16*)Cout)[off] = f2b(vv);
        }
      }
    }
  }
}

template<int ACT, bool OUTF32>
__global__ __launch_bounds__(256) void gemm_mfma(
    const u16* __restrict__ A, const u16* __restrict__ Bt,
    void* __restrict__ Cout, const float* __restrict__ bias, int K, int N)
{
  mfma_core<OUTF32>(A, Bt, Cout, bias, K, K, N, ACT);
}

// K-split GEMM: z-th block-slab accumulates k in [z*ksz, (z+1)*ksz), writes
// raw fp32 partials to Cp + z*4096*N. No activation (applied at consumer).
__global__ __launch_bounds__(256) void gemm_ksplit(
    const u16* __restrict__ A, const u16* __restrict__ Bt,
    float* __restrict__ Cp, int ld, int ksz, int N)
{
  const int z = blockIdx.z;
  mfma_core<true>(A + (size_t)z*ksz, Bt + (size_t)z*ksz,
                  Cp + (size_t)z*4096*N, nullptr, ld, ksz, N, 0);
}

// ---------------- 256x256 4-phase GEMM for the big batched r/k/v/g GEMMs ----------------
struct GPack { const u16* A[4]; const u16* B[4]; u16* C[4]; };

#define VMW(n) asm volatile("s_waitcnt vmcnt(" #n ")" ::: "memory")
#define LGKM0() asm volatile("s_waitcnt lgkmcnt(0)" ::: "memory")
#define SCHB() __builtin_amdgcn_sched_barrier(0)
#define HBAR() __builtin_amdgcn_s_barrier()

__global__ __launch_bounds__(512) void gemm_rkvg256(GPack gp) {
  __shared__ __align__(16) u16 lds[2][2][2][8192];   // [dbuf][A/B][khalf][256*32] = 128 KB
  const int z = blockIdx.z;
  const u16* __restrict__ Ap  = gp.A[z];
  const u16* __restrict__ Btp = gp.B[z];
  u16* __restrict__ Cp = gp.C[z];
  const int act = (z == 3) ? 2 : 0;

  const int tid = threadIdx.x;
  const int lane = tid & 63;
  const int wv = __builtin_amdgcn_readfirstlane(tid >> 6);

  const int i_lin = blockIdx.y * gridDim.x + blockIdx.x;   // 0..63
  const int tile = (i_lin & 7) * 8 + (i_lin >> 3);
  const int bm = (tile >> 2) * 256;
  const int bn = (tile & 3) * 256;

  const int wm = (wv >> 2) * 128;    // 2 wave-rows of 128
  const int wn = (wv & 3) * 64;      // 4 wave-cols of 64
  const int kc = lane >> 4;
  const int fr = lane & 15;

  const int srow0 = (wv*2 + 0)*16 + (lane >> 2);
  const int srow1 = (wv*2 + 1)*16 + (lane >> 2);
  const int sc0 = ((lane & 3) ^ ((srow0 >> 1) & 3)) * 8;
  const int sc1 = ((lane & 3) ^ ((srow1 >> 1) & 3)) * 8;
  const size_t aoff0 = (size_t)(bm + srow0)*Cc + sc0;
  const size_t aoff1 = (size_t)(bm + srow1)*Cc + sc1;
  const size_t boff0 = (size_t)(bn + srow0)*Cc + sc0;
  const size_t boff1 = (size_t)(bn + srow1)*Cc + sc1;

  int ard[8], brd[4];
  #pragma unroll
  for (int mh = 0; mh < 2; ++mh)
    #pragma unroll
    for (int mf = 0; mf < 4; ++mf) {
      int r = wm + mh*64 + mf*16 + fr;
      ard[mh*4+mf] = r*32 + (kc ^ ((r >> 1) & 3))*8;
    }
  #pragma unroll
  for (int nf = 0; nf < 4; ++nf) {
    int r = wn + nf*16 + fr;
    brd[nf] = r*32 + (kc ^ ((r >> 1) & 3))*8;
  }

  f32x4 acc[8][4];
  #pragma unroll
  for (int m = 0; m < 8; ++m)
    #pragma unroll
    for (int n = 0; n < 4; ++n)
      acc[m][n] = f32x4{0.f, 0.f, 0.f, 0.f};

#define STG256(DB, MAT, KH, kt, off0, off1, src) do { \
    u16* dst_ = &lds[(DB)][(MAT)][(KH)][wv*1024]; \
    __builtin_amdgcn_global_load_lds((GU*)((src) + (off0) + (size_t)(kt)*64 + (KH)*32), \
        (LU*)dst_, 16, 0, 0); \
    __builtin_amdgcn_global_load_lds((GU*)((src) + (off1) + (size_t)(kt)*64 + (KH)*32), \
        (LU*)(dst_ + 512), 16, 0, 0); \
  } while(0)

#define PH256(cur, KH, MH, LOADB, STMAT, STKH, DOSTAGE, VMTOK) do { \
    _Pragma("unroll") \
    for (int mf = 0; mf < 4; ++mf) \
      af[mf] = *(const bf16x8*)&lds[(cur)][0][KH][ard[(MH)*4+mf]]; \
    if (LOADB) { \
      _Pragma("unroll") \
      for (int nf = 0; nf < 4; ++nf) \
        bg[nf] = *(const bf16x8*)&lds[(cur)][1][KH][brd[nf]]; \
    } \
    if (DOSTAGE) { \
      if ((STMAT) == 0) STG256((cur)^1, 0, STKH, t+1, aoff0, aoff1, Ap); \
      else              STG256((cur)^1, 1, STKH, t+1, boff0, boff1, Btp); \
    } \
    VMTOK; \
    SCHB(); \
    HBAR(); \
    LGKM0(); \
    SCHB(); \
    __builtin_amdgcn_s_setprio(1); \
    _Pragma("unroll") \
    for (int mf = 0; mf < 4; ++mf) \
      _Pragma("unroll") \
      for (int nf = 0; nf < 4; ++nf) \
        acc[(MH)*4+mf][nf] = __builtin_amdgcn_mfma_f32_16x16x32_bf16(af[mf], bg[nf], acc[(MH)*4+mf][nf], 0, 0, 0); \
    __builtin_amdgcn_s_setprio(0); \
    SCHB(); \
    HBAR(); \
  } while(0)

  const int NK = Cc >> 6;   // 16 K-tiles of 64

  STG256(0, 0, 0, 0, aoff0, aoff1, Ap);
  STG256(0, 1, 0, 0, boff0, boff1, Btp);
  STG256(0, 0, 1, 0, aoff0, aoff1, Ap);
  STG256(0, 1, 1, 0, boff0, boff1, Btp);
  VMW(4);
  SCHB();
  HBAR();

  bf16x8 af[4], bg[4];
  int t;
  #pragma unroll 2
  for (t = 0; t < NK - 1; ++t) {
    const int cur = t & 1;
    PH256(cur, 0, 0, true,  0, 0, true,  (void)0);
    PH256(cur, 0, 1, false, 1, 0, true,  VMW(4));
    PH256(cur, 1, 0, true,  0, 1, true,  (void)0);
    PH256(cur, 1, 1, false, 1, 1, true,  VMW(4));
  }
  { // final K-tile: no prefetch; full drain before its second k-half
    const int cur = t & 1;
    PH256(cur, 0, 0, true,  0, 0, false, (void)0);
    PH256(cur, 0, 1, false, 0, 0, false, VMW(0));
    PH256(cur, 1, 0, true,  0, 0, false, (void)0);
    PH256(cur, 1, 1, false, 0, 0, false, (void)0);
  }
#undef PH256
#undef STG256

  const int orow = bm + wm + (lane >> 4) * 4;
  const int ocol = bn + wn + fr;
  #pragma unroll
  for (int m = 0; m < 8; ++m) {
    #pragma unroll
    for (int nf = 0; nf < 4; ++nf) {
      #pragma unroll
      for (int q = 0; q < 4; ++q) {
        float vv = acc[m][nf][q];
        if (act == 2) vv = vv / (1.f + __expf(-vv));
        Cp[(size_t)(orow + (m >> 2)*64 + (m & 3)*16 + q) * Cc + ocol + nf*16] = f2b(vv);
      }
    }
  }
}

// ---------------- WKV6 pass 1: chunked matmul formulation (MFMA) ----------------
// Fused ew-GEMM; coalesced y/S flush via dead LDS buffers (round 8).
__global__ __launch_bounds__(256) void wkv_pass1(u16* __restrict__ r,
    const u16* __restrict__ k, const u16* __restrict__ v,
    const float* __restrict__ wl1p, const u16* __restrict__ tdw2T,
    const float* __restrict__ tdecay, const float* __restrict__ u,
    u16* __restrict__ y, u16* __restrict__ S, float* __restrict__ D)
{
  __shared__ __align__(16) u16 rS[CHUNK][72];
  __shared__ __align__(16) u16 kS[CHUNK][72];
  __shared__ __align__(16) u16 vS[CHUNK][72];
  __shared__ __align__(16) u16 aW[CHUNK][72];        // tanh(sum wl1p) bf16
  __shared__ __align__(16) float bufEW[CHUNK][68];   // ew -> eR (in-place)
  __shared__ __align__(16) float eKnL[CHUNK][68];
  __shared__ __align__(16) u16 Rt[CHUNK][72];
  __shared__ __align__(16) u16 Kt[CHUNK][72];
  __shared__ __align__(16) u16 Ru[CHUNK][72];
  __shared__ __align__(16) u16 KhT[64][40];
  __shared__ __align__(16) u16 VT[64][40];
  __shared__ __align__(16) u16 A_lds[CHUNK][40];
  __shared__ float uL[64];
  __shared__ float Dl[64];

  const int blk = blockIdx.x;
  const int chunk = blk & (NCH-1);
  const int bh = blk >> 5;
  const int h = bh & (Hh-1);
  const int b = bh >> 4;
  const int tid = threadIdx.x;
  const int lane = tid & 63;
  const int wv = tid >> 6;
  const int fr = lane & 15;
  const int kc = lane >> 4;

  const int trow0 = b*Tt + chunk*CHUNK;
  const size_t rowbase = (size_t)trow0*Cc + h*64;
  {
    int tt = tid >> 3, c8 = (tid & 7)*8;
    size_t go = rowbase + (size_t)tt*Cc + c8;
    *(uint4*)&rS[tt][c8] = *(const uint4*)(r + go);
    *(uint4*)&kS[tt][c8] = *(const uint4*)(k + go);
    *(uint4*)&vS[tt][c8] = *(const uint4*)(v + go);
    // wl1 partial sum + tanh -> aW (bf16), K=64 row for this t
    size_t wrow = (size_t)(trow0 + tt)*64 + c8;
    float s8[8] = {0.f,0.f,0.f,0.f,0.f,0.f,0.f,0.f};
    #pragma unroll
    for (int z = 0; z < 4; ++z) {
      const float4* p = (const float4*)(wl1p + (size_t)z*262144 + wrow);
      float4 a = p[0], b2 = p[1];
      s8[0]+=a.x; s8[1]+=a.y; s8[2]+=a.z; s8[3]+=a.w;
      s8[4]+=b2.x; s8[5]+=b2.y; s8[6]+=b2.z; s8[7]+=b2.w;
    }
    u16 t8[8];
    #pragma unroll
    for (int j = 0; j < 8; ++j) t8[j] = f2b(fast_tanh(s8[j]));
    *(uint4*)&aW[tt][c8] = *(const uint4*)t8;
  }
  if (tid < 64) uL[tid] = u[h*64 + tid];
  __syncthreads();

  // ew MFMA: bufEW[t][i] = exp( (aW @ tdw2T^T)[t][i] + tdecay[h*64+i] )
  {
    const int icol = wv*16 + fr;
    const float bs = tdecay[h*64 + icol];
    #pragma unroll
    for (int tb = 0; tb < 2; ++tb) {
      f32x4 acc = {0.f,0.f,0.f,0.f};
      #pragma unroll
      for (int ks = 0; ks < 2; ++ks) {
        bf16x8 a  = *(const bf16x8*)&aW[tb*16+fr][kc*8 + ks*32];
        bf16x8 bb = *(const bf16x8*)(tdw2T + (size_t)(h*64 + icol)*64 + ks*32 + kc*8);
        acc = __builtin_amdgcn_mfma_f32_16x16x32_bf16(a, bb, acc, 0, 0, 0);
      }
      #pragma unroll
      for (int q = 0; q < 4; ++q)
        bufEW[tb*16 + kc*4 + q][icol] = __expf(acc[q] + bs);
    }
  }
  __syncthreads();

  if (tid < 64) {
    float eR = 1.f;
    for (int t = 0; t < CHUNK; ++t) {
      float e = bufEW[t][tid];
      bufEW[t][tid] = eR;                         // exp(lw[t-1])
      eR *= __expf(-e);                           // exp(lw[t])
      eKnL[t][tid] = __builtin_amdgcn_rcpf(eR);   // exp(-lw[t])
    }
    Dl[tid] = eR;
    D[(size_t)blk*64 + tid] = eR;
  }
  __syncthreads();

  {
    int t = tid >> 3, i0 = (tid & 7)*8;
    uint4 rv4 = *(const uint4*)&rS[t][i0];
    uint4 kv4 = *(const uint4*)&kS[t][i0];
    const uint* rw = (const uint*)&rv4;
    const uint* kw = (const uint*)&kv4;
    u16 rt8[8], kt8[8], ru8[8];
    #pragma unroll
    for (int q = 0; q < 8; ++q) {
      int i = i0 + q;
      float rv = (q & 1) ? bhi(rw[q>>1]) : blo(rw[q>>1]);
      float kv = (q & 1) ? bhi(kw[q>>1]) : blo(kw[q>>1]);
      float eR = bufEW[t][i];
      float eKn = eKnL[t][i];
      float ktv = kv * eKn;
      rt8[q] = f2b(rv * eR);
      kt8[q] = f2b(ktv);
      ru8[q] = f2b(rv * uL[i]);
      KhT[i][t] = f2b(ktv * Dl[i]);
      VT[i][t] = vS[t][i];
    }
    *(uint4*)&Rt[t][i0] = *(const uint4*)rt8;
    *(uint4*)&Kt[t][i0] = *(const uint4*)kt8;
    *(uint4*)&Ru[t][i0] = *(const uint4*)ru8;
  }
  __syncthreads();

  {
    const int wr = wv >> 1, wc = wv & 1;
    f32x4 accA = {0.f,0.f,0.f,0.f};
    f32x4 accD = {0.f,0.f,0.f,0.f};
    #pragma unroll
    for (int ks = 0; ks < 2; ++ks) {
      bf16x8 a  = *(const bf16x8*)&Rt[wr*16+fr][kc*8 + ks*32];
      bf16x8 bb = *(const bf16x8*)&Kt[wc*16+fr][kc*8 + ks*32];
      accA = __builtin_amdgcn_mfma_f32_16x16x32_bf16(a, bb, accA, 0, 0, 0);
      bf16x8 a2 = *(const bf16x8*)&Ru[wr*16+fr][kc*8 + ks*32];
      bf16x8 b2 = *(const bf16x8*)&kS[wc*16+fr][kc*8 + ks*32];
      accD = __builtin_amdgcn_mfma_f32_16x16x32_bf16(a2, b2, accD, 0, 0, 0);
    }
    #pragma unroll
    for (int q = 0; q < 4; ++q) {
      int trow = wr*16 + kc*4 + q;
      int scol = wc*16 + fr;
      float val = (scol < trow) ? accA[q] : ((scol == trow) ? accD[q] : 0.f);
      A_lds[trow][scol] = f2b(val);
    }
  }
  __syncthreads();
  // kS/rS/vS are dead from here (last reads above) -> reuse as store bounce.

  #pragma unroll
  for (int tb = 0; tb < 2; ++tb) {
    bf16x8 a  = *(const bf16x8*)&A_lds[tb*16+fr][kc*8];
    bf16x8 bb = *(const bf16x8*)&VT[wv*16+fr][kc*8];
    f32x4 acc = {0.f,0.f,0.f,0.f};
    acc = __builtin_amdgcn_mfma_f32_16x16x32_bf16(a, bb, acc, 0, 0, 0);
    #pragma unroll
    for (int q = 0; q < 4; ++q)
      kS[tb*16 + kc*4 + q][wv*16 + fr] = f2b(acc[q]);
  }
  #pragma unroll
  for (int jb = 0; jb < 4; ++jb) {
    bf16x8 a  = *(const bf16x8*)&KhT[wv*16+fr][kc*8];
    bf16x8 bb = *(const bf16x8*)&VT[jb*16+fr][kc*8];
    f32x4 acc = {0.f,0.f,0.f,0.f};
    acc = __builtin_amdgcn_mfma_f32_16x16x32_bf16(a, bb, acc, 0, 0, 0);
    #pragma unroll
    for (int q = 0; q < 4; ++q) {
      int i = kc*4 + q;     // row within the wave's 16-row band
      int j = jb*16 + fr;
      if (wv < 2) rS[wv*16 + i][j] = f2b(acc[q]);
      else        vS[(wv-2)*16 + i][j] = f2b(acc[q]);
    }
  }
  __syncthreads();
  { // coalesced y flush: 32 rows x 128B
    int row = tid >> 3, seg = tid & 7;
    *(uint4*)(y + rowbase + (size_t)row*Cc + seg*8) = *(const uint4*)&kS[row][seg*8];
  }
  #pragma unroll
  for (int rd = 0; rd < 2; ++rd) { // coalesced S flush: 64 rows x 128B
    int row = tid >> 2, s8 = (tid & 3) + rd*4;
    const u16* src = (row < 32) ? &rS[row][s8*8] : &vS[row-32][s8*8];
    *(uint4*)(S + ((size_t)blk*64 + row)*64 + s8*8) = *(const uint4*)src;
  }
  { // rc = R~ (in-place over r)
    int tt = tid >> 3, c8 = (tid & 7)*8;
    *(uint4*)(r + rowbase + (size_t)tt*Cc + c8) = *(const uint4*)&Rt[tt][c8];
  }
}

// ---------------- WKV6 pass 2: cross-chunk state propagation (in-place) ----------------
__global__ __launch_bounds__(256) void wkv_pass2(u16* __restrict__ S,
    const float* __restrict__ D)
{
  __shared__ float Dl[NCH][64];
  const int bh = blockIdx.x >> 2;
  const int jq = blockIdx.x & 3;
  const int tid = threadIdx.x;
  {
    const float4* src = (const float4*)(D + (size_t)bh*NCH*64);
    float4* dst = (float4*)&Dl[0][0];
    dst[tid] = src[tid];
    dst[tid + 256] = src[tid + 256];
  }
  __syncthreads();
  const int j = jq*16 + (tid & 15);
  const int i0 = (tid >> 4) * 4;
  const size_t base0 = (((size_t)bh*NCH)*64 + i0)*64 + j;
  u16 tmp[NCH][4];
  #pragma unroll
  for (int c = 0; c < NCH; ++c) {
    size_t base = base0 + (size_t)c*4096;
    #pragma unroll
    for (int ii = 0; ii < 4; ++ii) tmp[c][ii] = S[base + ii*64];
  }
  float Sr[4] = {0.f, 0.f, 0.f, 0.f};
  #pragma unroll
  for (int c = 0; c < NCH; ++c) {
    size_t base = base0 + (size_t)c*4096;
    #pragma unroll
    for (int ii = 0; ii < 4; ++ii) {
      S[base + ii*64] = f2b(Sr[ii]);
      Sr[ii] = fmaf(Sr[ii], Dl[c][i0+ii], b2f(tmp[c][ii]));
    }
  }
}

// ---------------- GroupNorm(H) + correction + gate, 8 rows/block ----------------
__global__ __launch_bounds__(256) void gn_gate(const u16* __restrict__ y,
   const u16* __restrict__ g, const u16* __restrict__ rc, const u16* __restrict__ S,
   const float* __restrict__ gamma, const float* __restrict__ beta, u16* __restrict__ out)
{
  __shared__ u16 rcl[8][Cc];
  const int bt0 = blockIdx.x * 8;
  const int b = bt0 >> 10;
  const int t0 = bt0 & (Tt-1);
  const int chunk = t0 >> 5;
  const int tid = threadIdx.x;
  #pragma unroll
  for (int rr = 0; rr < 8; ++rr)
    ((ushort4*)rcl[rr])[tid] = ((const ushort4*)(rc + (size_t)(bt0+rr)*Cc))[tid];
  __syncthreads();
  const int c0 = tid*4, h = c0 >> 6, j0 = c0 & 63;
  const u16* Sb = S + (((size_t)(b*Hh + h)*NCH + chunk)*64)*64 + j0;
  float corr[8][4];
  #pragma unroll
  for (int rr = 0; rr < 8; ++rr)
    #pragma unroll
    for (int q = 0; q < 4; ++q) corr[rr][q] = 0.f;
  #pragma unroll 4
  for (int i = 0; i < 64; ++i) {
    ushort4 sv = *(const ushort4*)(Sb + (size_t)i*64);
    float s0 = b2f(sv.x), s1 = b2f(sv.y), s2 = b2f(sv.z), s3 = b2f(sv.w);
    #pragma unroll
    for (int rr = 0; rr < 8; ++rr) {
      float rv = b2f(rcl[rr][h*64 + i]);
      corr[rr][0] = fmaf(rv, s0, corr[rr][0]);
      corr[rr][1] = fmaf(rv, s1, corr[rr][1]);
      corr[rr][2] = fmaf(rv, s2, corr[rr][2]);
      corr[rr][3] = fmaf(rv, s3, corr[rr][3]);
    }
  }
  float4 ga = ((const float4*)gamma)[tid];
  float4 be = ((const float4*)beta)[tid];
  #pragma unroll
  for (int rr = 0; rr < 8; ++rr) {
    size_t o4 = (size_t)(bt0+rr)*(Cc/4) + tid;
    ushort4 yv4 = ((const ushort4*)y)[o4];
    float y0 = b2f(yv4.x) + corr[rr][0];
    float y1 = b2f(yv4.y) + corr[rr][1];
    float y2 = b2f(yv4.z) + corr[rr][2];
    float y3 = b2f(yv4.w) + corr[rr][3];
    float s  = y0 + y1 + y2 + y3;
    float sq = y0*y0 + y1*y1 + y2*y2 + y3*y3;
    #pragma unroll
    for (int m = 1; m < 16; m <<= 1) {
      s  += __shfl_xor(s, m, 64);
      sq += __shfl_xor(sq, m, 64);
    }
    float mu  = s * (1.f/64.f);
    float var = sq * (1.f/64.f) - mu*mu;
    float rstd = rsqrtf(var + 6.4e-4f);
    ushort4 gu = ((const ushort4*)g)[o4];
    ushort4 ou;
    ou.x = f2b(((y0 - mu)*rstd*ga.x + be.x) * b2f(gu.x));
    ou.y = f2b(((y1 - mu)*rstd*ga.y + be.y) * b2f(gu.y));
    ou.z = f2b(((y2 - mu)*rstd*ga.z + be.z) * b2f(gu.z));
    ou.w = f2b(((y3 - mu)*rstd*ga.w + be.w) * b2f(gu.w));
    ((ushort4*)out)[o4] = ou;
  }
}

extern "C" void kernel_launch(void* const* d_in, const int* in_sizes, int n_in,
                              void* d_out, int out_size, void* d_ws, size_t ws_size,
                              hipStream_t stream) {
  const float* x      = (const float*)d_in[0];
  const float* maa_x  = (const float*)d_in[1];
  const float* maa_w  = (const float*)d_in[2];
  const float* maa_k  = (const float*)d_in[3];
  const float* maa_v  = (const float*)d_in[4];
  const float* maa_r  = (const float*)d_in[5];
  const float* maa_g  = (const float*)d_in[6];
  const float* w1     = (const float*)d_in[7];
  const float* w2     = (const float*)d_in[8];
  const float* tdecay = (const float*)d_in[9];
  const float* tdw1   = (const float*)d_in[10];
  const float* tdw2   = (const float*)d_in[11];
  const float* faaaa  = (const float*)d_in[12];
  const float* Wr     = (const float*)d_in[13];
  const float* Wk     = (const float*)d_in[14];
  const float* Wv     = (const float*)d_in[15];
  const float* Wg     = (const float*)d_in[16];
  const float* Wo     = (const float*)d_in[17];
  const float* gamma  = (const float*)d_in[18];
  const float* beta   = (const float*)d_in[19];
  float* out = (float*)d_out;

  const size_t MB = 1u << 20;
  char* wsb = (char*)d_ws;
  float* m1p  = (float*)(wsb + 0);            // 10.5M fp32 m1 k-partials (step2->3)
  u16*   w2T  = (u16*)(wsb + 12*MB);          // 320K bf16 w2 transposed (step0->3)
  u16*   xk   = (u16*)(wsb + 16*MB);          // 8M
  u16*   xv   = (u16*)(wsb + 24*MB);          // 8M
  u16*   xr   = (u16*)(wsb + 32*MB);          // 8M -> gated
  u16*   xg   = (u16*)(wsb + 40*MB);          // 8M
  float* wl1p = (float*)(wsb + 48*MB);        // 4M fp32 wl1 k-partials (step3->6; old xw slot)
  u16*   rbuf = (u16*)(wsb + 56*MB);          // 8M (r -> rc in-place)
  u16*   kbuf = (u16*)(wsb + 64*MB);          // 8M
  u16*   vbuf = (u16*)(wsb + 72*MB);          // 8M
  u16*   gbuf = (u16*)(wsb + 80*MB);          // 8M
  float* Dbuf = (float*)(wsb + 88*MB);        // 512K
  u16*   Sbuf = (u16*)(wsb + 16*MB);          // 16M over xk+xv (dead by pass1)
  u16*   BW0  = (u16*)(wsb + 88*MB + 512*1024);
  u16*   BW1  = (u16*)((char*)BW0 + 2*MB);
  u16*   BW2  = (u16*)((char*)BW1 + 2*MB);
  u16*   BW3  = (u16*)((char*)BW2 + 2*MB);
  u16*   BW4  = (u16*)((char*)BW3 + 2*MB);    // ends 98.5M
  u16*   w1T  = (u16*)((char*)BW4 + 2*MB);    // 320K
  u16*   tdw1T = (u16*)(wsb + 99*MB);
  u16*   tdw2T = (u16*)(wsb + 99*MB + 256*1024);
  u16*   gated = xr;
  u16*   xxx16 = (u16*)d_out;
  u16*   yb16  = (u16*)d_out;                 // 8M bf16 y (step5->6)

  dim3 blk(256);
  // 0+1. merged: weight transpose (z<9) + prep xxx (z>=9)
  WPack wp;
  wp.p[0] = {Wr, BW0, Cc, Cc};  wp.p[1] = {Wk, BW1, Cc, Cc};
  wp.p[2] = {Wv, BW2, Cc, Cc};  wp.p[3] = {Wg, BW3, Cc, Cc};
  wp.p[4] = {Wo, BW4, Cc, Cc};  wp.p[5] = {w1, w1T, Cc, 160};
  wp.p[6] = {tdw1, tdw1T, Cc, 64}; wp.p[7] = {tdw2, tdw2T, 64, Cc};
  wp.p[8] = {w2, w2T, 160, Cc};
  prep_transW<<<dim3(32,32,13), blk, 0, stream>>>(wp, x, maa_x, xxx16);
  // 2. m1 partials = xxx @ w1 (K-split z=4, fp32; tanh applied in mix_mfma)
  gemm_ksplit<<<dim3(2, 32, 4), blk, 0, stream>>>(xxx16, w1T, m1p, Cc, 256, 160);
  // 3. fused MFMA mix -> xk,xv,xr,xg + wl1 partials (xw never materialized)
  mix_mfma<<<1024, blk, 0, stream>>>(x, m1p, w2T, tdw1T,
                                     maa_w, maa_k, maa_v, maa_r, maa_g,
                                     wl1p, xk, xv, xr, xg);
  // 4. r,k,v,g batched — 256x256 4-phase kernel, 256 blocks
  GPack gp;
  gp.A[0] = xr; gp.A[1] = xk; gp.A[2] = xv; gp.A[3] = xg;
  gp.B[0] = BW0; gp.B[1] = BW1; gp.B[2] = BW2; gp.B[3] = BW3;
  gp.C[0] = rbuf; gp.C[1] = kbuf; gp.C[2] = vbuf; gp.C[3] = gbuf;
  gemm_rkvg256<<<dim3(4, 16, 4), dim3(512), 0, stream>>>(gp);
  // 5. wkv chunked scan (fused ew-GEMM; coalesced y/S flush)
  wkv_pass1<<<Bb*Hh*NCH, blk, 0, stream>>>(rbuf, kbuf, vbuf, wl1p, tdw2T, tdecay,
                                           faaaa, yb16, Sbuf, Dbuf);
  wkv_pass2<<<Bb*Hh*4, blk, 0, stream>>>(Sbuf, Dbuf);
  // 6. groupnorm + correction + gate
  gn_gate<<<BT/8, blk, 0, stream>>>(yb16, gbuf, rbuf, Sbuf, gamma, beta, gated);
  // 7. out = gated @ Wo (fp32)
  gemm_mfma<0,true><<<dim3(8, 32), blk, 0, stream>>>(gated, BW4, out, nullptr, Cc, Cc);
}

// Round 10
// 172.278 us; speedup vs baseline: 1.1648x; 1.0110x over previous
//
#include <hip/hip_runtime.h>

#define Bb 4
#define Tt 1024
#define Cc 1024
#define Hh 16
#define BT (Bb*Tt)
#define CHUNK 32
#define NCH (Tt/CHUNK)

typedef unsigned int uint;
typedef unsigned short u16;
typedef __bf16 bf16x8 __attribute__((ext_vector_type(8)));
typedef float f32x4 __attribute__((ext_vector_type(4)));
typedef const __attribute__((address_space(1))) uint GU;
typedef __attribute__((address_space(3))) uint LU;

__device__ __forceinline__ float blo(uint u) { return __uint_as_float(u << 16); }
__device__ __forceinline__ float bhi(uint u) { return __uint_as_float(u & 0xffff0000u); }
__device__ __forceinline__ float b2f(u16 u) { return __uint_as_float(((uint)u) << 16); }
__device__ __forceinline__ u16 f2b(float f) {
  uint u = __float_as_uint(f);
  return (u16)((u + 0x7fffu + ((u >> 16) & 1u)) >> 16);   // RNE
}
// fast tanh: 1 - 2/(e^{2x}+1); exact limits at +-inf, rel err ~2^-21
__device__ __forceinline__ float fast_tanh(float x) {
  float e = __expf(2.f * x);
  return 1.f - 2.f / (e + 1.f);
}

// ---------------- merged: weight transpose (z<9) + prep_xxx (z>=9) ----------
struct WPair { const float* s; u16* d; int K; int N; };
struct WPack { WPair p[9]; };

__global__ __launch_bounds__(256) void prep_transW(WPack wp,
    const float* __restrict__ x, const float* __restrict__ maa_x,
    u16* __restrict__ xxx)
{
  __shared__ float tile[32][33];
  if (blockIdx.z < 9) {
    WPair pr = wp.p[blockIdx.z];
    int c0 = blockIdx.x*32, r0 = blockIdx.y*32;
    if (c0 >= pr.N || r0 >= pr.K) return;
    int tc = threadIdx.x & 31, tr = threadIdx.x >> 5;
    #pragma unroll
    for (int p = 0; p < 4; ++p)
      tile[tr + p*8][tc] = pr.s[(size_t)(r0 + tr + p*8)*pr.N + c0 + tc];
    __syncthreads();
    #pragma unroll
    for (int p = 0; p < 4; ++p) {
      int n = tr + p*8;
      pr.d[(size_t)(c0 + n)*pr.K + r0 + tc] = f2b(tile[tc][n]);
    }
  } else {
    int vb = (blockIdx.z - 9)*1024 + blockIdx.y*32 + blockIdx.x;  // 0..4095
    int idx = vb*256 + threadIdx.x;
    int c4 = idx & 255;
    int bt = idx >> 8;
    int t = bt & (Tt-1);
    float4 xc = ((const float4*)x)[idx];
    float4 xp = make_float4(0.f,0.f,0.f,0.f);
    if (t > 0) xp = ((const float4*)x)[idx - 256];
    float4 mx = ((const float4*)maa_x)[c4];
    ushort4 o;
    o.x = f2b(fmaf(xp.x - xc.x, mx.x, xc.x));
    o.y = f2b(fmaf(xp.y - xc.y, mx.y, xc.y));
    o.z = f2b(fmaf(xp.z - xc.z, mx.z, xc.z));
    o.w = f2b(fmaf(xp.w - xc.w, mx.w, xc.w));
    ((ushort4*)xxx)[idx] = o;
  }
}

// ---------------- fused mix: MFMA (tanh Σ m1-partials)@w2 + epilogue ----------
// Block = 16 rows x 256 cols. Staged aW + xS; wl1 K-split partial fused at
// f=0 (round 9); coalesced strip-bounce epilogue stores.
__global__ __launch_bounds__(256) void mix_mfma(
    const float* __restrict__ x, const float* __restrict__ m1p,
    const u16* __restrict__ w2T, const u16* __restrict__ tdw1T,
    const float* __restrict__ maa_w, const float* __restrict__ maa_k,
    const float* __restrict__ maa_v, const float* __restrict__ maa_r,
    const float* __restrict__ maa_g,
    float* __restrict__ wl1p,
    u16* __restrict__ xk, u16* __restrict__ xv,
    u16* __restrict__ xr, u16* __restrict__ xg)
{
  __shared__ __align__(16) u16 aW[16][168];
  __shared__ __align__(16) float xS[17][260];     // reused as wl1 reduction buf
  __shared__ __align__(16) u16 strip[4][16][72];
  const int tid = threadIdx.x;
  const int lane = tid & 63;
  const int wv = tid >> 6;
  const int rs = blockIdx.x >> 2;          // 0..255
  const int cb = blockIdx.x & 3;           // 0..3
  const int r0 = rs*16;
  const int c0b = cb*256;
  const int fr = lane & 15, kc = lane >> 4;
  const bool firstrow = (r0 & (Tt-1)) == 0;

  // stage aW (640 float4-tasks: 5 f x 16 rows x 8 col4)
  for (int task = tid; task < 640; task += 256) {
    int f  = task >> 7;
    int r  = (task >> 3) & 15;
    int c4 = task & 7;
    size_t off = (size_t)(r0 + r)*160 + f*32 + c4*4;
    float4 s = *(const float4*)(m1p + off);
    #pragma unroll
    for (int z = 1; z < 4; ++z) {
      float4 p = *(const float4*)(m1p + (size_t)z*655360 + off);
      s.x += p.x; s.y += p.y; s.z += p.z; s.w += p.w;
    }
    ushort4 t4;
    t4.x = f2b(fast_tanh(s.x)); t4.y = f2b(fast_tanh(s.y));
    t4.z = f2b(fast_tanh(s.z)); t4.w = f2b(fast_tanh(s.w));
    *(ushort4*)&aW[r][f*32 + c4*4] = t4;
  }
  // stage x rows r0-1..r0+15, cols c0b..c0b+255 (1088 float4-tasks)
  for (int i = tid; i < 1088; i += 256) {
    int r17 = i >> 6;            // 0..16
    int c4  = i & 63;
    float4 v = make_float4(0.f,0.f,0.f,0.f);
    if (!(r17 == 0 && firstrow))
      v = *(const float4*)(x + (size_t)(r0 - 1 + r17)*Cc + c0b + c4*4);
    *(float4*)&xS[r17][c4*4] = v;
  }
  __syncthreads();

  const int c0 = c0b + wv*64;
  float xc[4][4], xd[4][4];
  #pragma unroll
  for (int n = 0; n < 4; ++n) {
    int cl = wv*64 + n*16 + fr;
    #pragma unroll
    for (int q = 0; q < 4; ++q) {
      int rl = kc*4 + q;
      float v = xS[rl + 1][cl];
      float p = xS[rl][cl];
      xc[n][q] = v;
      xd[n][q] = p - v;
    }
  }

  u16* const outs[5] = {nullptr, xk, xv, xr, xg};
  const float* const maas[5] = {maa_w, maa_k, maa_v, maa_r, maa_g};
  f32x4 wacc[4];
  #pragma unroll
  for (int n = 0; n < 4; ++n) wacc[n] = f32x4{0.f,0.f,0.f,0.f};

  #pragma unroll
  for (int f = 0; f < 5; ++f) {
    bf16x8 af = *(const bf16x8*)&aW[fr][f*32 + kc*8];
    f32x4 acc[4];
    #pragma unroll
    for (int n = 0; n < 4; ++n) {
      bf16x8 bg = *(const bf16x8*)(w2T + (size_t)(c0 + n*16 + fr)*160 + f*32 + kc*8);
      acc[n] = __builtin_amdgcn_mfma_f32_16x16x32_bf16(af, bg, f32x4{0.f,0.f,0.f,0.f}, 0, 0, 0);
    }
    const float* __restrict__ ma = maas[f];
    #pragma unroll
    for (int n = 0; n < 4; ++n) {
      int colL = n*16 + fr;
      float mv = ma[c0 + colL];
      #pragma unroll
      for (int q = 0; q < 4; ++q)
        strip[wv][kc*4 + q][colL] = f2b(fmaf(xd[n][q], mv + acc[n][q], xc[n][q]));
    }
    if (f == 0) {
      // wl1 partial: (xw strip 16x64K) @ tdw1T -> wacc (K=64 per wave)
      #pragma unroll
      for (int ks = 0; ks < 2; ++ks) {
        bf16x8 a = *(const bf16x8*)&strip[wv][fr][ks*32 + kc*8];
        #pragma unroll
        for (int n2 = 0; n2 < 4; ++n2) {
          bf16x8 bg2 = *(const bf16x8*)(tdw1T + (size_t)(n2*16 + fr)*Cc + c0 + ks*32 + kc*8);
          wacc[n2] = __builtin_amdgcn_mfma_f32_16x16x32_bf16(a, bg2, wacc[n2], 0, 0, 0);
        }
      }
    } else {
      u16* __restrict__ op = outs[f];
      #pragma unroll
      for (int rd = 0; rd < 2; ++rd) {
        int r8 = (lane >> 3) + rd*8;
        uint4 v = *(const uint4*)&strip[wv][r8][(lane & 7)*8];
        *(uint4*)(op + (size_t)(r0 + r8)*Cc + c0 + (lane & 7)*8) = v;
      }
    }
  }

  // cross-wave wl1 reduction through dead xS (all xS reads happened pre-loop)
  __syncthreads();
  float* red = (float*)&xS[0][0];           // [4][16][68]
  #pragma unroll
  for (int n2 = 0; n2 < 4; ++n2)
    #pragma unroll
    for (int q = 0; q < 4; ++q)
      red[wv*1088 + (kc*4 + q)*68 + n2*16 + fr] = wacc[n2][q];
  __syncthreads();
  {
    int row = tid >> 4, c4 = (tid & 15) * 4;
    float4 s = make_float4(0.f,0.f,0.f,0.f);
    #pragma unroll
    for (int w2i = 0; w2i < 4; ++w2i) {
      float4 p = *(const float4*)&red[w2i*1088 + row*68 + c4];
      s.x += p.x; s.y += p.y; s.z += p.z; s.w += p.w;
    }
    *(float4*)(wl1p + (size_t)cb*262144 + (size_t)(r0 + row)*64 + c4) = s;
  }
}

// ---------------- bf16 MFMA GEMM core (m97 structure + chunk swizzle) ----------------
// ld: row stride (elems) of A and Bt; kloop: K extent to accumulate (<= ld).
template<bool OUTF32>
__device__ __forceinline__ void mfma_core(
    const u16* __restrict__ A, const u16* __restrict__ Bt,
    void* __restrict__ Cout, const float* __restrict__ bias,
    int ld, int kloop, int N, int act)
{
  __shared__ __align__(16) u16 lds[2][2][128*32];   // 32 KB
  const int tid = threadIdx.x;
  const int lane = tid & 63;
  const int wv = __builtin_amdgcn_readfirstlane(tid >> 6);

  // bijective XCD swizzle (requires gridDim.y % 8 == 0)
  const int nby8 = gridDim.y >> 3;
  const int i_lin = blockIdx.y * gridDim.x + blockIdx.x;
  const int cx = i_lin & 7, rest = i_lin >> 3;
  const int bm = (cx * nby8 + rest % nby8) * 128;
  const int bn = (rest / nby8) * 128;

  const int wm = (wv >> 1) * 64;
  const int wn = (wv & 1) * 64;
  const int kc = lane >> 4;
  const int fr = lane & 15;

  const int srow = wv*16 + (lane >> 2);
  const int ssw  = (srow >> 1) & 3;                 // == s(srow+64)
  const int scol = ((lane & 3) ^ ssw) * 8;
  const size_t aoff = (size_t)(bm + srow) * ld + scol;
  const size_t boff = (size_t)(bn + srow) * ld + scol;

#define STAGE(bufi, kt) do { \
    size_t ko_ = (size_t)(kt) * 32; \
    __builtin_amdgcn_global_load_lds((GU*)(A + aoff + ko_), \
        (LU*)&lds[bufi][0][wv*512], 16, 0, 0); \
    __builtin_amdgcn_global_load_lds((GU*)(A + aoff + (size_t)64*ld + ko_), \
        (LU*)&lds[bufi][0][wv*512 + 64*32], 16, 0, 0); \
    __builtin_amdgcn_global_load_lds((GU*)(Bt + boff + ko_), \
        (LU*)&lds[bufi][1][wv*512], 16, 0, 0); \
    __builtin_amdgcn_global_load_lds((GU*)(Bt + boff + (size_t)64*ld + ko_), \
        (LU*)&lds[bufi][1][wv*512 + 64*32], 16, 0, 0); \
  } while(0)

  int ard[4], brd[4];
  #pragma unroll
  for (int m = 0; m < 4; ++m) {
    int ra = wm + m*16 + fr;
    int rb = wn + m*16 + fr;
    ard[m] = ra*32 + (kc ^ ((ra >> 1) & 3))*8;
    brd[m] = rb*32 + (kc ^ ((rb >> 1) & 3))*8;
  }

  f32x4 acc[4][4];
  #pragma unroll
  for (int m = 0; m < 4; ++m)
    #pragma unroll
    for (int n = 0; n < 4; ++n)
      acc[m][n] = f32x4{0.f, 0.f, 0.f, 0.f};

  const int NK = kloop >> 5;
  STAGE(0, 0);
  __syncthreads();
  int buf = 0;
  for (int kt = 0; kt < NK; ++kt) {
    if (kt + 1 < NK) STAGE(buf^1, kt+1);
    bf16x8 af[4], bg[4];
    #pragma unroll
    for (int m = 0; m < 4; ++m) af[m] = *(const bf16x8*)&lds[buf][0][ard[m]];
    #pragma unroll
    for (int n = 0; n < 4; ++n) bg[n] = *(const bf16x8*)&lds[buf][1][brd[n]];
    #pragma unroll
    for (int m = 0; m < 4; ++m)
      #pragma unroll
      for (int n = 0; n < 4; ++n)
        acc[m][n] = __builtin_amdgcn_mfma_f32_16x16x32_bf16(af[m], bg[n], acc[m][n], 0, 0, 0);
    __syncthreads();
    buf ^= 1;
  }
#undef STAGE

  const int orow = bm + wm + (lane >> 4) * 4;
  const int ocol = bn + wn + fr;
  #pragma unroll
  for (int m = 0; m < 4; ++m) {
    #pragma unroll
    for (int n = 0; n < 4; ++n) {
      int col = ocol + n*16;
      if (col < N) {
        float bs = bias ? bias[col] : 0.f;
        #pragma unroll
        for (int q = 0; q < 4; ++q) {
          float vv = acc[m][n][q] + bs;
          if (act == 1) vv = tanhf(vv);
          else if (act == 2) vv = vv / (1.f + __expf(-vv));
          size_t off = (size_t)(orow + m*16 + q) * N + col;
          if (OUTF32) ((float*)Cout)[off] = vv;
          else ((u16*)Cout)[off] = f2b(vv);
        }
      }
    }
  }
}

template<int ACT, bool OUTF32>
__global__ __launch_bounds__(256) void gemm_mfma(
    const u16* __restrict__ A, const u16* __restrict__ Bt,
    void* __restrict__ Cout, const float* __restrict__ bias, int K, int N)
{
  mfma_core<OUTF32>(A, Bt, Cout, bias, K, K, N, ACT);
}

// K-split GEMM: z-th block-slab accumulates k in [z*ksz, (z+1)*ksz), writes
// raw fp32 partials to Cp + z*4096*N. No activation (applied at consumer).
__global__ __launch_bounds__(256) void gemm_ksplit(
    const u16* __restrict__ A, const u16* __restrict__ Bt,
    float* __restrict__ Cp, int ld, int ksz, int N)
{
  const int z = blockIdx.z;
  mfma_core<true>(A + (size_t)z*ksz, Bt + (size_t)z*ksz,
                  Cp + (size_t)z*4096*N, nullptr, ld, ksz, N, 0);
}

// ---------------- 256x256 4-phase GEMM for the big batched r/k/v/g GEMMs ----------------
struct GPack { const u16* A[4]; const u16* B[4]; u16* C[4]; };

#define VMW(n) asm volatile("s_waitcnt vmcnt(" #n ")" ::: "memory")
#define LGKM0() asm volatile("s_waitcnt lgkmcnt(0)" ::: "memory")
#define SCHB() __builtin_amdgcn_sched_barrier(0)
#define HBAR() __builtin_amdgcn_s_barrier()

__global__ __launch_bounds__(512) void gemm_rkvg256(GPack gp) {
  __shared__ __align__(16) u16 lds[2][2][2][8192];   // [dbuf][A/B][khalf][256*32] = 128 KB
  const int z = blockIdx.z;
  const u16* __restrict__ Ap  = gp.A[z];
  const u16* __restrict__ Btp = gp.B[z];
  u16* __restrict__ Cp = gp.C[z];
  const int act = (z == 3) ? 2 : 0;

  const int tid = threadIdx.x;
  const int lane = tid & 63;
  const int wv = __builtin_amdgcn_readfirstlane(tid >> 6);

  const int i_lin = blockIdx.y * gridDim.x + blockIdx.x;   // 0..63
  const int tile = (i_lin & 7) * 8 + (i_lin >> 3);
  const int bm = (tile >> 2) * 256;
  const int bn = (tile & 3) * 256;

  const int wm = (wv >> 2) * 128;    // 2 wave-rows of 128
  const int wn = (wv & 3) * 64;      // 4 wave-cols of 64
  const int kc = lane >> 4;
  const int fr = lane & 15;

  const int srow0 = (wv*2 + 0)*16 + (lane >> 2);
  const int srow1 = (wv*2 + 1)*16 + (lane >> 2);
  const int sc0 = ((lane & 3) ^ ((srow0 >> 1) & 3)) * 8;
  const int sc1 = ((lane & 3) ^ ((srow1 >> 1) & 3)) * 8;
  const size_t aoff0 = (size_t)(bm + srow0)*Cc + sc0;
  const size_t aoff1 = (size_t)(bm + srow1)*Cc + sc1;
  const size_t boff0 = (size_t)(bn + srow0)*Cc + sc0;
  const size_t boff1 = (size_t)(bn + srow1)*Cc + sc1;

  int ard[8], brd[4];
  #pragma unroll
  for (int mh = 0; mh < 2; ++mh)
    #pragma unroll
    for (int mf = 0; mf < 4; ++mf) {
      int r = wm + mh*64 + mf*16 + fr;
      ard[mh*4+mf] = r*32 + (kc ^ ((r >> 1) & 3))*8;
    }
  #pragma unroll
  for (int nf = 0; nf < 4; ++nf) {
    int r = wn + nf*16 + fr;
    brd[nf] = r*32 + (kc ^ ((r >> 1) & 3))*8;
  }

  f32x4 acc[8][4];
  #pragma unroll
  for (int m = 0; m < 8; ++m)
    #pragma unroll
    for (int n = 0; n < 4; ++n)
      acc[m][n] = f32x4{0.f, 0.f, 0.f, 0.f};

#define STG256(DB, MAT, KH, kt, off0, off1, src) do { \
    u16* dst_ = &lds[(DB)][(MAT)][(KH)][wv*1024]; \
    __builtin_amdgcn_global_load_lds((GU*)((src) + (off0) + (size_t)(kt)*64 + (KH)*32), \
        (LU*)dst_, 16, 0, 0); \
    __builtin_amdgcn_global_load_lds((GU*)((src) + (off1) + (size_t)(kt)*64 + (KH)*32), \
        (LU*)(dst_ + 512), 16, 0, 0); \
  } while(0)

#define PH256(cur, KH, MH, LOADB, STMAT, STKH, DOSTAGE, VMTOK) do { \
    _Pragma("unroll") \
    for (int mf = 0; mf < 4; ++mf) \
      af[mf] = *(const bf16x8*)&lds[(cur)][0][KH][ard[(MH)*4+mf]]; \
    if (LOADB) { \
      _Pragma("unroll") \
      for (int nf = 0; nf < 4; ++nf) \
        bg[nf] = *(const bf16x8*)&lds[(cur)][1][KH][brd[nf]]; \
    } \
    if (DOSTAGE) { \
      if ((STMAT) == 0) STG256((cur)^1, 0, STKH, t+1, aoff0, aoff1, Ap); \
      else              STG256((cur)^1, 1, STKH, t+1, boff0, boff1, Btp); \
    } \
    VMTOK; \
    SCHB(); \
    HBAR(); \
    LGKM0(); \
    SCHB(); \
    __builtin_amdgcn_s_setprio(1); \
    _Pragma("unroll") \
    for (int mf = 0; mf < 4; ++mf) \
      _Pragma("unroll") \
      for (int nf = 0; nf < 4; ++nf) \
        acc[(MH)*4+mf][nf] = __builtin_amdgcn_mfma_f32_16x16x32_bf16(af[mf], bg[nf], acc[(MH)*4+mf][nf], 0, 0, 0); \
    __builtin_amdgcn_s_setprio(0); \
    SCHB(); \
    HBAR(); \
  } while(0)

  const int NK = Cc >> 6;   // 16 K-tiles of 64

  STG256(0, 0, 0, 0, aoff0, aoff1, Ap);
  STG256(0, 1, 0, 0, boff0, boff1, Btp);
  STG256(0, 0, 1, 0, aoff0, aoff1, Ap);
  STG256(0, 1, 1, 0, boff0, boff1, Btp);
  VMW(4);
  SCHB();
  HBAR();

  bf16x8 af[4], bg[4];
  int t;
  #pragma unroll 2
  for (t = 0; t < NK - 1; ++t) {
    const int cur = t & 1;
    PH256(cur, 0, 0, true,  0, 0, true,  (void)0);
    PH256(cur, 0, 1, false, 1, 0, true,  VMW(4));
    PH256(cur, 1, 0, true,  0, 1, true,  (void)0);
    PH256(cur, 1, 1, false, 1, 1, true,  VMW(4));
  }
  { // final K-tile: no prefetch; full drain before its second k-half
    const int cur = t & 1;
    PH256(cur, 0, 0, true,  0, 0, false, (void)0);
    PH256(cur, 0, 1, false, 0, 0, false, VMW(0));
    PH256(cur, 1, 0, true,  0, 0, false, (void)0);
    PH256(cur, 1, 1, false, 0, 0, false, (void)0);
  }
#undef PH256
#undef STG256

  const int orow = bm + wm + (lane >> 4) * 4;
  const int ocol = bn + wn + fr;
  #pragma unroll
  for (int m = 0; m < 8; ++m) {
    #pragma unroll
    for (int nf = 0; nf < 4; ++nf) {
      #pragma unroll
      for (int q = 0; q < 4; ++q) {
        float vv = acc[m][nf][q];
        if (act == 2) vv = vv / (1.f + __expf(-vv));
        Cp[(size_t)(orow + (m >> 2)*64 + (m & 3)*16 + q) * Cc + ocol + nf*16] = f2b(vv);
      }
    }
  }
}

// ---------------- WKV6 pass 1: chunked matmul formulation (MFMA) ----------------
// Fused ew-GEMM; coalesced y/S flush. Round 10: the cumulative-decay scan is
// now PARALLEL across all 256 threads (thread (c, q) owns 8 timesteps;
// quarter offsets via qsum LDS; direct exp of prefix sums — serial depth
// 32 -> 8, all 4 waves active; numerics = direct-exp form, more accurate
// than the iterated product).
__global__ __launch_bounds__(256) void wkv_pass1(u16* __restrict__ r,
    const u16* __restrict__ k, const u16* __restrict__ v,
    const float* __restrict__ wl1p, const u16* __restrict__ tdw2T,
    const float* __restrict__ tdecay, const float* __restrict__ u,
    u16* __restrict__ y, u16* __restrict__ S, float* __restrict__ D)
{
  __shared__ __align__(16) u16 rS[CHUNK][72];
  __shared__ __align__(16) u16 kS[CHUNK][72];
  __shared__ __align__(16) u16 vS[CHUNK][72];
  __shared__ __align__(16) u16 aW[CHUNK][72];        // tanh(sum wl1p) bf16
  __shared__ __align__(16) float bufEW[CHUNK][68];   // ew -> eR (in-place)
  __shared__ __align__(16) float eKnL[CHUNK][68];
  __shared__ __align__(16) u16 Rt[CHUNK][72];
  __shared__ __align__(16) u16 Kt[CHUNK][72];
  __shared__ __align__(16) u16 Ru[CHUNK][72];
  __shared__ __align__(16) u16 KhT[64][40];
  __shared__ __align__(16) u16 VT[64][40];
  __shared__ __align__(16) u16 A_lds[CHUNK][40];
  __shared__ float qsum[4][64];
  __shared__ float uL[64];
  __shared__ float Dl[64];

  const int blk = blockIdx.x;
  const int chunk = blk & (NCH-1);
  const int bh = blk >> 5;
  const int h = bh & (Hh-1);
  const int b = bh >> 4;
  const int tid = threadIdx.x;
  const int lane = tid & 63;
  const int wv = tid >> 6;
  const int fr = lane & 15;
  const int kc = lane >> 4;

  const int trow0 = b*Tt + chunk*CHUNK;
  const size_t rowbase = (size_t)trow0*Cc + h*64;
  {
    int tt = tid >> 3, c8 = (tid & 7)*8;
    size_t go = rowbase + (size_t)tt*Cc + c8;
    *(uint4*)&rS[tt][c8] = *(const uint4*)(r + go);
    *(uint4*)&kS[tt][c8] = *(const uint4*)(k + go);
    *(uint4*)&vS[tt][c8] = *(const uint4*)(v + go);
    // wl1 partial sum + tanh -> aW (bf16), K=64 row for this t
    size_t wrow = (size_t)(trow0 + tt)*64 + c8;
    float s8[8] = {0.f,0.f,0.f,0.f,0.f,0.f,0.f,0.f};
    #pragma unroll
    for (int z = 0; z < 4; ++z) {
      const float4* p = (const float4*)(wl1p + (size_t)z*262144 + wrow);
      float4 a = p[0], b2 = p[1];
      s8[0]+=a.x; s8[1]+=a.y; s8[2]+=a.z; s8[3]+=a.w;
      s8[4]+=b2.x; s8[5]+=b2.y; s8[6]+=b2.z; s8[7]+=b2.w;
    }
    u16 t8[8];
    #pragma unroll
    for (int j = 0; j < 8; ++j) t8[j] = f2b(fast_tanh(s8[j]));
    *(uint4*)&aW[tt][c8] = *(const uint4*)t8;
  }
  if (tid < 64) uL[tid] = u[h*64 + tid];
  __syncthreads();

  // ew MFMA: bufEW[t][i] = exp( (aW @ tdw2T^T)[t][i] + tdecay[h*64+i] )
  {
    const int icol = wv*16 + fr;
    const float bs = tdecay[h*64 + icol];
    #pragma unroll
    for (int tb = 0; tb < 2; ++tb) {
      f32x4 acc = {0.f,0.f,0.f,0.f};
      #pragma unroll
      for (int ks = 0; ks < 2; ++ks) {
        bf16x8 a  = *(const bf16x8*)&aW[tb*16+fr][kc*8 + ks*32];
        bf16x8 bb = *(const bf16x8*)(tdw2T + (size_t)(h*64 + icol)*64 + ks*32 + kc*8);
        acc = __builtin_amdgcn_mfma_f32_16x16x32_bf16(a, bb, acc, 0, 0, 0);
      }
      #pragma unroll
      for (int q = 0; q < 4; ++q)
        bufEW[tb*16 + kc*4 + q][icol] = __expf(acc[q] + bs);
    }
  }
  __syncthreads();

  // parallel cumulative-decay: thread (c, qq) owns t in [qq*8, qq*8+8)
  {
    const int c = tid & 63, qq = tid >> 6;
    float e8[8]; float s = 0.f;
    #pragma unroll
    for (int i = 0; i < 8; ++i) { e8[i] = bufEW[qq*8 + i][c]; s += e8[i]; }
    qsum[qq][c] = s;
    __syncthreads();
    float pre = 0.f;
    if (qq > 0) pre += qsum[0][c];
    if (qq > 1) pre += qsum[1][c];
    if (qq > 2) pre += qsum[2][c];
    #pragma unroll
    for (int i = 0; i < 8; ++i) {
      bufEW[qq*8 + i][c] = __expf(-pre);   // eR[t] = exp(lw[t-1])
      pre += e8[i];
      eKnL[qq*8 + i][c] = __expf(pre);     // exp(-lw[t])
    }
    if (qq == 3) {
      float dv = __expf(-pre);             // exp(lw[31])
      Dl[c] = dv;
      D[(size_t)blk*64 + c] = dv;
    }
  }
  __syncthreads();

  {
    int t = tid >> 3, i0 = (tid & 7)*8;
    uint4 rv4 = *(const uint4*)&rS[t][i0];
    uint4 kv4 = *(const uint4*)&kS[t][i0];
    const uint* rw = (const uint*)&rv4;
    const uint* kw = (const uint*)&kv4;
    u16 rt8[8], kt8[8], ru8[8];
    #pragma unroll
    for (int q = 0; q < 8; ++q) {
      int i = i0 + q;
      float rv = (q & 1) ? bhi(rw[q>>1]) : blo(rw[q>>1]);
      float kv = (q & 1) ? bhi(kw[q>>1]) : blo(kw[q>>1]);
      float eR = bufEW[t][i];
      float eKn = eKnL[t][i];
      float ktv = kv * eKn;
      rt8[q] = f2b(rv * eR);
      kt8[q] = f2b(ktv);
      ru8[q] = f2b(rv * uL[i]);
      KhT[i][t] = f2b(ktv * Dl[i]);
      VT[i][t] = vS[t][i];
    }
    *(uint4*)&Rt[t][i0] = *(const uint4*)rt8;
    *(uint4*)&Kt[t][i0] = *(const uint4*)kt8;
    *(uint4*)&Ru[t][i0] = *(const uint4*)ru8;
  }
  __syncthreads();

  {
    const int wr = wv >> 1, wc = wv & 1;
    f32x4 accA = {0.f,0.f,0.f,0.f};
    f32x4 accD = {0.f,0.f,0.f,0.f};
    #pragma unroll
    for (int ks = 0; ks < 2; ++ks) {
      bf16x8 a  = *(const bf16x8*)&Rt[wr*16+fr][kc*8 + ks*32];
      bf16x8 bb = *(const bf16x8*)&Kt[wc*16+fr][kc*8 + ks*32];
      accA = __builtin_amdgcn_mfma_f32_16x16x32_bf16(a, bb, accA, 0, 0, 0);
      bf16x8 a2 = *(const bf16x8*)&Ru[wr*16+fr][kc*8 + ks*32];
      bf16x8 b2 = *(const bf16x8*)&kS[wc*16+fr][kc*8 + ks*32];
      accD = __builtin_amdgcn_mfma_f32_16x16x32_bf16(a2, b2, accD, 0, 0, 0);
    }
    #pragma unroll
    for (int q = 0; q < 4; ++q) {
      int trow = wr*16 + kc*4 + q;
      int scol = wc*16 + fr;
      float val = (scol < trow) ? accA[q] : ((scol == trow) ? accD[q] : 0.f);
      A_lds[trow][scol] = f2b(val);
    }
  }
  __syncthreads();
  // kS/rS/vS are dead from here (last reads above) -> reuse as store bounce.

  #pragma unroll
  for (int tb = 0; tb < 2; ++tb) {
    bf16x8 a  = *(const bf16x8*)&A_lds[tb*16+fr][kc*8];
    bf16x8 bb = *(const bf16x8*)&VT[wv*16+fr][kc*8];
    f32x4 acc = {0.f,0.f,0.f,0.f};
    acc = __builtin_amdgcn_mfma_f32_16x16x32_bf16(a, bb, acc, 0, 0, 0);
    #pragma unroll
    for (int q = 0; q < 4; ++q)
      kS[tb*16 + kc*4 + q][wv*16 + fr] = f2b(acc[q]);
  }
  #pragma unroll
  for (int jb = 0; jb < 4; ++jb) {
    bf16x8 a  = *(const bf16x8*)&KhT[wv*16+fr][kc*8];
    bf16x8 bb = *(const bf16x8*)&VT[jb*16+fr][kc*8];
    f32x4 acc = {0.f,0.f,0.f,0.f};
    acc = __builtin_amdgcn_mfma_f32_16x16x32_bf16(a, bb, acc, 0, 0, 0);
    #pragma unroll
    for (int q = 0; q < 4; ++q) {
      int i = kc*4 + q;     // row within the wave's 16-row band
      int j = jb*16 + fr;
      if (wv < 2) rS[wv*16 + i][j] = f2b(acc[q]);
      else        vS[(wv-2)*16 + i][j] = f2b(acc[q]);
    }
  }
  __syncthreads();
  { // coalesced y flush: 32 rows x 128B
    int row = tid >> 3, seg = tid & 7;
    *(uint4*)(y + rowbase + (size_t)row*Cc + seg*8) = *(const uint4*)&kS[row][seg*8];
  }
  #pragma unroll
  for (int rd = 0; rd < 2; ++rd) { // coalesced S flush: 64 rows x 128B
    int row = tid >> 2, s8 = (tid & 3) + rd*4;
    const u16* src = (row < 32) ? &rS[row][s8*8] : &vS[row-32][s8*8];
    *(uint4*)(S + ((size_t)blk*64 + row)*64 + s8*8) = *(const uint4*)src;
  }
  { // rc = R~ (in-place over r)
    int tt = tid >> 3, c8 = (tid & 7)*8;
    *(uint4*)(r + rowbase + (size_t)tt*Cc + c8) = *(const uint4*)&Rt[tt][c8];
  }
}

// ---------------- WKV6 pass 2: cross-chunk state propagation (in-place) ----------------
__global__ __launch_bounds__(256) void wkv_pass2(u16* __restrict__ S,
    const float* __restrict__ D)
{
  __shared__ float Dl[NCH][64];
  const int bh = blockIdx.x >> 2;
  const int jq = blockIdx.x & 3;
  const int tid = threadIdx.x;
  {
    const float4* src = (const float4*)(D + (size_t)bh*NCH*64);
    float4* dst = (float4*)&Dl[0][0];
    dst[tid] = src[tid];
    dst[tid + 256] = src[tid + 256];
  }
  __syncthreads();
  const int j = jq*16 + (tid & 15);
  const int i0 = (tid >> 4) * 4;
  const size_t base0 = (((size_t)bh*NCH)*64 + i0)*64 + j;
  u16 tmp[NCH][4];
  #pragma unroll
  for (int c = 0; c < NCH; ++c) {
    size_t base = base0 + (size_t)c*4096;
    #pragma unroll
    for (int ii = 0; ii < 4; ++ii) tmp[c][ii] = S[base + ii*64];
  }
  float Sr[4] = {0.f, 0.f, 0.f, 0.f};
  #pragma unroll
  for (int c = 0; c < NCH; ++c) {
    size_t base = base0 + (size_t)c*4096;
    #pragma unroll
    for (int ii = 0; ii < 4; ++ii) {
      S[base + ii*64] = f2b(Sr[ii]);
      Sr[ii] = fmaf(Sr[ii], Dl[c][i0+ii], b2f(tmp[c][ii]));
    }
  }
}

// ---------------- GroupNorm(H) + correction + gate, 8 rows/block ----------------
__global__ __launch_bounds__(256) void gn_gate(const u16* __restrict__ y,
   const u16* __restrict__ g, const u16* __restrict__ rc, const u16* __restrict__ S,
   const float* __restrict__ gamma, const float* __restrict__ beta, u16* __restrict__ out)
{
  __shared__ u16 rcl[8][Cc];
  const int bt0 = blockIdx.x * 8;
  const int b = bt0 >> 10;
  const int t0 = bt0 & (Tt-1);
  const int chunk = t0 >> 5;
  const int tid = threadIdx.x;
  #pragma unroll
  for (int rr = 0; rr < 8; ++rr)
    ((ushort4*)rcl[rr])[tid] = ((const ushort4*)(rc + (size_t)(bt0+rr)*Cc))[tid];
  __syncthreads();
  const int c0 = tid*4, h = c0 >> 6, j0 = c0 & 63;
  const u16* Sb = S + (((size_t)(b*Hh + h)*NCH + chunk)*64)*64 + j0;
  float corr[8][4];
  #pragma unroll
  for (int rr = 0; rr < 8; ++rr)
    #pragma unroll
    for (int q = 0; q < 4; ++q) corr[rr][q] = 0.f;
  #pragma unroll 8
  for (int i = 0; i < 64; ++i) {
    ushort4 sv = *(const ushort4*)(Sb + (size_t)i*64);
    float s0 = b2f(sv.x), s1 = b2f(sv.y), s2 = b2f(sv.z), s3 = b2f(sv.w);
    #pragma unroll
    for (int rr = 0; rr < 8; ++rr) {
      float rv = b2f(rcl[rr][h*64 + i]);
      corr[rr][0] = fmaf(rv, s0, corr[rr][0]);
      corr[rr][1] = fmaf(rv, s1, corr[rr][1]);
      corr[rr][2] = fmaf(rv, s2, corr[rr][2]);
      corr[rr][3] = fmaf(rv, s3, corr[rr][3]);
    }
  }
  float4 ga = ((const float4*)gamma)[tid];
  float4 be = ((const float4*)beta)[tid];
  #pragma unroll
  for (int rr = 0; rr < 8; ++rr) {
    size_t o4 = (size_t)(bt0+rr)*(Cc/4) + tid;
    ushort4 yv4 = ((const ushort4*)y)[o4];
    float y0 = b2f(yv4.x) + corr[rr][0];
    float y1 = b2f(yv4.y) + corr[rr][1];
    float y2 = b2f(yv4.z) + corr[rr][2];
    float y3 = b2f(yv4.w) + corr[rr][3];
    float s  = y0 + y1 + y2 + y3;
    float sq = y0*y0 + y1*y1 + y2*y2 + y3*y3;
    #pragma unroll
    for (int m = 1; m < 16; m <<= 1) {
      s  += __shfl_xor(s, m, 64);
      sq += __shfl_xor(sq, m, 64);
    }
    float mu  = s * (1.f/64.f);
    float var = sq * (1.f/64.f) - mu*mu;
    float rstd = rsqrtf(var + 6.4e-4f);
    ushort4 gu = ((const ushort4*)g)[o4];
    ushort4 ou;
    ou.x = f2b(((y0 - mu)*rstd*ga.x + be.x) * b2f(gu.x));
    ou.y = f2b(((y1 - mu)*rstd*ga.y + be.y) * b2f(gu.y));
    ou.z = f2b(((y2 - mu)*rstd*ga.z + be.z) * b2f(gu.z));
    ou.w = f2b(((y3 - mu)*rstd*ga.w + be.w) * b2f(gu.w));
    ((ushort4*)out)[o4] = ou;
  }
}

extern "C" void kernel_launch(void* const* d_in, const int* in_sizes, int n_in,
                              void* d_out, int out_size, void* d_ws, size_t ws_size,
                              hipStream_t stream) {
  const float* x      = (const float*)d_in[0];
  const float* maa_x  = (const float*)d_in[1];
  const float* maa_w  = (const float*)d_in[2];
  const float* maa_k  = (const float*)d_in[3];
  const float* maa_v  = (const float*)d_in[4];
  const float* maa_r  = (const float*)d_in[5];
  const float* maa_g  = (const float*)d_in[6];
  const float* w1     = (const float*)d_in[7];
  const float* w2     = (const float*)d_in[8];
  const float* tdecay = (const float*)d_in[9];
  const float* tdw1   = (const float*)d_in[10];
  const float* tdw2   = (const float*)d_in[11];
  const float* faaaa  = (const float*)d_in[12];
  const float* Wr     = (const float*)d_in[13];
  const float* Wk     = (const float*)d_in[14];
  const float* Wv     = (const float*)d_in[15];
  const float* Wg     = (const float*)d_in[16];
  const float* Wo     = (const float*)d_in[17];
  const float* gamma  = (const float*)d_in[18];
  const float* beta   = (const float*)d_in[19];
  float* out = (float*)d_out;

  const size_t MB = 1u << 20;
  char* wsb = (char*)d_ws;
  float* m1p  = (float*)(wsb + 0);            // 10.5M fp32 m1 k-partials (step2->3)
  u16*   w2T  = (u16*)(wsb + 12*MB);          // 320K bf16 w2 transposed (step0->3)
  u16*   xk   = (u16*)(wsb + 16*MB);          // 8M
  u16*   xv   = (u16*)(wsb + 24*MB);          // 8M
  u16*   xr   = (u16*)(wsb + 32*MB);          // 8M -> gated
  u16*   xg   = (u16*)(wsb + 40*MB);          // 8M
  float* wl1p = (float*)(wsb + 48*MB);        // 4M fp32 wl1 k-partials (step3->5)
  u16*   rbuf = (u16*)(wsb + 56*MB);          // 8M (r -> rc in-place)
  u16*   kbuf = (u16*)(wsb + 64*MB);          // 8M
  u16*   vbuf = (u16*)(wsb + 72*MB);          // 8M
  u16*   gbuf = (u16*)(wsb + 80*MB);          // 8M
  float* Dbuf = (float*)(wsb + 88*MB);        // 512K
  u16*   Sbuf = (u16*)(wsb + 16*MB);          // 16M over xk+xv (dead by pass1)
  u16*   BW0  = (u16*)(wsb + 88*MB + 512*1024);
  u16*   BW1  = (u16*)((char*)BW0 + 2*MB);
  u16*   BW2  = (u16*)((char*)BW1 + 2*MB);
  u16*   BW3  = (u16*)((char*)BW2 + 2*MB);
  u16*   BW4  = (u16*)((char*)BW3 + 2*MB);    // ends 98.5M
  u16*   w1T  = (u16*)((char*)BW4 + 2*MB);    // 320K
  u16*   tdw1T = (u16*)(wsb + 99*MB);
  u16*   tdw2T = (u16*)(wsb + 99*MB + 256*1024);
  u16*   gated = xr;
  u16*   xxx16 = (u16*)d_out;
  u16*   yb16  = (u16*)d_out;                 // 8M bf16 y (step5->6)

  dim3 blk(256);
  // 0+1. merged: weight transpose (z<9) + prep xxx (z>=9)
  WPack wp;
  wp.p[0] = {Wr, BW0, Cc, Cc};  wp.p[1] = {Wk, BW1, Cc, Cc};
  wp.p[2] = {Wv, BW2, Cc, Cc};  wp.p[3] = {Wg, BW3, Cc, Cc};
  wp.p[4] = {Wo, BW4, Cc, Cc};  wp.p[5] = {w1, w1T, Cc, 160};
  wp.p[6] = {tdw1, tdw1T, Cc, 64}; wp.p[7] = {tdw2, tdw2T, 64, Cc};
  wp.p[8] = {w2, w2T, 160, Cc};
  prep_transW<<<dim3(32,32,13), blk, 0, stream>>>(wp, x, maa_x, xxx16);
  // 2. m1 partials = xxx @ w1 (K-split z=4, fp32; tanh applied in mix_mfma)
  gemm_ksplit<<<dim3(2, 32, 4), blk, 0, stream>>>(xxx16, w1T, m1p, Cc, 256, 160);
  // 3. fused MFMA mix -> xk,xv,xr,xg + wl1 partials (xw never materialized)
  mix_mfma<<<1024, blk, 0, stream>>>(x, m1p, w2T, tdw1T,
                                     maa_w, maa_k, maa_v, maa_r, maa_g,
                                     wl1p, xk, xv, xr, xg);
  // 4. r,k,v,g batched — 256x256 4-phase kernel, 256 blocks
  GPack gp;
  gp.A[0] = xr; gp.A[1] = xk; gp.A[2] = xv; gp.A[3] = xg;
  gp.B[0] = BW0; gp.B[1] = BW1; gp.B[2] = BW2; gp.B[3] = BW3;
  gp.C[0] = rbuf; gp.C[1] = kbuf; gp.C[2] = vbuf; gp.C[3] = gbuf;
  gemm_rkvg256<<<dim3(4, 16, 4), dim3(512), 0, stream>>>(gp);
  // 5. wkv chunked scan (fused ew-GEMM; parallel decay scan; coalesced flush)
  wkv_pass1<<<Bb*Hh*NCH, blk, 0, stream>>>(rbuf, kbuf, vbuf, wl1p, tdw2T, tdecay,
                                           faaaa, yb16, Sbuf, Dbuf);
  wkv_pass2<<<Bb*Hh*4, blk, 0, stream>>>(Sbuf, Dbuf);
  // 6. groupnorm + correction + gate
  gn_gate<<<BT/8, blk, 0, stream>>>(yb16, gbuf, rbuf, Sbuf, gamma, beta, gated);
  // 7. out = gated @ Wo (fp32)
  gemm_mfma<0,true><<<dim3(8, 32), blk, 0, stream>>>(gated, BW4, out, nullptr, Cc, Cc);
}